// Round 2
// baseline (2297.776 us; speedup 1.0000x reference)
//
#include <hip/hip_runtime.h>
#include <hip/hip_bf16.h>

#define NN 100000
#define EE 1600000
#define DOUT 40
#define LN_EPS 1e-5f
#define NBUCK 391  // buckets of 256 dst nodes
#define TILE 2048
#define TBLK 782   // ceil(EE/TILE)
#define BCAP 8192  // per-bucket capacity (expected 4092 +- 64)
#define APITCH 65  // LDS accumulator row pitch (dwords) - bank rotation

typedef __attribute__((ext_vector_type(8))) short short8;   // 8 bf16 = 4 VGPRs
typedef __attribute__((ext_vector_type(4))) float f32x4;    // MFMA acc

// Hidden-state storage permutation: storage float position p = 4f+j holds TRUE
// feature f + 16j  (f in [0,16), j in [0,4)).  sigma(p) maps storage pos -> true
// feature; GEMMs stage W rows with sigma so X@W is unchanged.  LN is
// permutation-invariant; bias/gamma/beta are loaded at permuted indices.
__device__ __forceinline__ int sigmaP(int p) { return (p >> 2) | ((p & 3) << 4); }

// ---------------------------------------------------------------- bf16 helpers (RNE pack)
__device__ __forceinline__ float blo(unsigned u) { return __uint_as_float(u << 16); }
__device__ __forceinline__ float bhi(unsigned u) { return __uint_as_float(u & 0xffff0000u); }
__device__ __forceinline__ unsigned bpack(float lo, float hi) {
    unsigned a = __float_as_uint(lo);
    unsigned b = __float_as_uint(hi);
    a = (a + 0x7fffu + ((a >> 16) & 1u)) >> 16;
    b = (b + 0x7fffu + ((b >> 16) & 1u)) & 0xffff0000u;
    return (a & 0xffffu) | b;
}

// ---------------------------------------------------------------- bucket build
__global__ void binit_k(int* __restrict__ bucketCur) {
    int b = blockIdx.x * 256 + threadIdx.x;
    if (b < NBUCK) bucketCur[b] = b * BCAP;
}

// 782 blocks x 512 threads x 4 edges. Pass 1: per-wave LDS histogram.
// One global atomic per nonzero bucket per block. Pass 2: scatter into
// fixed-capacity bucket regions, per-wave sub-chunks (contiguous writes).
__global__ __launch_bounds__(512, 8) void bucket_k(const int* __restrict__ src,
                                                   const int* __restrict__ dst,
                                                   int* __restrict__ bucketCur,
                                                   unsigned* __restrict__ bE) {
    __shared__ int cnt[8][NBUCK];
    __shared__ int basew[8][NBUCK];
    int tid = threadIdx.x;
    int wv = tid >> 6;
    for (int i = tid; i < 8 * NBUCK; i += 512) ((int*)cnt)[i] = 0;
    __syncthreads();
    long e0 = (long)blockIdx.x * TILE;
    int d[4];
#pragma unroll
    for (int i = 0; i < 4; ++i) {
        long e = e0 + tid + i * 512;
        d[i] = (e < EE) ? dst[e] : -1;
    }
#pragma unroll
    for (int i = 0; i < 4; ++i) {
        if (d[i] >= 0) atomicAdd(&cnt[wv][d[i] >> 8], 1);
    }
    __syncthreads();
    for (int b = tid; b < NBUCK; b += 512) {
        int c[8];
        int tot = 0;
#pragma unroll
        for (int w = 0; w < 8; ++w) { c[w] = cnt[w][b]; tot += c[w]; }
        int base = tot ? atomicAdd(&bucketCur[b], tot) : 0;
        int run = base;
#pragma unroll
        for (int w = 0; w < 8; ++w) { basew[w][b] = run; run += c[w]; cnt[w][b] = 0; }
    }
    __syncthreads();
#pragma unroll
    for (int i = 0; i < 4; ++i) {
        if (d[i] >= 0) {
            long e = e0 + tid + i * 512;
            int b = d[i] >> 8;
            int pos = basew[wv][b] + atomicAdd(&cnt[wv][b], 1);
            bE[pos] = (unsigned)src[e] | ((unsigned)(d[i] & 255) << 24);
        }
    }
}

// ---------------------------------------------------------------- per-bucket degree -> dinv (no CSR needed)
__global__ __launch_bounds__(256, 8) void hist_k(const int* __restrict__ bucketCur,
                                                 const unsigned* __restrict__ bE,
                                                 float* __restrict__ dinv) {
    __shared__ int h[256];
    int tid = threadIdx.x;
    h[tid] = 0;
    __syncthreads();
    int b = blockIdx.x;
    int end = bucketCur[b];
    for (int e = b * BCAP + tid; e < end; e += 256) atomicAdd(&h[bE[e] >> 24], 1);
    __syncthreads();
    int node = (b << 8) + tid;
    if (node < NN) dinv[node] = rsqrtf((float)h[tid] + 1.0f);
}

// ---------------------------------------------------------------- MFMA GEMM: H' = bf16((X@W)*dinv), output in P-order
// PIN=1: input (bufB) is in P-order -> stage W rows at sigma(k).
// Output H (bf16): uint2[f] = (pack(feat f, feat f+16), pack(feat f+32, feat f+48)).
template <int K, int PIN>
__global__ __launch_bounds__(256, 2) void gemm_mfma(const float* __restrict__ X,
                                                    const float* __restrict__ W,
                                                    const float* __restrict__ dinv,
                                                    unsigned* __restrict__ H) {
    constexpr int C = K / 32;
    __shared__ unsigned short sW16[K * 66];
    __shared__ float sD[64 * 65];
    int tid = threadIdx.x;
    for (int i = tid; i < K * 64; i += 256) {
        int k = i >> 6, n = i & 63;
        int kk = PIN ? sigmaP(k) : k;
        sW16[k * 66 + n] = (unsigned short)(bpack(W[kk * 64 + n], 0.f) & 0xffffu);
    }
    __syncthreads();
    int wv = tid >> 6, lane = tid & 63;
    int q = lane >> 4, ln = lane & 15;
    short8 bfrag[C][4];
#pragma unroll
    for (int c = 0; c < C; ++c) {
#pragma unroll
        for (int t = 0; t < 4; ++t) {
            int kb = (c * 32 + q * 8) * 66 + t * 16 + ln;
            unsigned u0 = (unsigned)sW16[kb]       | ((unsigned)sW16[kb + 66]  << 16);
            unsigned u1 = (unsigned)sW16[kb + 132] | ((unsigned)sW16[kb + 198] << 16);
            unsigned u2 = (unsigned)sW16[kb + 264] | ((unsigned)sW16[kb + 330] << 16);
            unsigned u3 = (unsigned)sW16[kb + 396] | ((unsigned)sW16[kb + 462] << 16);
            uint4 u = make_uint4(u0, u1, u2, u3);
            bfrag[c][t] = __builtin_bit_cast(short8, u);
        }
    }
    int base = blockIdx.x * 64;
    int node = base + wv * 16 + ln;
    bool ok = node < NN;
    short8 afrag[C];
#pragma unroll
    for (int c = 0; c < C; ++c) {
        float4 f0 = make_float4(0.f, 0.f, 0.f, 0.f);
        float4 f1 = make_float4(0.f, 0.f, 0.f, 0.f);
        if (ok) {
            const float4* xp = (const float4*)(X + (long)node * K + c * 32 + q * 8);
            f0 = xp[0];
            f1 = xp[1];
        }
        uint4 u;
        u.x = bpack(f0.x, f0.y);
        u.y = bpack(f0.z, f0.w);
        u.z = bpack(f1.x, f1.y);
        u.w = bpack(f1.z, f1.w);
        afrag[c] = __builtin_bit_cast(short8, u);
    }
#pragma unroll
    for (int t = 0; t < 4; ++t) {
        f32x4 acc = {0.f, 0.f, 0.f, 0.f};
#pragma unroll
        for (int c = 0; c < C; ++c)
            acc = __builtin_amdgcn_mfma_f32_16x16x32_bf16(afrag[c], bfrag[c][t], acc, 0, 0, 0);
#pragma unroll
        for (int r = 0; r < 4; ++r)
            sD[(wv * 16 + q * 4 + r) * 65 + t * 16 + ln] = acc[r];
    }
    __syncthreads();
    for (int i = tid; i < 64 * 32; i += 256) {
        int row = i >> 5, c2 = i & 31;
        int nd = base + row;
        if (nd < NN) {
            float di = dinv[nd];
            int fbase = ((c2 >> 1) & 15) + ((c2 & 1) << 5);  // feats (fbase, fbase+16)
            float lo = sD[row * 65 + fbase] * di;
            float hi = sD[row * 65 + fbase + 16] * di;
            H[nd * 32 + c2] = bpack(lo, hi);
        }
    }
}

// ---------------------------------------------------------------- bucket-LDS aggregate + bias + relu + optional LN
// One block per bucket: 256 dst nodes x 64 f32 accumulated in LDS via ds_add_f32.
// Edge list consumed directly from bE (unordered).  16-lane group per edge.
__global__ __launch_bounds__(512, 4) void aggb_k(
        const int* __restrict__ bucketCur, const unsigned* __restrict__ bE,
        const float* __restrict__ dinv, const uint2* __restrict__ H2,
        const float* __restrict__ bias, const float* __restrict__ gam,
        const float* __restrict__ beta, float4* __restrict__ OUT4, int doLN) {
    __shared__ __align__(16) float acc[256 * APITCH];
    int tid = threadIdx.x;
    float4 z4 = make_float4(0.f, 0.f, 0.f, 0.f);
    for (int i = tid; i < 256 * APITCH / 4; i += 512) ((float4*)acc)[i] = z4;
    __syncthreads();
    int b = blockIdx.x;
    int grp = tid >> 4;   // 0..31 (16-lane groups)
    int f = tid & 15;
    int start = b * BCAP;
    int end = bucketCur[b];
    int e = start + grp;
    for (; e + 96 < end; e += 128) {
        unsigned v0 = bE[e];
        unsigned v1 = bE[e + 32];
        unsigned v2 = bE[e + 64];
        unsigned v3 = bE[e + 96];
        uint2 q0 = H2[(v0 & 0xFFFFFFu) * 16 + f];
        uint2 q1 = H2[(v1 & 0xFFFFFFu) * 16 + f];
        uint2 q2 = H2[(v2 & 0xFFFFFFu) * 16 + f];
        uint2 q3 = H2[(v3 & 0xFFFFFFu) * 16 + f];
        float* p0 = acc + (v0 >> 24) * APITCH + f;
        float* p1 = acc + (v1 >> 24) * APITCH + f;
        float* p2 = acc + (v2 >> 24) * APITCH + f;
        float* p3 = acc + (v3 >> 24) * APITCH + f;
        unsafeAtomicAdd(p0, blo(q0.x));      unsafeAtomicAdd(p0 + 16, bhi(q0.x));
        unsafeAtomicAdd(p0 + 32, blo(q0.y)); unsafeAtomicAdd(p0 + 48, bhi(q0.y));
        unsafeAtomicAdd(p1, blo(q1.x));      unsafeAtomicAdd(p1 + 16, bhi(q1.x));
        unsafeAtomicAdd(p1 + 32, blo(q1.y)); unsafeAtomicAdd(p1 + 48, bhi(q1.y));
        unsafeAtomicAdd(p2, blo(q2.x));      unsafeAtomicAdd(p2 + 16, bhi(q2.x));
        unsafeAtomicAdd(p2 + 32, blo(q2.y)); unsafeAtomicAdd(p2 + 48, bhi(q2.y));
        unsafeAtomicAdd(p3, blo(q3.x));      unsafeAtomicAdd(p3 + 16, bhi(q3.x));
        unsafeAtomicAdd(p3 + 32, blo(q3.y)); unsafeAtomicAdd(p3 + 48, bhi(q3.y));
    }
    for (; e < end; e += 32) {
        unsigned v = bE[e];
        uint2 q = H2[(v & 0xFFFFFFu) * 16 + f];
        float* p = acc + (v >> 24) * APITCH + f;
        unsafeAtomicAdd(p, blo(q.x));      unsafeAtomicAdd(p + 16, bhi(q.x));
        unsafeAtomicAdd(p + 32, blo(q.y)); unsafeAtomicAdd(p + 48, bhi(q.y));
    }
    __syncthreads();
    // epilogue: one node per 16-lane group; lane f holds true feats f, f+16, f+32, f+48
    for (int n0 = grp; n0 < 256; n0 += 32) {
        int node = (b << 8) + n0;
        if (node >= NN) break;
        float di = dinv[node];
        uint2 qs = H2[(long)node * 16 + f];
        const float* ap = acc + n0 * APITCH + f;
        float vx = fmaxf((ap[0]  + blo(qs.x)) * di + bias[f], 0.f);
        float vy = fmaxf((ap[16] + bhi(qs.x)) * di + bias[f + 16], 0.f);
        float vz = fmaxf((ap[32] + blo(qs.y)) * di + bias[f + 32], 0.f);
        float vw = fmaxf((ap[48] + bhi(qs.y)) * di + bias[f + 48], 0.f);
        if (doLN) {
            float s = vx + vy + vz + vw;
            s += __shfl_xor(s, 1); s += __shfl_xor(s, 2);
            s += __shfl_xor(s, 4); s += __shfl_xor(s, 8);
            float mu = s * (1.f / 64.f);
            vx -= mu; vy -= mu; vz -= mu; vw -= mu;
            float vs = vx * vx + vy * vy + vz * vz + vw * vw;
            vs += __shfl_xor(vs, 1); vs += __shfl_xor(vs, 2);
            vs += __shfl_xor(vs, 4); vs += __shfl_xor(vs, 8);
            float inv = rsqrtf(vs * (1.f / 64.f) + LN_EPS);
            vx = vx * inv * gam[f]      + beta[f];
            vy = vy * inv * gam[f + 16] + beta[f + 16];
            vz = vz * inv * gam[f + 32] + beta[f + 32];
            vw = vw * inv * gam[f + 48] + beta[f + 48];
        }
        OUT4[(long)node * 16 + f] = make_float4(vx, vy, vz, vw);
    }
}

// ---------------------------------------------------------------- fuse the two head linears
__global__ void fuse_k(const float* __restrict__ W0, const float* __restrict__ b0,
                       const float* __restrict__ W1, const float* __restrict__ b1,
                       float* __restrict__ Wf, float* __restrict__ bf) {
    int tid = threadIdx.x;
    for (int i = tid; i < 64 * 48; i += 256) {
        int k = i / 48, n = i % 48;
        float acc = 0.f;
        if (n < DOUT) {
            for (int j = 0; j < 64; ++j) acc = fmaf(W0[k * 64 + j], W1[j * DOUT + n], acc);
        }
        Wf[i] = acc;
    }
    for (int n = tid; n < 48; n += 256) {
        float acc = 0.f;
        if (n < DOUT) {
            acc = b1[n];
            for (int j = 0; j < 64; ++j) acc = fmaf(b0[j], W1[j * DOUT + n], acc);
        }
        bf[n] = acc;
    }
}

// ---------------------------------------------------------------- MLP head via MFMA: OUT = Hin @ Wf + bf (Hin in P-order)
__global__ __launch_bounds__(256, 2) void mlp_mfma(const float* __restrict__ Hin,
                                                   const float* __restrict__ Wf,
                                                   const float* __restrict__ bf,
                                                   float* __restrict__ OUT) {
    __shared__ unsigned short sW16[64 * 50];
    int tid = threadIdx.x;
    for (int i = tid; i < 64 * 48; i += 256) {
        int k = i / 48, n = i % 48;
        sW16[k * 50 + n] = (unsigned short)(bpack(Wf[sigmaP(k) * 48 + n], 0.f) & 0xffffu);
    }
    __syncthreads();
    int wv = tid >> 6, lane = tid & 63;
    int q = lane >> 4, ln = lane & 15;
    short8 bfrag[2][3];
#pragma unroll
    for (int c = 0; c < 2; ++c) {
#pragma unroll
        for (int t = 0; t < 3; ++t) {
            int kb = (c * 32 + q * 8) * 50 + t * 16 + ln;
            unsigned u0 = (unsigned)sW16[kb]       | ((unsigned)sW16[kb + 50]  << 16);
            unsigned u1 = (unsigned)sW16[kb + 100] | ((unsigned)sW16[kb + 150] << 16);
            unsigned u2 = (unsigned)sW16[kb + 200] | ((unsigned)sW16[kb + 250] << 16);
            unsigned u3 = (unsigned)sW16[kb + 300] | ((unsigned)sW16[kb + 350] << 16);
            uint4 u = make_uint4(u0, u1, u2, u3);
            bfrag[c][t] = __builtin_bit_cast(short8, u);
        }
    }
    int base = blockIdx.x * 64;
    int node = base + wv * 16 + ln;
    bool ok = node < NN;
    short8 afrag[2];
#pragma unroll
    for (int c = 0; c < 2; ++c) {
        float4 f0 = make_float4(0.f, 0.f, 0.f, 0.f);
        float4 f1 = make_float4(0.f, 0.f, 0.f, 0.f);
        if (ok) {
            const float4* xp = (const float4*)(Hin + (long)node * 64 + c * 32 + q * 8);
            f0 = xp[0];
            f1 = xp[1];
        }
        uint4 u;
        u.x = bpack(f0.x, f0.y);
        u.y = bpack(f0.z, f0.w);
        u.z = bpack(f1.x, f1.y);
        u.w = bpack(f1.z, f1.w);
        afrag[c] = __builtin_bit_cast(short8, u);
    }
#pragma unroll
    for (int t = 0; t < 3; ++t) {
        f32x4 acc = {0.f, 0.f, 0.f, 0.f};
        acc = __builtin_amdgcn_mfma_f32_16x16x32_bf16(afrag[0], bfrag[0][t], acc, 0, 0, 0);
        acc = __builtin_amdgcn_mfma_f32_16x16x32_bf16(afrag[1], bfrag[1][t], acc, 0, 0, 0);
        int col = t * 16 + ln;
        if (col < DOUT) {
            float bv = bf[col];
#pragma unroll
            for (int r = 0; r < 4; ++r) {
                int nd = base + wv * 16 + q * 4 + r;
                if (nd < NN) OUT[(long)nd * DOUT + col] = acc[r] + bv;
            }
        }
    }
}

// ----------------------------------------------------------------
extern "C" void kernel_launch(void* const* d_in, const int* in_sizes, int n_in,
                              void* d_out, int out_size, void* d_ws, size_t ws_size,
                              hipStream_t stream) {
    const float* x    = (const float*)d_in[0];
    const int*   ei   = (const int*)d_in[1];
    const int*   srcI = ei;
    const int*   dstI = ei + EE;
    const float* W0   = (const float*)d_in[2];
    const float* b0   = (const float*)d_in[3];
    const float* W1   = (const float*)d_in[4];
    const float* b1   = (const float*)d_in[5];
    const float* W2   = (const float*)d_in[6];
    const float* b2   = (const float*)d_in[7];
    const float* ln0g = (const float*)d_in[8];
    const float* ln0b = (const float*)d_in[9];
    const float* ln1g = (const float*)d_in[10];
    const float* ln1b = (const float*)d_in[11];
    const float* mpW0 = (const float*)d_in[12];
    const float* mpb0 = (const float*)d_in[13];
    const float* mpW1 = (const float*)d_in[14];
    const float* mpb1 = (const float*)d_in[15];
    float* out = (float*)d_out;

    char* ws = (char*)d_ws;
    float*    dinv      = (float*)   (ws + 0);                      // 400 KB
    int*      bucketCur = (int*)     (ws + 512l * 1024);
    float*    Wf        = (float*)   (ws + 640l * 1024);
    float*    bfv       = (float*)   (ws + 768l * 1024);
    unsigned* bE        = (unsigned*)(ws + 1024l * 1024);           // 391*8192*4 = 12.8 MB
    unsigned* bufA      = (unsigned*)(ws + 16l * 1024 * 1024);      // bf16 H' (P-order) 12.8 MB
    float*    bufB      = (float*)   (ws + 32l * 1024 * 1024);      // f32 hidden (P-order) 25.6 MB

    const int gemmBlocks = (NN + 63) / 64;     // 1563

    binit_k<<<2, 256, 0, stream>>>(bucketCur);
    bucket_k<<<TBLK, 512, 0, stream>>>(srcI, dstI, bucketCur, bE);
    hist_k<<<NBUCK, 256, 0, stream>>>(bucketCur, bE, dinv);
    fuse_k<<<1, 256, 0, stream>>>(mpW0, mpb0, mpW1, mpb1, Wf, bfv);

    // layer 0
    gemm_mfma<128, 0><<<gemmBlocks, 256, 0, stream>>>(x, W0, dinv, bufA);
    aggb_k<<<NBUCK, 512, 0, stream>>>(bucketCur, bE, dinv, (const uint2*)bufA,
                                      b0, ln0g, ln0b, (float4*)bufB, 1);
    // layer 1
    gemm_mfma<64, 1><<<gemmBlocks, 256, 0, stream>>>(bufB, W1, dinv, bufA);
    aggb_k<<<NBUCK, 512, 0, stream>>>(bucketCur, bE, dinv, (const uint2*)bufA,
                                      b1, ln1g, ln1b, (float4*)bufB, 1);
    // layer 2 (no LN) then fused MLP head via MFMA
    gemm_mfma<64, 1><<<gemmBlocks, 256, 0, stream>>>(bufB, W2, dinv, bufA);
    aggb_k<<<NBUCK, 512, 0, stream>>>(bucketCur, bE, dinv, (const uint2*)bufA,
                                      b2, ln0g, ln0b, (float4*)bufB, 0);
    mlp_mfma<<<gemmBlocks, 256, 0, stream>>>(bufB, Wf, bfv, out);
}

// Round 3
// 2295.392 us; speedup vs baseline: 1.0010x; 1.0010x over previous
//
#include <hip/hip_runtime.h>
#include <hip/hip_bf16.h>

#define NN 100000
#define EE 1600000
#define DOUT 40
#define LN_EPS 1e-5f
#define NBUCK 391  // buckets of 256 dst nodes
#define TILE 2048
#define TBLK 782   // ceil(EE/TILE)
#define BCAP 8192  // per-bucket capacity (expected 4092 +- 64)
#define APITCH 65  // LDS accumulator row pitch (dwords) - bank rotation

typedef __attribute__((ext_vector_type(8))) short short8;   // 8 bf16 = 4 VGPRs
typedef __attribute__((ext_vector_type(4))) float f32x4;    // MFMA acc

// Hidden-state storage permutation: storage float position p = 4f+j holds TRUE
// feature f + 16j  (f in [0,16), j in [0,4)).  sigma(p) maps storage pos -> true
// feature; GEMMs stage W rows with sigma so X@W is unchanged.  LN is
// permutation-invariant; bias/gamma/beta are loaded at permuted indices.
__device__ __forceinline__ int sigmaP(int p) { return (p >> 2) | ((p & 3) << 4); }

// ---------------------------------------------------------------- bf16 helpers (RNE pack)
__device__ __forceinline__ float blo(unsigned u) { return __uint_as_float(u << 16); }
__device__ __forceinline__ float bhi(unsigned u) { return __uint_as_float(u & 0xffff0000u); }
__device__ __forceinline__ unsigned bpack(float lo, float hi) {
    unsigned a = __float_as_uint(lo);
    unsigned b = __float_as_uint(hi);
    a = (a + 0x7fffu + ((a >> 16) & 1u)) >> 16;
    b = (b + 0x7fffu + ((b >> 16) & 1u)) & 0xffff0000u;
    return (a & 0xffffu) | b;
}

// ---------------------------------------------------------------- bucket build
__global__ void binit_k(int* __restrict__ bucketCur) {
    int b = blockIdx.x * 256 + threadIdx.x;
    if (b < NBUCK) bucketCur[b] = b * BCAP;
}

// 782 blocks x 512 threads x 4 edges. Pass 1: per-wave LDS histogram.
// One global atomic per nonzero bucket per block. Pass 2: scatter into
// fixed-capacity bucket regions, per-wave sub-chunks (contiguous writes).
__global__ __launch_bounds__(512, 8) void bucket_k(const int* __restrict__ src,
                                                   const int* __restrict__ dst,
                                                   int* __restrict__ bucketCur,
                                                   unsigned* __restrict__ bE) {
    __shared__ int cnt[8][NBUCK];
    __shared__ int basew[8][NBUCK];
    int tid = threadIdx.x;
    int wv = tid >> 6;
    for (int i = tid; i < 8 * NBUCK; i += 512) ((int*)cnt)[i] = 0;
    __syncthreads();
    long e0 = (long)blockIdx.x * TILE;
    int d[4];
#pragma unroll
    for (int i = 0; i < 4; ++i) {
        long e = e0 + tid + i * 512;
        d[i] = (e < EE) ? dst[e] : -1;
    }
#pragma unroll
    for (int i = 0; i < 4; ++i) {
        if (d[i] >= 0) atomicAdd(&cnt[wv][d[i] >> 8], 1);
    }
    __syncthreads();
    for (int b = tid; b < NBUCK; b += 512) {
        int c[8];
        int tot = 0;
#pragma unroll
        for (int w = 0; w < 8; ++w) { c[w] = cnt[w][b]; tot += c[w]; }
        int base = tot ? atomicAdd(&bucketCur[b], tot) : 0;
        int run = base;
#pragma unroll
        for (int w = 0; w < 8; ++w) { basew[w][b] = run; run += c[w]; cnt[w][b] = 0; }
    }
    __syncthreads();
#pragma unroll
    for (int i = 0; i < 4; ++i) {
        if (d[i] >= 0) {
            long e = e0 + tid + i * 512;
            int b = d[i] >> 8;
            int pos = basew[wv][b] + atomicAdd(&cnt[wv][b], 1);
            bE[pos] = (unsigned)src[e] | ((unsigned)(d[i] & 255) << 24);
        }
    }
}

// ---------------------------------------------------------------- per-bucket degree -> dinv (no CSR needed)
__global__ __launch_bounds__(256, 8) void hist_k(const int* __restrict__ bucketCur,
                                                 const unsigned* __restrict__ bE,
                                                 float* __restrict__ dinv) {
    __shared__ int h[256];
    int tid = threadIdx.x;
    h[tid] = 0;
    __syncthreads();
    int b = blockIdx.x;
    int end = bucketCur[b];
    for (int e = b * BCAP + tid; e < end; e += 256) atomicAdd(&h[bE[e] >> 24], 1);
    __syncthreads();
    int node = (b << 8) + tid;
    if (node < NN) dinv[node] = rsqrtf((float)h[tid] + 1.0f);
}

// ---------------------------------------------------------------- MFMA GEMM: H' = bf16((X@W)*dinv), output in P-order
// PIN=1: input (bufB) is in P-order -> stage W rows at sigma(k).
// Output H (bf16): uint2[f] = (pack(feat f, feat f+16), pack(feat f+32, feat f+48)).
template <int K, int PIN>
__global__ __launch_bounds__(256, 2) void gemm_mfma(const float* __restrict__ X,
                                                    const float* __restrict__ W,
                                                    const float* __restrict__ dinv,
                                                    unsigned* __restrict__ H) {
    constexpr int C = K / 32;
    __shared__ unsigned short sW16[K * 66];
    __shared__ float sD[64 * 65];
    int tid = threadIdx.x;
    for (int i = tid; i < K * 64; i += 256) {
        int k = i >> 6, n = i & 63;
        int kk = PIN ? sigmaP(k) : k;
        sW16[k * 66 + n] = (unsigned short)(bpack(W[kk * 64 + n], 0.f) & 0xffffu);
    }
    __syncthreads();
    int wv = tid >> 6, lane = tid & 63;
    int q = lane >> 4, ln = lane & 15;
    short8 bfrag[C][4];
#pragma unroll
    for (int c = 0; c < C; ++c) {
#pragma unroll
        for (int t = 0; t < 4; ++t) {
            int kb = (c * 32 + q * 8) * 66 + t * 16 + ln;
            unsigned u0 = (unsigned)sW16[kb]       | ((unsigned)sW16[kb + 66]  << 16);
            unsigned u1 = (unsigned)sW16[kb + 132] | ((unsigned)sW16[kb + 198] << 16);
            unsigned u2 = (unsigned)sW16[kb + 264] | ((unsigned)sW16[kb + 330] << 16);
            unsigned u3 = (unsigned)sW16[kb + 396] | ((unsigned)sW16[kb + 462] << 16);
            uint4 u = make_uint4(u0, u1, u2, u3);
            bfrag[c][t] = __builtin_bit_cast(short8, u);
        }
    }
    int base = blockIdx.x * 64;
    int node = base + wv * 16 + ln;
    bool ok = node < NN;
    short8 afrag[C];
#pragma unroll
    for (int c = 0; c < C; ++c) {
        float4 f0 = make_float4(0.f, 0.f, 0.f, 0.f);
        float4 f1 = make_float4(0.f, 0.f, 0.f, 0.f);
        if (ok) {
            const float4* xp = (const float4*)(X + (long)node * K + c * 32 + q * 8);
            f0 = xp[0];
            f1 = xp[1];
        }
        uint4 u;
        u.x = bpack(f0.x, f0.y);
        u.y = bpack(f0.z, f0.w);
        u.z = bpack(f1.x, f1.y);
        u.w = bpack(f1.z, f1.w);
        afrag[c] = __builtin_bit_cast(short8, u);
    }
#pragma unroll
    for (int t = 0; t < 4; ++t) {
        f32x4 acc = {0.f, 0.f, 0.f, 0.f};
#pragma unroll
        for (int c = 0; c < C; ++c)
            acc = __builtin_amdgcn_mfma_f32_16x16x32_bf16(afrag[c], bfrag[c][t], acc, 0, 0, 0);
#pragma unroll
        for (int r = 0; r < 4; ++r)
            sD[(wv * 16 + q * 4 + r) * 65 + t * 16 + ln] = acc[r];
    }
    __syncthreads();
    for (int i = tid; i < 64 * 32; i += 256) {
        int row = i >> 5, c2 = i & 31;
        int nd = base + row;
        if (nd < NN) {
            float di = dinv[nd];
            int fbase = ((c2 >> 1) & 15) + ((c2 & 1) << 5);  // feats (fbase, fbase+16)
            float lo = sD[row * 65 + fbase] * di;
            float hi = sD[row * 65 + fbase + 16] * di;
            H[nd * 32 + c2] = bpack(lo, hi);
        }
    }
}

// ---------------------------------------------------------------- bucket-LDS aggregate + bias + relu + optional LN
// One block per bucket: 256 dst nodes x 64 f32 accumulated in LDS via ds_add_f32.
// atomicAdd is written against the __shared__ array expression so the address
// space is statically known (flat-atomic fadd to the LDS aperture is ~20x
// slower - round-2 lesson).  Edge list consumed directly from bE (unordered).
__global__ __launch_bounds__(512, 4) void aggb_k(
        const int* __restrict__ bucketCur, const unsigned* __restrict__ bE,
        const float* __restrict__ dinv, const uint2* __restrict__ H2,
        const float* __restrict__ bias, const float* __restrict__ gam,
        const float* __restrict__ beta, float4* __restrict__ OUT4, int doLN) {
    __shared__ __align__(16) float acc[256 * APITCH];
    int tid = threadIdx.x;
    float4 z4 = make_float4(0.f, 0.f, 0.f, 0.f);
    for (int i = tid; i < 256 * APITCH / 4; i += 512) ((float4*)acc)[i] = z4;
    __syncthreads();
    int b = blockIdx.x;
    int grp = tid >> 4;   // 0..31 (16-lane groups)
    int f = tid & 15;
    int start = b * BCAP;
    int end = bucketCur[b];
    int e = start + grp;
    for (; e + 96 < end; e += 128) {
        unsigned v0 = bE[e];
        unsigned v1 = bE[e + 32];
        unsigned v2 = bE[e + 64];
        unsigned v3 = bE[e + 96];
        uint2 q0 = H2[(v0 & 0xFFFFFFu) * 16 + f];
        uint2 q1 = H2[(v1 & 0xFFFFFFu) * 16 + f];
        uint2 q2 = H2[(v2 & 0xFFFFFFu) * 16 + f];
        uint2 q3 = H2[(v3 & 0xFFFFFFu) * 16 + f];
        int i0 = (int)(v0 >> 24) * APITCH + f;
        int i1 = (int)(v1 >> 24) * APITCH + f;
        int i2 = (int)(v2 >> 24) * APITCH + f;
        int i3 = (int)(v3 >> 24) * APITCH + f;
        atomicAdd(&acc[i0], blo(q0.x));      atomicAdd(&acc[i0 + 16], bhi(q0.x));
        atomicAdd(&acc[i0 + 32], blo(q0.y)); atomicAdd(&acc[i0 + 48], bhi(q0.y));
        atomicAdd(&acc[i1], blo(q1.x));      atomicAdd(&acc[i1 + 16], bhi(q1.x));
        atomicAdd(&acc[i1 + 32], blo(q1.y)); atomicAdd(&acc[i1 + 48], bhi(q1.y));
        atomicAdd(&acc[i2], blo(q2.x));      atomicAdd(&acc[i2 + 16], bhi(q2.x));
        atomicAdd(&acc[i2 + 32], blo(q2.y)); atomicAdd(&acc[i2 + 48], bhi(q2.y));
        atomicAdd(&acc[i3], blo(q3.x));      atomicAdd(&acc[i3 + 16], bhi(q3.x));
        atomicAdd(&acc[i3 + 32], blo(q3.y)); atomicAdd(&acc[i3 + 48], bhi(q3.y));
    }
    for (; e < end; e += 32) {
        unsigned v = bE[e];
        uint2 q = H2[(v & 0xFFFFFFu) * 16 + f];
        int i0 = (int)(v >> 24) * APITCH + f;
        atomicAdd(&acc[i0], blo(q.x));      atomicAdd(&acc[i0 + 16], bhi(q.x));
        atomicAdd(&acc[i0 + 32], blo(q.y)); atomicAdd(&acc[i0 + 48], bhi(q.y));
    }
    __syncthreads();
    // epilogue: one node per 16-lane group; lane f holds true feats f, f+16, f+32, f+48
    for (int n0 = grp; n0 < 256; n0 += 32) {
        int node = (b << 8) + n0;
        if (node >= NN) break;
        float di = dinv[node];
        uint2 qs = H2[(long)node * 16 + f];
        const float* ap = acc + n0 * APITCH + f;
        float vx = fmaxf((ap[0]  + blo(qs.x)) * di + bias[f], 0.f);
        float vy = fmaxf((ap[16] + bhi(qs.x)) * di + bias[f + 16], 0.f);
        float vz = fmaxf((ap[32] + blo(qs.y)) * di + bias[f + 32], 0.f);
        float vw = fmaxf((ap[48] + bhi(qs.y)) * di + bias[f + 48], 0.f);
        if (doLN) {
            float s = vx + vy + vz + vw;
            s += __shfl_xor(s, 1); s += __shfl_xor(s, 2);
            s += __shfl_xor(s, 4); s += __shfl_xor(s, 8);
            float mu = s * (1.f / 64.f);
            vx -= mu; vy -= mu; vz -= mu; vw -= mu;
            float vs = vx * vx + vy * vy + vz * vz + vw * vw;
            vs += __shfl_xor(vs, 1); vs += __shfl_xor(vs, 2);
            vs += __shfl_xor(vs, 4); vs += __shfl_xor(vs, 8);
            float inv = rsqrtf(vs * (1.f / 64.f) + LN_EPS);
            vx = vx * inv * gam[f]      + beta[f];
            vy = vy * inv * gam[f + 16] + beta[f + 16];
            vz = vz * inv * gam[f + 32] + beta[f + 32];
            vw = vw * inv * gam[f + 48] + beta[f + 48];
        }
        OUT4[(long)node * 16 + f] = make_float4(vx, vy, vz, vw);
    }
}

// ---------------------------------------------------------------- fuse the two head linears
__global__ void fuse_k(const float* __restrict__ W0, const float* __restrict__ b0,
                       const float* __restrict__ W1, const float* __restrict__ b1,
                       float* __restrict__ Wf, float* __restrict__ bf) {
    int tid = threadIdx.x;
    for (int i = tid; i < 64 * 48; i += 256) {
        int k = i / 48, n = i % 48;
        float acc = 0.f;
        if (n < DOUT) {
            for (int j = 0; j < 64; ++j) acc = fmaf(W0[k * 64 + j], W1[j * DOUT + n], acc);
        }
        Wf[i] = acc;
    }
    for (int n = tid; n < 48; n += 256) {
        float acc = 0.f;
        if (n < DOUT) {
            acc = b1[n];
            for (int j = 0; j < 64; ++j) acc = fmaf(b0[j], W1[j * DOUT + n], acc);
        }
        bf[n] = acc;
    }
}

// ---------------------------------------------------------------- MLP head via MFMA: OUT = Hin @ Wf + bf (Hin in P-order)
__global__ __launch_bounds__(256, 2) void mlp_mfma(const float* __restrict__ Hin,
                                                   const float* __restrict__ Wf,
                                                   const float* __restrict__ bf,
                                                   float* __restrict__ OUT) {
    __shared__ unsigned short sW16[64 * 50];
    int tid = threadIdx.x;
    for (int i = tid; i < 64 * 48; i += 256) {
        int k = i / 48, n = i % 48;
        sW16[k * 50 + n] = (unsigned short)(bpack(Wf[sigmaP(k) * 48 + n], 0.f) & 0xffffu);
    }
    __syncthreads();
    int wv = tid >> 6, lane = tid & 63;
    int q = lane >> 4, ln = lane & 15;
    short8 bfrag[2][3];
#pragma unroll
    for (int c = 0; c < 2; ++c) {
#pragma unroll
        for (int t = 0; t < 3; ++t) {
            int kb = (c * 32 + q * 8) * 50 + t * 16 + ln;
            unsigned u0 = (unsigned)sW16[kb]       | ((unsigned)sW16[kb + 50]  << 16);
            unsigned u1 = (unsigned)sW16[kb + 100] | ((unsigned)sW16[kb + 150] << 16);
            unsigned u2 = (unsigned)sW16[kb + 200] | ((unsigned)sW16[kb + 250] << 16);
            unsigned u3 = (unsigned)sW16[kb + 300] | ((unsigned)sW16[kb + 350] << 16);
            uint4 u = make_uint4(u0, u1, u2, u3);
            bfrag[c][t] = __builtin_bit_cast(short8, u);
        }
    }
    int base = blockIdx.x * 64;
    int node = base + wv * 16 + ln;
    bool ok = node < NN;
    short8 afrag[2];
#pragma unroll
    for (int c = 0; c < 2; ++c) {
        float4 f0 = make_float4(0.f, 0.f, 0.f, 0.f);
        float4 f1 = make_float4(0.f, 0.f, 0.f, 0.f);
        if (ok) {
            const float4* xp = (const float4*)(Hin + (long)node * 64 + c * 32 + q * 8);
            f0 = xp[0];
            f1 = xp[1];
        }
        uint4 u;
        u.x = bpack(f0.x, f0.y);
        u.y = bpack(f0.z, f0.w);
        u.z = bpack(f1.x, f1.y);
        u.w = bpack(f1.z, f1.w);
        afrag[c] = __builtin_bit_cast(short8, u);
    }
#pragma unroll
    for (int t = 0; t < 3; ++t) {
        f32x4 acc = {0.f, 0.f, 0.f, 0.f};
        acc = __builtin_amdgcn_mfma_f32_16x16x32_bf16(afrag[0], bfrag[0][t], acc, 0, 0, 0);
        acc = __builtin_amdgcn_mfma_f32_16x16x32_bf16(afrag[1], bfrag[1][t], acc, 0, 0, 0);
        int col = t * 16 + ln;
        if (col < DOUT) {
            float bv = bf[col];
#pragma unroll
            for (int r = 0; r < 4; ++r) {
                int nd = base + wv * 16 + q * 4 + r;
                if (nd < NN) OUT[(long)nd * DOUT + col] = acc[r] + bv;
            }
        }
    }
}

// ----------------------------------------------------------------
extern "C" void kernel_launch(void* const* d_in, const int* in_sizes, int n_in,
                              void* d_out, int out_size, void* d_ws, size_t ws_size,
                              hipStream_t stream) {
    const float* x    = (const float*)d_in[0];
    const int*   ei   = (const int*)d_in[1];
    const int*   srcI = ei;
    const int*   dstI = ei + EE;
    const float* W0   = (const float*)d_in[2];
    const float* b0   = (const float*)d_in[3];
    const float* W1   = (const float*)d_in[4];
    const float* b1   = (const float*)d_in[5];
    const float* W2   = (const float*)d_in[6];
    const float* b2   = (const float*)d_in[7];
    const float* ln0g = (const float*)d_in[8];
    const float* ln0b = (const float*)d_in[9];
    const float* ln1g = (const float*)d_in[10];
    const float* ln1b = (const float*)d_in[11];
    const float* mpW0 = (const float*)d_in[12];
    const float* mpb0 = (const float*)d_in[13];
    const float* mpW1 = (const float*)d_in[14];
    const float* mpb1 = (const float*)d_in[15];
    float* out = (float*)d_out;

    char* ws = (char*)d_ws;
    float*    dinv      = (float*)   (ws + 0);                      // 400 KB
    int*      bucketCur = (int*)     (ws + 512l * 1024);
    float*    Wf        = (float*)   (ws + 640l * 1024);
    float*    bfv       = (float*)   (ws + 768l * 1024);
    unsigned* bE        = (unsigned*)(ws + 1024l * 1024);           // 391*8192*4 = 12.8 MB
    unsigned* bufA      = (unsigned*)(ws + 16l * 1024 * 1024);      // bf16 H' (P-order) 12.8 MB
    float*    bufB      = (float*)   (ws + 32l * 1024 * 1024);      // f32 hidden (P-order) 25.6 MB

    const int gemmBlocks = (NN + 63) / 64;     // 1563

    binit_k<<<2, 256, 0, stream>>>(bucketCur);
    bucket_k<<<TBLK, 512, 0, stream>>>(srcI, dstI, bucketCur, bE);
    hist_k<<<NBUCK, 256, 0, stream>>>(bucketCur, bE, dinv);
    fuse_k<<<1, 256, 0, stream>>>(mpW0, mpb0, mpW1, mpb1, Wf, bfv);

    // layer 0
    gemm_mfma<128, 0><<<gemmBlocks, 256, 0, stream>>>(x, W0, dinv, bufA);
    aggb_k<<<NBUCK, 512, 0, stream>>>(bucketCur, bE, dinv, (const uint2*)bufA,
                                      b0, ln0g, ln0b, (float4*)bufB, 1);
    // layer 1
    gemm_mfma<64, 1><<<gemmBlocks, 256, 0, stream>>>(bufB, W1, dinv, bufA);
    aggb_k<<<NBUCK, 512, 0, stream>>>(bucketCur, bE, dinv, (const uint2*)bufA,
                                      b1, ln1g, ln1b, (float4*)bufB, 1);
    // layer 2 (no LN) then fused MLP head via MFMA
    gemm_mfma<64, 1><<<gemmBlocks, 256, 0, stream>>>(bufB, W2, dinv, bufA);
    aggb_k<<<NBUCK, 512, 0, stream>>>(bucketCur, bE, dinv, (const uint2*)bufA,
                                      b2, ln0g, ln0b, (float4*)bufB, 0);
    mlp_mfma<<<gemmBlocks, 256, 0, stream>>>(bufB, Wf, bfv, out);
}

// Round 6
// 400.012 us; speedup vs baseline: 5.7443x; 5.7383x over previous
//
#include <hip/hip_runtime.h>
#include <hip/hip_bf16.h>

#define NN 100000
#define EE 1600000
#define DOUT 40
#define LN_EPS 1e-5f
#define NBUCK 391  // buckets of 256 dst nodes
#define TILE 2048
#define TBLK 782   // ceil(EE/TILE)
#define BCAP 8192  // per-bucket capacity (expected 4092 +- 64)

typedef __attribute__((ext_vector_type(8))) short short8;   // 8 bf16 = 4 VGPRs
typedef __attribute__((ext_vector_type(4))) float f32x4;    // MFMA acc

// ---------------------------------------------------------------- bf16 helpers (RNE pack)
__device__ __forceinline__ float blo(unsigned u) { return __uint_as_float(u << 16); }
__device__ __forceinline__ float bhi(unsigned u) { return __uint_as_float(u & 0xffff0000u); }
__device__ __forceinline__ unsigned bpack(float lo, float hi) {
    unsigned a = __float_as_uint(lo);
    unsigned b = __float_as_uint(hi);
    a = (a + 0x7fffu + ((a >> 16) & 1u)) >> 16;
    b = (b + 0x7fffu + ((b >> 16) & 1u)) & 0xffff0000u;
    return (a & 0xffffu) | b;
}

// ---------------------------------------------------------------- bucket build
__global__ void binit_k(int* __restrict__ bucketCur) {
    int b = blockIdx.x * 256 + threadIdx.x;
    if (b < NBUCK) bucketCur[b] = b * BCAP;
}

// 782 blocks x 512 threads x 4 edges. Pass 1: per-wave LDS histogram.
// One global atomic per nonzero bucket per block. Pass 2: scatter into
// fixed-capacity bucket regions, per-wave sub-chunks (contiguous writes).
__global__ __launch_bounds__(512, 8) void bucket_k(const int* __restrict__ src,
                                                   const int* __restrict__ dst,
                                                   int* __restrict__ bucketCur,
                                                   unsigned* __restrict__ bE) {
    __shared__ int cnt[8][NBUCK];
    __shared__ int basew[8][NBUCK];
    int tid = threadIdx.x;
    int wv = tid >> 6;
    for (int i = tid; i < 8 * NBUCK; i += 512) ((int*)cnt)[i] = 0;
    __syncthreads();
    long e0 = (long)blockIdx.x * TILE;
    int d[4];
#pragma unroll
    for (int i = 0; i < 4; ++i) {
        long e = e0 + tid + i * 512;
        d[i] = (e < EE) ? dst[e] : -1;
    }
#pragma unroll
    for (int i = 0; i < 4; ++i) {
        if (d[i] >= 0) atomicAdd(&cnt[wv][d[i] >> 8], 1);
    }
    __syncthreads();
    for (int b = tid; b < NBUCK; b += 512) {
        int c[8];
        int tot = 0;
#pragma unroll
        for (int w = 0; w < 8; ++w) { c[w] = cnt[w][b]; tot += c[w]; }
        int base = tot ? atomicAdd(&bucketCur[b], tot) : 0;
        int run = base;
#pragma unroll
        for (int w = 0; w < 8; ++w) { basew[w][b] = run; run += c[w]; cnt[w][b] = 0; }
    }
    __syncthreads();
#pragma unroll
    for (int i = 0; i < 4; ++i) {
        if (d[i] >= 0) {
            long e = e0 + tid + i * 512;
            int b = d[i] >> 8;
            int pos = basew[wv][b] + atomicAdd(&cnt[wv][b], 1);
            bE[pos] = (unsigned)src[e] | ((unsigned)(d[i] & 255) << 24);
        }
    }
}

// ---------------------------------------------------------------- bucket -> exact CSR + degI + cursor + dinv
// One block per bucket. Bucket prefix computed in-block via LDS scan of
// exact bucket totals (bucketCur[b] - b*BCAP). Per-node degrees via a
// 256-entry LDS histogram; CSR writes stay in one ~16KB window.
__global__ __launch_bounds__(512, 4) void reorder2_k(const int* __restrict__ bucketCur,
                                                     const unsigned* __restrict__ bE,
                                                     int* __restrict__ csrSrc,
                                                     int* __restrict__ degI,
                                                     int* __restrict__ cursor,
                                                     float* __restrict__ dinv) {
    __shared__ int sScan[512];
    __shared__ int sHist[256];
    __shared__ int sPre[256];
    __shared__ int sStart[256];
    int tid = threadIdx.x;
    int b = blockIdx.x;
    // --- exclusive prefix of bucket totals (391 values, 512-wide scan)
    int c = (tid < NBUCK) ? (bucketCur[tid] - tid * BCAP) : 0;
    sScan[tid] = c;
    __syncthreads();
    for (int off = 1; off < 512; off <<= 1) {
        int t = (tid >= off) ? sScan[tid - off] : 0;
        __syncthreads();
        sScan[tid] += t;
        __syncthreads();
    }
    int bbase = (b == 0) ? 0 : sScan[b - 1];   // LDS broadcast
    // --- per-node histogram of this bucket
    if (tid < 256) sHist[tid] = 0;
    __syncthreads();
    int start = b * BCAP;
    int end = bucketCur[b];
    for (int e = start + tid; e < end; e += 512) {
        unsigned v = bE[e];
        atomicAdd(&sHist[v >> 24], 1);
    }
    __syncthreads();
    // --- inclusive scan over 256 node counts
    if (tid < 256) sPre[tid] = sHist[tid];
    __syncthreads();
    for (int off = 1; off < 256; off <<= 1) {
        int t = (tid >= off && tid < 256) ? sPre[tid - off] : 0;
        __syncthreads();
        if (tid < 256) sPre[tid] += t;
        __syncthreads();
    }
    if (tid < 256) {
        int h = sHist[tid];
        int excl = sPre[tid] - h;
        int st = bbase + excl;
        sStart[tid] = st;
        int nd = (b << 8) + tid;
        if (nd < NN) {
            degI[nd] = h;
            cursor[nd] = st;
            dinv[nd] = rsqrtf((float)h + 1.0f);
        }
    }
    __syncthreads();
    // --- scatter into exact CSR
    for (int e = start + tid; e < end; e += 512) {
        unsigned v = bE[e];
        int pos = atomicAdd(&sStart[v >> 24], 1);
        csrSrc[pos] = (int)(v & 0xFFFFFFu);
    }
}

// ---------------------------------------------------------------- MFMA GEMM: H' = bf16((X@W)*dinv)
template <int K>
__global__ __launch_bounds__(256, 2) void gemm_mfma(const float* __restrict__ X,
                                                    const float* __restrict__ W,
                                                    const float* __restrict__ dinv,
                                                    unsigned* __restrict__ H) {
    constexpr int C = K / 32;
    __shared__ unsigned short sW16[K * 66];
    __shared__ float sD[64 * 65];
    int tid = threadIdx.x;
    for (int i = tid; i < K * 64; i += 256) {
        int k = i >> 6, n = i & 63;
        sW16[k * 66 + n] = (unsigned short)(bpack(W[i], 0.f) & 0xffffu);
    }
    __syncthreads();
    int wv = tid >> 6, lane = tid & 63;
    int q = lane >> 4, ln = lane & 15;
    short8 bfrag[C][4];
#pragma unroll
    for (int c = 0; c < C; ++c) {
#pragma unroll
        for (int t = 0; t < 4; ++t) {
            int kb = (c * 32 + q * 8) * 66 + t * 16 + ln;
            unsigned u0 = (unsigned)sW16[kb]       | ((unsigned)sW16[kb + 66]  << 16);
            unsigned u1 = (unsigned)sW16[kb + 132] | ((unsigned)sW16[kb + 198] << 16);
            unsigned u2 = (unsigned)sW16[kb + 264] | ((unsigned)sW16[kb + 330] << 16);
            unsigned u3 = (unsigned)sW16[kb + 396] | ((unsigned)sW16[kb + 462] << 16);
            uint4 u = make_uint4(u0, u1, u2, u3);
            bfrag[c][t] = __builtin_bit_cast(short8, u);
        }
    }
    int base = blockIdx.x * 64;
    int node = base + wv * 16 + ln;
    bool ok = node < NN;
    short8 afrag[C];
#pragma unroll
    for (int c = 0; c < C; ++c) {
        float4 f0 = make_float4(0.f, 0.f, 0.f, 0.f);
        float4 f1 = make_float4(0.f, 0.f, 0.f, 0.f);
        if (ok) {
            const float4* xp = (const float4*)(X + (long)node * K + c * 32 + q * 8);
            f0 = xp[0];
            f1 = xp[1];
        }
        uint4 u;
        u.x = bpack(f0.x, f0.y);
        u.y = bpack(f0.z, f0.w);
        u.z = bpack(f1.x, f1.y);
        u.w = bpack(f1.z, f1.w);
        afrag[c] = __builtin_bit_cast(short8, u);
    }
#pragma unroll
    for (int t = 0; t < 4; ++t) {
        f32x4 acc = {0.f, 0.f, 0.f, 0.f};
#pragma unroll
        for (int c = 0; c < C; ++c)
            acc = __builtin_amdgcn_mfma_f32_16x16x32_bf16(afrag[c], bfrag[c][t], acc, 0, 0, 0);
#pragma unroll
        for (int r = 0; r < 4; ++r)
            sD[(wv * 16 + q * 4 + r) * 65 + t * 16 + ln] = acc[r];
    }
    __syncthreads();
    for (int i = tid; i < 64 * 32; i += 256) {
        int row = i >> 5, c2 = i & 31;
        int nd = base + row;
        if (nd < NN) {
            float di = dinv[nd];
            float lo = sD[row * 65 + c2 * 2] * di;
            float hi = sD[row * 65 + c2 * 2 + 1] * di;
            H[nd * 32 + c2] = bpack(lo, hi);
        }
    }
}

// ---------------------------------------------------------------- aggregate + bias + relu + optional LN
// Register accumulation (round-1 structure).  All gather indices are 32-bit
// unsigned so loads use the SGPR-base + 32-bit-voffset (saddr) form instead
// of 64-bit per-lane address arithmetic (~7 VALU/load -> ~2).  4-edge unroll.
__global__ __launch_bounds__(256, 4) void agg_k(
        const int* __restrict__ cursor, const int* __restrict__ degI,
        const int* __restrict__ csrSrc, const float* __restrict__ dinv,
        const uint2* __restrict__ H2, const float4* __restrict__ bias4,
        const float4* __restrict__ g4, const float4* __restrict__ beta4,
        float4* __restrict__ OUT4, int doLN) {
    int tid = threadIdx.x;
    int w = tid >> 6, lane = tid & 63;
    int g = lane >> 4;
    unsigned f = (unsigned)(lane & 15);
    unsigned node = (unsigned)(blockIdx.x * 4 + w);
    int start = cursor[node];
    int end = start + degI[node];
    float ax = 0.f, ay = 0.f, az = 0.f, aw = 0.f;
    float bx = 0.f, by = 0.f, bz = 0.f, bw = 0.f;
    int e = start + g;
    for (; e + 12 < end; e += 16) {
        unsigned s0 = (unsigned)csrSrc[(unsigned)e];
        unsigned s1 = (unsigned)csrSrc[(unsigned)(e + 4)];
        unsigned s2 = (unsigned)csrSrc[(unsigned)(e + 8)];
        unsigned s3 = (unsigned)csrSrc[(unsigned)(e + 12)];
        uint2 q0 = H2[s0 * 16u + f];
        uint2 q1 = H2[s1 * 16u + f];
        uint2 q2 = H2[s2 * 16u + f];
        uint2 q3 = H2[s3 * 16u + f];
        ax += blo(q0.x); ay += bhi(q0.x); az += blo(q0.y); aw += bhi(q0.y);
        bx += blo(q1.x); by += bhi(q1.x); bz += blo(q1.y); bw += bhi(q1.y);
        ax += blo(q2.x); ay += bhi(q2.x); az += blo(q2.y); aw += bhi(q2.y);
        bx += blo(q3.x); by += bhi(q3.x); bz += blo(q3.y); bw += bhi(q3.y);
    }
    for (; e < end; e += 4) {
        uint2 q0 = H2[(unsigned)csrSrc[(unsigned)e] * 16u + f];
        ax += blo(q0.x); ay += bhi(q0.x); az += blo(q0.y); aw += bhi(q0.y);
    }
    ax += bx; ay += by; az += bz; aw += bw;
    ax += __shfl_xor(ax, 16); ay += __shfl_xor(ay, 16);
    az += __shfl_xor(az, 16); aw += __shfl_xor(aw, 16);
    ax += __shfl_xor(ax, 32); ay += __shfl_xor(ay, 32);
    az += __shfl_xor(az, 32); aw += __shfl_xor(aw, 32);
    float di = dinv[node];
    uint2 qs = H2[node * 16u + f];
    float4 bb = bias4[f];
    float vx = fmaxf((ax + blo(qs.x)) * di + bb.x, 0.f);
    float vy = fmaxf((ay + bhi(qs.x)) * di + bb.y, 0.f);
    float vz = fmaxf((az + blo(qs.y)) * di + bb.z, 0.f);
    float vw = fmaxf((aw + bhi(qs.y)) * di + bb.w, 0.f);
    if (doLN) {
        float s = vx + vy + vz + vw;
        s += __shfl_xor(s, 1); s += __shfl_xor(s, 2);
        s += __shfl_xor(s, 4); s += __shfl_xor(s, 8);
        float mu = s * (1.f / 64.f);
        vx -= mu; vy -= mu; vz -= mu; vw -= mu;
        float vs = vx * vx + vy * vy + vz * vz + vw * vw;
        vs += __shfl_xor(vs, 1); vs += __shfl_xor(vs, 2);
        vs += __shfl_xor(vs, 4); vs += __shfl_xor(vs, 8);
        float inv = rsqrtf(vs * (1.f / 64.f) + LN_EPS);
        float4 gg = g4[f];
        float4 tt = beta4[f];
        vx = vx * inv * gg.x + tt.x;
        vy = vy * inv * gg.y + tt.y;
        vz = vz * inv * gg.z + tt.z;
        vw = vw * inv * gg.w + tt.w;
    }
    if (g == 0) OUT4[node * 16u + f] = make_float4(vx, vy, vz, vw);
}

// ---------------------------------------------------------------- fuse the two head linears
__global__ void fuse_k(const float* __restrict__ W0, const float* __restrict__ b0,
                       const float* __restrict__ W1, const float* __restrict__ b1,
                       float* __restrict__ Wf, float* __restrict__ bf) {
    int tid = threadIdx.x;
    for (int i = tid; i < 64 * 48; i += 256) {
        int k = i / 48, n = i % 48;
        float acc = 0.f;
        if (n < DOUT) {
            for (int j = 0; j < 64; ++j) acc = fmaf(W0[k * 64 + j], W1[j * DOUT + n], acc);
        }
        Wf[i] = acc;
    }
    for (int n = tid; n < 48; n += 256) {
        float acc = 0.f;
        if (n < DOUT) {
            acc = b1[n];
            for (int j = 0; j < 64; ++j) acc = fmaf(b0[j], W1[j * DOUT + n], acc);
        }
        bf[n] = acc;
    }
}

// ---------------------------------------------------------------- MLP head via MFMA: OUT = Hin @ Wf + bf
__global__ __launch_bounds__(256, 2) void mlp_mfma(const float* __restrict__ Hin,
                                                   const float* __restrict__ Wf,
                                                   const float* __restrict__ bf,
                                                   float* __restrict__ OUT) {
    __shared__ unsigned short sW16[64 * 50];
    int tid = threadIdx.x;
    for (int i = tid; i < 64 * 48; i += 256) {
        int k = i / 48, n = i % 48;
        sW16[k * 50 + n] = (unsigned short)(bpack(Wf[i], 0.f) & 0xffffu);
    }
    __syncthreads();
    int wv = tid >> 6, lane = tid & 63;
    int q = lane >> 4, ln = lane & 15;
    short8 bfrag[2][3];
#pragma unroll
    for (int c = 0; c < 2; ++c) {
#pragma unroll
        for (int t = 0; t < 3; ++t) {
            int kb = (c * 32 + q * 8) * 50 + t * 16 + ln;
            unsigned u0 = (unsigned)sW16[kb]       | ((unsigned)sW16[kb + 50]  << 16);
            unsigned u1 = (unsigned)sW16[kb + 100] | ((unsigned)sW16[kb + 150] << 16);
            unsigned u2 = (unsigned)sW16[kb + 200] | ((unsigned)sW16[kb + 250] << 16);
            unsigned u3 = (unsigned)sW16[kb + 300] | ((unsigned)sW16[kb + 350] << 16);
            uint4 u = make_uint4(u0, u1, u2, u3);
            bfrag[c][t] = __builtin_bit_cast(short8, u);
        }
    }
    int base = blockIdx.x * 64;
    int node = base + wv * 16 + ln;
    bool ok = node < NN;
    short8 afrag[2];
#pragma unroll
    for (int c = 0; c < 2; ++c) {
        float4 f0 = make_float4(0.f, 0.f, 0.f, 0.f);
        float4 f1 = make_float4(0.f, 0.f, 0.f, 0.f);
        if (ok) {
            const float4* xp = (const float4*)(Hin + (long)node * 64 + c * 32 + q * 8);
            f0 = xp[0];
            f1 = xp[1];
        }
        uint4 u;
        u.x = bpack(f0.x, f0.y);
        u.y = bpack(f0.z, f0.w);
        u.z = bpack(f1.x, f1.y);
        u.w = bpack(f1.z, f1.w);
        afrag[c] = __builtin_bit_cast(short8, u);
    }
#pragma unroll
    for (int t = 0; t < 3; ++t) {
        f32x4 acc = {0.f, 0.f, 0.f, 0.f};
        acc = __builtin_amdgcn_mfma_f32_16x16x32_bf16(afrag[0], bfrag[0][t], acc, 0, 0, 0);
        acc = __builtin_amdgcn_mfma_f32_16x16x32_bf16(afrag[1], bfrag[1][t], acc, 0, 0, 0);
        int col = t * 16 + ln;
        if (col < DOUT) {
            float bv = bf[col];
#pragma unroll
            for (int r = 0; r < 4; ++r) {
                int nd = base + wv * 16 + q * 4 + r;
                if (nd < NN) OUT[(long)nd * DOUT + col] = acc[r] + bv;
            }
        }
    }
}

// ----------------------------------------------------------------
extern "C" void kernel_launch(void* const* d_in, const int* in_sizes, int n_in,
                              void* d_out, int out_size, void* d_ws, size_t ws_size,
                              hipStream_t stream) {
    const float* x    = (const float*)d_in[0];
    const int*   ei   = (const int*)d_in[1];
    const int*   srcI = ei;
    const int*   dstI = ei + EE;
    const float* W0   = (const float*)d_in[2];
    const float* b0   = (const float*)d_in[3];
    const float* W1   = (const float*)d_in[4];
    const float* b1   = (const float*)d_in[5];
    const float* W2   = (const float*)d_in[6];
    const float* b2   = (const float*)d_in[7];
    const float* ln0g = (const float*)d_in[8];
    const float* ln0b = (const float*)d_in[9];
    const float* ln1g = (const float*)d_in[10];
    const float* ln1b = (const float*)d_in[11];
    const float* mpW0 = (const float*)d_in[12];
    const float* mpb0 = (const float*)d_in[13];
    const float* mpW1 = (const float*)d_in[14];
    const float* mpb1 = (const float*)d_in[15];
    float* out = (float*)d_out;

    char* ws = (char*)d_ws;
    float*    dinv      = (float*)   (ws + 0);                      // 400 KB
    int*      degI      = (int*)     (ws + 512l * 1024);            // 400 KB
    int*      cursor    = (int*)     (ws + 1024l * 1024);           // 400 KB
    int*      bucketCur = (int*)     (ws + 1600l * 1024);
    float*    Wf        = (float*)   (ws + 1792l * 1024);
    float*    bfv       = (float*)   (ws + 1984l * 1024);
    unsigned* bE        = (unsigned*)(ws + 2048l * 1024);           // 391*8192*4 = 12.8 MB
    int*      csrSrc    = (int*)     (ws + 15l * 1024 * 1024);      // 6.4 MB
    unsigned* bufA      = (unsigned*)(ws + 22l * 1024 * 1024);      // bf16 H' 12.8 MB
    float*    bufB      = (float*)   (ws + 35l * 1024 * 1024);      // f32 hidden 25.6 MB

    const int aggBlocks  = NN / 4;             // 25000 exact
    const int gemmBlocks = (NN + 63) / 64;     // 1563

    binit_k<<<2, 256, 0, stream>>>(bucketCur);
    bucket_k<<<TBLK, 512, 0, stream>>>(srcI, dstI, bucketCur, bE);
    reorder2_k<<<NBUCK, 512, 0, stream>>>(bucketCur, bE, csrSrc, degI, cursor, dinv);
    fuse_k<<<1, 256, 0, stream>>>(mpW0, mpb0, mpW1, mpb1, Wf, bfv);

    // layer 0
    gemm_mfma<128><<<gemmBlocks, 256, 0, stream>>>(x, W0, dinv, bufA);
    agg_k<<<aggBlocks, 256, 0, stream>>>(cursor, degI, csrSrc, dinv, (const uint2*)bufA,
                                         (const float4*)b0, (const float4*)ln0g,
                                         (const float4*)ln0b, (float4*)bufB, 1);
    // layer 1
    gemm_mfma<64><<<gemmBlocks, 256, 0, stream>>>(bufB, W1, dinv, bufA);
    agg_k<<<aggBlocks, 256, 0, stream>>>(cursor, degI, csrSrc, dinv, (const uint2*)bufA,
                                         (const float4*)b1, (const float4*)ln1g,
                                         (const float4*)ln1b, (float4*)bufB, 1);
    // layer 2 (no LN) then fused MLP head via MFMA
    gemm_mfma<64><<<gemmBlocks, 256, 0, stream>>>(bufB, W2, dinv, bufA);
    agg_k<<<aggBlocks, 256, 0, stream>>>(cursor, degI, csrSrc, dinv, (const uint2*)bufA,
                                         (const float4*)b2, (const float4*)ln0g,
                                         (const float4*)ln0b, (float4*)bufB, 0);
    mlp_mfma<<<gemmBlocks, 256, 0, stream>>>(bufB, Wf, bfv, out);
}

// Round 7
// 372.970 us; speedup vs baseline: 6.1607x; 1.0725x over previous
//
#include <hip/hip_runtime.h>
#include <hip/hip_bf16.h>

#define NN 100000
#define EE 1600000
#define DOUT 40
#define LN_EPS 1e-5f
#define NBUCK 391  // buckets of 256 dst nodes
#define TILE 2048
#define TBLK 782   // ceil(EE/TILE)
#define BCAP 8192  // per-bucket capacity (expected 4092 +- 64)

typedef __attribute__((ext_vector_type(8))) short short8;   // 8 bf16 = 4 VGPRs
typedef __attribute__((ext_vector_type(4))) float f32x4;    // MFMA acc

// ---------------------------------------------------------------- bf16 helpers (RNE pack)
__device__ __forceinline__ float blo(unsigned u) { return __uint_as_float(u << 16); }
__device__ __forceinline__ float bhi(unsigned u) { return __uint_as_float(u & 0xffff0000u); }
__device__ __forceinline__ unsigned bpack(float lo, float hi) {
    unsigned a = __float_as_uint(lo);
    unsigned b = __float_as_uint(hi);
    a = (a + 0x7fffu + ((a >> 16) & 1u)) >> 16;
    b = (b + 0x7fffu + ((b >> 16) & 1u)) & 0xffff0000u;
    return (a & 0xffffu) | b;
}

// ---------------------------------------------------------------- bucket build
__global__ void binit_k(int* __restrict__ bucketCur) {
    int b = blockIdx.x * 256 + threadIdx.x;
    if (b < NBUCK) bucketCur[b] = b * BCAP;
}

// 782 blocks x 512 threads x 4 edges. Pass 1: per-wave LDS histogram.
// One global atomic per nonzero bucket per block. Pass 2: scatter into
// fixed-capacity bucket regions, per-wave sub-chunks (contiguous writes).
__global__ __launch_bounds__(512, 8) void bucket_k(const int* __restrict__ src,
                                                   const int* __restrict__ dst,
                                                   int* __restrict__ bucketCur,
                                                   unsigned* __restrict__ bE) {
    __shared__ int cnt[8][NBUCK];
    __shared__ int basew[8][NBUCK];
    int tid = threadIdx.x;
    int wv = tid >> 6;
    for (int i = tid; i < 8 * NBUCK; i += 512) ((int*)cnt)[i] = 0;
    __syncthreads();
    long e0 = (long)blockIdx.x * TILE;
    int d[4];
#pragma unroll
    for (int i = 0; i < 4; ++i) {
        long e = e0 + tid + i * 512;
        d[i] = (e < EE) ? dst[e] : -1;
    }
#pragma unroll
    for (int i = 0; i < 4; ++i) {
        if (d[i] >= 0) atomicAdd(&cnt[wv][d[i] >> 8], 1);
    }
    __syncthreads();
    for (int b = tid; b < NBUCK; b += 512) {
        int c[8];
        int tot = 0;
#pragma unroll
        for (int w = 0; w < 8; ++w) { c[w] = cnt[w][b]; tot += c[w]; }
        int base = tot ? atomicAdd(&bucketCur[b], tot) : 0;
        int run = base;
#pragma unroll
        for (int w = 0; w < 8; ++w) { basew[w][b] = run; run += c[w]; cnt[w][b] = 0; }
    }
    __syncthreads();
#pragma unroll
    for (int i = 0; i < 4; ++i) {
        if (d[i] >= 0) {
            long e = e0 + tid + i * 512;
            int b = d[i] >> 8;
            int pos = basew[wv][b] + atomicAdd(&cnt[wv][b], 1);
            bE[pos] = (unsigned)src[e] | ((unsigned)(d[i] & 255) << 24);
        }
    }
}

// ---------------------------------------------------------------- bucket -> exact CSR + degI + cursor + dinv
__global__ __launch_bounds__(512, 4) void reorder2_k(const int* __restrict__ bucketCur,
                                                     const unsigned* __restrict__ bE,
                                                     int* __restrict__ csrSrc,
                                                     int* __restrict__ degI,
                                                     int* __restrict__ cursor,
                                                     float* __restrict__ dinv) {
    __shared__ int sScan[512];
    __shared__ int sHist[256];
    __shared__ int sPre[256];
    __shared__ int sStart[256];
    int tid = threadIdx.x;
    int b = blockIdx.x;
    // --- exclusive prefix of bucket totals (391 values, 512-wide scan)
    int c = (tid < NBUCK) ? (bucketCur[tid] - tid * BCAP) : 0;
    sScan[tid] = c;
    __syncthreads();
    for (int off = 1; off < 512; off <<= 1) {
        int t = (tid >= off) ? sScan[tid - off] : 0;
        __syncthreads();
        sScan[tid] += t;
        __syncthreads();
    }
    int bbase = (b == 0) ? 0 : sScan[b - 1];   // LDS broadcast
    // --- per-node histogram of this bucket
    if (tid < 256) sHist[tid] = 0;
    __syncthreads();
    int start = b * BCAP;
    int end = bucketCur[b];
    for (int e = start + tid; e < end; e += 512) {
        unsigned v = bE[e];
        atomicAdd(&sHist[v >> 24], 1);
    }
    __syncthreads();
    // --- inclusive scan over 256 node counts
    if (tid < 256) sPre[tid] = sHist[tid];
    __syncthreads();
    for (int off = 1; off < 256; off <<= 1) {
        int t = (tid >= off && tid < 256) ? sPre[tid - off] : 0;
        __syncthreads();
        if (tid < 256) sPre[tid] += t;
        __syncthreads();
    }
    if (tid < 256) {
        int h = sHist[tid];
        int excl = sPre[tid] - h;
        int st = bbase + excl;
        sStart[tid] = st;
        int nd = (b << 8) + tid;
        if (nd < NN) {
            degI[nd] = h;
            cursor[nd] = st;
            dinv[nd] = rsqrtf((float)h + 1.0f);
        }
    }
    __syncthreads();
    // --- scatter into exact CSR
    for (int e = start + tid; e < end; e += 512) {
        unsigned v = bE[e];
        int pos = atomicAdd(&sStart[v >> 24], 1);
        csrSrc[pos] = (int)(v & 0xFFFFFFu);
    }
}

// ---------------------------------------------------------------- MFMA GEMM: H' = bf16((X@W)*dinv)
template <int K>
__global__ __launch_bounds__(256, 2) void gemm_mfma(const float* __restrict__ X,
                                                    const float* __restrict__ W,
                                                    const float* __restrict__ dinv,
                                                    unsigned* __restrict__ H) {
    constexpr int C = K / 32;
    __shared__ unsigned short sW16[K * 66];
    __shared__ float sD[64 * 65];
    int tid = threadIdx.x;
    for (int i = tid; i < K * 64; i += 256) {
        int k = i >> 6, n = i & 63;
        sW16[k * 66 + n] = (unsigned short)(bpack(W[i], 0.f) & 0xffffu);
    }
    __syncthreads();
    int wv = tid >> 6, lane = tid & 63;
    int q = lane >> 4, ln = lane & 15;
    short8 bfrag[C][4];
#pragma unroll
    for (int c = 0; c < C; ++c) {
#pragma unroll
        for (int t = 0; t < 4; ++t) {
            int kb = (c * 32 + q * 8) * 66 + t * 16 + ln;
            unsigned u0 = (unsigned)sW16[kb]       | ((unsigned)sW16[kb + 66]  << 16);
            unsigned u1 = (unsigned)sW16[kb + 132] | ((unsigned)sW16[kb + 198] << 16);
            unsigned u2 = (unsigned)sW16[kb + 264] | ((unsigned)sW16[kb + 330] << 16);
            unsigned u3 = (unsigned)sW16[kb + 396] | ((unsigned)sW16[kb + 462] << 16);
            uint4 u = make_uint4(u0, u1, u2, u3);
            bfrag[c][t] = __builtin_bit_cast(short8, u);
        }
    }
    int base = blockIdx.x * 64;
    int node = base + wv * 16 + ln;
    bool ok = node < NN;
    short8 afrag[C];
#pragma unroll
    for (int c = 0; c < C; ++c) {
        float4 f0 = make_float4(0.f, 0.f, 0.f, 0.f);
        float4 f1 = make_float4(0.f, 0.f, 0.f, 0.f);
        if (ok) {
            const float4* xp = (const float4*)(X + (long)node * K + c * 32 + q * 8);
            f0 = xp[0];
            f1 = xp[1];
        }
        uint4 u;
        u.x = bpack(f0.x, f0.y);
        u.y = bpack(f0.z, f0.w);
        u.z = bpack(f1.x, f1.y);
        u.w = bpack(f1.z, f1.w);
        afrag[c] = __builtin_bit_cast(short8, u);
    }
#pragma unroll
    for (int t = 0; t < 4; ++t) {
        f32x4 acc = {0.f, 0.f, 0.f, 0.f};
#pragma unroll
        for (int c = 0; c < C; ++c)
            acc = __builtin_amdgcn_mfma_f32_16x16x32_bf16(afrag[c], bfrag[c][t], acc, 0, 0, 0);
#pragma unroll
        for (int r = 0; r < 4; ++r)
            sD[(wv * 16 + q * 4 + r) * 65 + t * 16 + ln] = acc[r];
    }
    __syncthreads();
    for (int i = tid; i < 64 * 32; i += 256) {
        int row = i >> 5, c2 = i & 31;
        int nd = base + row;
        if (nd < NN) {
            float di = dinv[nd];
            float lo = sD[row * 65 + c2 * 2] * di;
            float hi = sD[row * 65 + c2 * 2 + 1] * di;
            H[nd * 32 + c2] = bpack(lo, hi);
        }
    }
}

// ---------------------------------------------------------------- aggregate + bias + relu + optional LN
// Latency-restructured: ONE coalesced csrSrc load covers the whole node's
// edge list (deg<=64 w.h.p.); per-round source indices come from __shfl of
// that register, so all gathers are independent of each other (the old code
// ran a serial csr-load -> gather chain per 4 edges: Poisson(16) degrees
// never reached the unrolled path).  2-round software pipeline.
__global__ __launch_bounds__(256, 4) void agg_k(
        const int* __restrict__ cursor, const int* __restrict__ degI,
        const int* __restrict__ csrSrc, const float* __restrict__ dinv,
        const uint2* __restrict__ H2, const float4* __restrict__ bias4,
        const float4* __restrict__ g4, const float4* __restrict__ beta4,
        float4* __restrict__ OUT4, int doLN) {
    int tid = threadIdx.x;
    int w = tid >> 6, lane = tid & 63;
    int g = lane >> 4;
    unsigned f = (unsigned)(lane & 15);
    unsigned node = (unsigned)(blockIdx.x * 4 + w);
    int start = cursor[node];
    int deg = degI[node];
    // one coalesced index load for the whole wave (edges 0..min(deg,64))
    int myIdx = 0;
    if (lane < deg) myIdx = csrSrc[(unsigned)(start + lane)];
    float ax = 0.f, ay = 0.f, az = 0.f, aw = 0.f;
    float bx = 0.f, by = 0.f, bz = 0.f, bw = 0.f;
    int R = (deg + 3) >> 2;          // rounds of 4 edges (group g takes edge 4r+g)
    if (R > 16) R = 16;
    int r = 0;
    for (; r + 1 < R; r += 2) {
        int e0 = r * 4 + g;
        int e1 = e0 + 4;
        unsigned s0 = (unsigned)__shfl(myIdx, e0);
        unsigned s1 = (unsigned)__shfl(myIdx, e1);
        uint2 q0 = make_uint2(0u, 0u), q1 = make_uint2(0u, 0u);
        if (e0 < deg) q0 = H2[s0 * 16u + f];
        if (e1 < deg) q1 = H2[s1 * 16u + f];
        ax += blo(q0.x); ay += bhi(q0.x); az += blo(q0.y); aw += bhi(q0.y);
        bx += blo(q1.x); by += bhi(q1.x); bz += blo(q1.y); bw += bhi(q1.y);
    }
    if (r < R) {
        int e0 = r * 4 + g;
        unsigned s0 = (unsigned)__shfl(myIdx, e0);
        uint2 q0 = make_uint2(0u, 0u);
        if (e0 < deg) q0 = H2[s0 * 16u + f];
        ax += blo(q0.x); ay += bhi(q0.x); az += blo(q0.y); aw += bhi(q0.y);
    }
    // rare deg>64 tail (Poisson(16): effectively never; correctness only)
    for (int ee = 64 + g; ee < deg; ee += 4) {
        uint2 q = H2[(unsigned)csrSrc[(unsigned)(start + ee)] * 16u + f];
        ax += blo(q.x); ay += bhi(q.x); az += blo(q.y); aw += bhi(q.y);
    }
    ax += bx; ay += by; az += bz; aw += bw;
    ax += __shfl_xor(ax, 16); ay += __shfl_xor(ay, 16);
    az += __shfl_xor(az, 16); aw += __shfl_xor(aw, 16);
    ax += __shfl_xor(ax, 32); ay += __shfl_xor(ay, 32);
    az += __shfl_xor(az, 32); aw += __shfl_xor(aw, 32);
    float di = dinv[node];
    uint2 qs = H2[node * 16u + f];
    float4 bb = bias4[f];
    float vx = fmaxf((ax + blo(qs.x)) * di + bb.x, 0.f);
    float vy = fmaxf((ay + bhi(qs.x)) * di + bb.y, 0.f);
    float vz = fmaxf((az + blo(qs.y)) * di + bb.z, 0.f);
    float vw = fmaxf((aw + bhi(qs.y)) * di + bb.w, 0.f);
    if (doLN) {
        float s = vx + vy + vz + vw;
        s += __shfl_xor(s, 1); s += __shfl_xor(s, 2);
        s += __shfl_xor(s, 4); s += __shfl_xor(s, 8);
        float mu = s * (1.f / 64.f);
        vx -= mu; vy -= mu; vz -= mu; vw -= mu;
        float vs = vx * vx + vy * vy + vz * vz + vw * vw;
        vs += __shfl_xor(vs, 1); vs += __shfl_xor(vs, 2);
        vs += __shfl_xor(vs, 4); vs += __shfl_xor(vs, 8);
        float inv = rsqrtf(vs * (1.f / 64.f) + LN_EPS);
        float4 gg = g4[f];
        float4 tt = beta4[f];
        vx = vx * inv * gg.x + tt.x;
        vy = vy * inv * gg.y + tt.y;
        vz = vz * inv * gg.z + tt.z;
        vw = vw * inv * gg.w + tt.w;
    }
    if (g == 0) OUT4[node * 16u + f] = make_float4(vx, vy, vz, vw);
}

// ---------------------------------------------------------------- fuse the two head linears
__global__ void fuse_k(const float* __restrict__ W0, const float* __restrict__ b0,
                       const float* __restrict__ W1, const float* __restrict__ b1,
                       float* __restrict__ Wf, float* __restrict__ bf) {
    int tid = threadIdx.x;
    for (int i = tid; i < 64 * 48; i += 256) {
        int k = i / 48, n = i % 48;
        float acc = 0.f;
        if (n < DOUT) {
            for (int j = 0; j < 64; ++j) acc = fmaf(W0[k * 64 + j], W1[j * DOUT + n], acc);
        }
        Wf[i] = acc;
    }
    for (int n = tid; n < 48; n += 256) {
        float acc = 0.f;
        if (n < DOUT) {
            acc = b1[n];
            for (int j = 0; j < 64; ++j) acc = fmaf(b0[j], W1[j * DOUT + n], acc);
        }
        bf[n] = acc;
    }
}

// ---------------------------------------------------------------- MLP head via MFMA: OUT = Hin @ Wf + bf
__global__ __launch_bounds__(256, 2) void mlp_mfma(const float* __restrict__ Hin,
                                                   const float* __restrict__ Wf,
                                                   const float* __restrict__ bf,
                                                   float* __restrict__ OUT) {
    __shared__ unsigned short sW16[64 * 50];
    int tid = threadIdx.x;
    for (int i = tid; i < 64 * 48; i += 256) {
        int k = i / 48, n = i % 48;
        sW16[k * 50 + n] = (unsigned short)(bpack(Wf[i], 0.f) & 0xffffu);
    }
    __syncthreads();
    int wv = tid >> 6, lane = tid & 63;
    int q = lane >> 4, ln = lane & 15;
    short8 bfrag[2][3];
#pragma unroll
    for (int c = 0; c < 2; ++c) {
#pragma unroll
        for (int t = 0; t < 3; ++t) {
            int kb = (c * 32 + q * 8) * 50 + t * 16 + ln;
            unsigned u0 = (unsigned)sW16[kb]       | ((unsigned)sW16[kb + 50]  << 16);
            unsigned u1 = (unsigned)sW16[kb + 100] | ((unsigned)sW16[kb + 150] << 16);
            unsigned u2 = (unsigned)sW16[kb + 200] | ((unsigned)sW16[kb + 250] << 16);
            unsigned u3 = (unsigned)sW16[kb + 300] | ((unsigned)sW16[kb + 350] << 16);
            uint4 u = make_uint4(u0, u1, u2, u3);
            bfrag[c][t] = __builtin_bit_cast(short8, u);
        }
    }
    int base = blockIdx.x * 64;
    int node = base + wv * 16 + ln;
    bool ok = node < NN;
    short8 afrag[2];
#pragma unroll
    for (int c = 0; c < 2; ++c) {
        float4 f0 = make_float4(0.f, 0.f, 0.f, 0.f);
        float4 f1 = make_float4(0.f, 0.f, 0.f, 0.f);
        if (ok) {
            const float4* xp = (const float4*)(Hin + (long)node * 64 + c * 32 + q * 8);
            f0 = xp[0];
            f1 = xp[1];
        }
        uint4 u;
        u.x = bpack(f0.x, f0.y);
        u.y = bpack(f0.z, f0.w);
        u.z = bpack(f1.x, f1.y);
        u.w = bpack(f1.z, f1.w);
        afrag[c] = __builtin_bit_cast(short8, u);
    }
#pragma unroll
    for (int t = 0; t < 3; ++t) {
        f32x4 acc = {0.f, 0.f, 0.f, 0.f};
        acc = __builtin_amdgcn_mfma_f32_16x16x32_bf16(afrag[0], bfrag[0][t], acc, 0, 0, 0);
        acc = __builtin_amdgcn_mfma_f32_16x16x32_bf16(afrag[1], bfrag[1][t], acc, 0, 0, 0);
        int col = t * 16 + ln;
        if (col < DOUT) {
            float bv = bf[col];
#pragma unroll
            for (int r = 0; r < 4; ++r) {
                int nd = base + wv * 16 + q * 4 + r;
                if (nd < NN) OUT[(long)nd * DOUT + col] = acc[r] + bv;
            }
        }
    }
}

// ----------------------------------------------------------------
extern "C" void kernel_launch(void* const* d_in, const int* in_sizes, int n_in,
                              void* d_out, int out_size, void* d_ws, size_t ws_size,
                              hipStream_t stream) {
    const float* x    = (const float*)d_in[0];
    const int*   ei   = (const int*)d_in[1];
    const int*   srcI = ei;
    const int*   dstI = ei + EE;
    const float* W0   = (const float*)d_in[2];
    const float* b0   = (const float*)d_in[3];
    const float* W1   = (const float*)d_in[4];
    const float* b1   = (const float*)d_in[5];
    const float* W2   = (const float*)d_in[6];
    const float* b2   = (const float*)d_in[7];
    const float* ln0g = (const float*)d_in[8];
    const float* ln0b = (const float*)d_in[9];
    const float* ln1g = (const float*)d_in[10];
    const float* ln1b = (const float*)d_in[11];
    const float* mpW0 = (const float*)d_in[12];
    const float* mpb0 = (const float*)d_in[13];
    const float* mpW1 = (const float*)d_in[14];
    const float* mpb1 = (const float*)d_in[15];
    float* out = (float*)d_out;

    char* ws = (char*)d_ws;
    float*    dinv      = (float*)   (ws + 0);                      // 400 KB
    int*      degI      = (int*)     (ws + 512l * 1024);            // 400 KB
    int*      cursor    = (int*)     (ws + 1024l * 1024);           // 400 KB
    int*      bucketCur = (int*)     (ws + 1600l * 1024);
    float*    Wf        = (float*)   (ws + 1792l * 1024);
    float*    bfv       = (float*)   (ws + 1984l * 1024);
    unsigned* bE        = (unsigned*)(ws + 2048l * 1024);           // 391*8192*4 = 12.8 MB
    int*      csrSrc    = (int*)     (ws + 15l * 1024 * 1024);      // 6.4 MB
    unsigned* bufA      = (unsigned*)(ws + 22l * 1024 * 1024);      // bf16 H' 12.8 MB
    float*    bufB      = (float*)   (ws + 35l * 1024 * 1024);      // f32 hidden 25.6 MB

    const int aggBlocks  = NN / 4;             // 25000 exact
    const int gemmBlocks = (NN + 63) / 64;     // 1563

    binit_k<<<2, 256, 0, stream>>>(bucketCur);
    bucket_k<<<TBLK, 512, 0, stream>>>(srcI, dstI, bucketCur, bE);
    reorder2_k<<<NBUCK, 512, 0, stream>>>(bucketCur, bE, csrSrc, degI, cursor, dinv);
    fuse_k<<<1, 256, 0, stream>>>(mpW0, mpb0, mpW1, mpb1, Wf, bfv);

    // layer 0
    gemm_mfma<128><<<gemmBlocks, 256, 0, stream>>>(x, W0, dinv, bufA);
    agg_k<<<aggBlocks, 256, 0, stream>>>(cursor, degI, csrSrc, dinv, (const uint2*)bufA,
                                         (const float4*)b0, (const float4*)ln0g,
                                         (const float4*)ln0b, (float4*)bufB, 1);
    // layer 1
    gemm_mfma<64><<<gemmBlocks, 256, 0, stream>>>(bufB, W1, dinv, bufA);
    agg_k<<<aggBlocks, 256, 0, stream>>>(cursor, degI, csrSrc, dinv, (const uint2*)bufA,
                                         (const float4*)b1, (const float4*)ln1g,
                                         (const float4*)ln1b, (float4*)bufB, 1);
    // layer 2 (no LN) then fused MLP head via MFMA
    gemm_mfma<64><<<gemmBlocks, 256, 0, stream>>>(bufB, W2, dinv, bufA);
    agg_k<<<aggBlocks, 256, 0, stream>>>(cursor, degI, csrSrc, dinv, (const uint2*)bufA,
                                         (const float4*)b2, (const float4*)ln0g,
                                         (const float4*)ln0b, (float4*)bufB, 0);
    mlp_mfma<<<gemmBlocks, 256, 0, stream>>>(bufB, Wf, bfv, out);
}

// Round 9
// 357.532 us; speedup vs baseline: 6.4268x; 1.0432x over previous
//
#include <hip/hip_runtime.h>
#include <hip/hip_bf16.h>

#define NN 100000
#define EE 1600000
#define DOUT 40
#define LN_EPS 1e-5f
#define NBUCK 391  // buckets of 256 dst nodes
#define TILE 2048
#define TBLK 782   // ceil(EE/TILE)
#define BCAP 8192  // per-bucket capacity (expected 4092 +- 64)

typedef __attribute__((ext_vector_type(8))) short short8;   // 8 bf16 = 4 VGPRs
typedef __attribute__((ext_vector_type(4))) float f32x4;    // MFMA acc

// ---------------------------------------------------------------- bf16 helpers (RNE pack)
__device__ __forceinline__ float blo(unsigned u) { return __uint_as_float(u << 16); }
__device__ __forceinline__ float bhi(unsigned u) { return __uint_as_float(u & 0xffff0000u); }
__device__ __forceinline__ unsigned bpack(float lo, float hi) {
    unsigned a = __float_as_uint(lo);
    unsigned b = __float_as_uint(hi);
    a = (a + 0x7fffu + ((a >> 16) & 1u)) >> 16;
    b = (b + 0x7fffu + ((b >> 16) & 1u)) & 0xffff0000u;
    return (a & 0xffffu) | b;
}

// ---------------------------------------------------------------- bucket build
__global__ void binit_k(int* __restrict__ bucketCur) {
    int b = blockIdx.x * 256 + threadIdx.x;
    if (b < NBUCK) bucketCur[b] = b * BCAP;
}

// 782 blocks x 512 threads x 4 edges. Pass 1: per-wave LDS histogram.
// One global atomic per nonzero bucket per block. Pass 2: scatter into
// fixed-capacity bucket regions, per-wave sub-chunks (contiguous writes).
__global__ __launch_bounds__(512, 8) void bucket_k(const int* __restrict__ src,
                                                   const int* __restrict__ dst,
                                                   int* __restrict__ bucketCur,
                                                   unsigned* __restrict__ bE) {
    __shared__ int cnt[8][NBUCK];
    __shared__ int basew[8][NBUCK];
    int tid = threadIdx.x;
    int wv = tid >> 6;
    for (int i = tid; i < 8 * NBUCK; i += 512) ((int*)cnt)[i] = 0;
    __syncthreads();
    long e0 = (long)blockIdx.x * TILE;
    int d[4];
#pragma unroll
    for (int i = 0; i < 4; ++i) {
        long e = e0 + tid + i * 512;
        d[i] = (e < EE) ? dst[e] : -1;
    }
#pragma unroll
    for (int i = 0; i < 4; ++i) {
        if (d[i] >= 0) atomicAdd(&cnt[wv][d[i] >> 8], 1);
    }
    __syncthreads();
    for (int b = tid; b < NBUCK; b += 512) {
        int c[8];
        int tot = 0;
#pragma unroll
        for (int w = 0; w < 8; ++w) { c[w] = cnt[w][b]; tot += c[w]; }
        int base = tot ? atomicAdd(&bucketCur[b], tot) : 0;
        int run = base;
#pragma unroll
        for (int w = 0; w < 8; ++w) { basew[w][b] = run; run += c[w]; cnt[w][b] = 0; }
    }
    __syncthreads();
#pragma unroll
    for (int i = 0; i < 4; ++i) {
        if (d[i] >= 0) {
            long e = e0 + tid + i * 512;
            int b = d[i] >> 8;
            int pos = basew[wv][b] + atomicAdd(&cnt[wv][b], 1);
            bE[pos] = (unsigned)src[e] | ((unsigned)(d[i] & 255) << 24);
        }
    }
}

// ---------------------------------------------------------------- bucket -> exact CSR + degI + cursor + dinv
__global__ __launch_bounds__(512, 4) void reorder2_k(const int* __restrict__ bucketCur,
                                                     const unsigned* __restrict__ bE,
                                                     int* __restrict__ csrSrc,
                                                     int* __restrict__ degI,
                                                     int* __restrict__ cursor,
                                                     float* __restrict__ dinv) {
    __shared__ int sScan[512];
    __shared__ int sHist[256];
    __shared__ int sPre[256];
    __shared__ int sStart[256];
    int tid = threadIdx.x;
    int b = blockIdx.x;
    // --- exclusive prefix of bucket totals (391 values, 512-wide scan)
    int c = (tid < NBUCK) ? (bucketCur[tid] - tid * BCAP) : 0;
    sScan[tid] = c;
    __syncthreads();
    for (int off = 1; off < 512; off <<= 1) {
        int t = (tid >= off) ? sScan[tid - off] : 0;
        __syncthreads();
        sScan[tid] += t;
        __syncthreads();
    }
    int bbase = (b == 0) ? 0 : sScan[b - 1];   // LDS broadcast
    // --- per-node histogram of this bucket
    if (tid < 256) sHist[tid] = 0;
    __syncthreads();
    int start = b * BCAP;
    int end = bucketCur[b];
    for (int e = start + tid; e < end; e += 512) {
        unsigned v = bE[e];
        atomicAdd(&sHist[v >> 24], 1);
    }
    __syncthreads();
    // --- inclusive scan over 256 node counts
    if (tid < 256) sPre[tid] = sHist[tid];
    __syncthreads();
    for (int off = 1; off < 256; off <<= 1) {
        int t = (tid >= off && tid < 256) ? sPre[tid - off] : 0;
        __syncthreads();
        if (tid < 256) sPre[tid] += t;
        __syncthreads();
    }
    if (tid < 256) {
        int h = sHist[tid];
        int excl = sPre[tid] - h;
        int st = bbase + excl;
        sStart[tid] = st;
        int nd = (b << 8) + tid;
        if (nd < NN) {
            degI[nd] = h;
            cursor[nd] = st;
            dinv[nd] = rsqrtf((float)h + 1.0f);
        }
    }
    __syncthreads();
    // --- scatter into exact CSR
    for (int e = start + tid; e < end; e += 512) {
        unsigned v = bE[e];
        int pos = atomicAdd(&sStart[v >> 24], 1);
        csrSrc[pos] = (int)(v & 0xFFFFFFu);
    }
}

// ---------------------------------------------------------------- MFMA GEMM: H' = bf16((X@W)*dinv)
template <int K>
__global__ __launch_bounds__(256, 2) void gemm_mfma(const float* __restrict__ X,
                                                    const float* __restrict__ W,
                                                    const float* __restrict__ dinv,
                                                    unsigned* __restrict__ H) {
    constexpr int C = K / 32;
    __shared__ unsigned short sW16[K * 66];
    __shared__ float sD[64 * 65];
    int tid = threadIdx.x;
    for (int i = tid; i < K * 64; i += 256) {
        int k = i >> 6, n = i & 63;
        sW16[k * 66 + n] = (unsigned short)(bpack(W[i], 0.f) & 0xffffu);
    }
    __syncthreads();
    int wv = tid >> 6, lane = tid & 63;
    int q = lane >> 4, ln = lane & 15;
    short8 bfrag[C][4];
#pragma unroll
    for (int c = 0; c < C; ++c) {
#pragma unroll
        for (int t = 0; t < 4; ++t) {
            int kb = (c * 32 + q * 8) * 66 + t * 16 + ln;
            unsigned u0 = (unsigned)sW16[kb]       | ((unsigned)sW16[kb + 66]  << 16);
            unsigned u1 = (unsigned)sW16[kb + 132] | ((unsigned)sW16[kb + 198] << 16);
            unsigned u2 = (unsigned)sW16[kb + 264] | ((unsigned)sW16[kb + 330] << 16);
            unsigned u3 = (unsigned)sW16[kb + 396] | ((unsigned)sW16[kb + 462] << 16);
            uint4 u = make_uint4(u0, u1, u2, u3);
            bfrag[c][t] = __builtin_bit_cast(short8, u);
        }
    }
    int base = blockIdx.x * 64;
    int node = base + wv * 16 + ln;
    bool ok = node < NN;
    short8 afrag[C];
#pragma unroll
    for (int c = 0; c < C; ++c) {
        float4 f0 = make_float4(0.f, 0.f, 0.f, 0.f);
        float4 f1 = make_float4(0.f, 0.f, 0.f, 0.f);
        if (ok) {
            const float4* xp = (const float4*)(X + (long)node * K + c * 32 + q * 8);
            f0 = xp[0];
            f1 = xp[1];
        }
        uint4 u;
        u.x = bpack(f0.x, f0.y);
        u.y = bpack(f0.z, f0.w);
        u.z = bpack(f1.x, f1.y);
        u.w = bpack(f1.z, f1.w);
        afrag[c] = __builtin_bit_cast(short8, u);
    }
#pragma unroll
    for (int t = 0; t < 4; ++t) {
        f32x4 acc = {0.f, 0.f, 0.f, 0.f};
#pragma unroll
        for (int c = 0; c < C; ++c)
            acc = __builtin_amdgcn_mfma_f32_16x16x32_bf16(afrag[c], bfrag[c][t], acc, 0, 0, 0);
#pragma unroll
        for (int r = 0; r < 4; ++r)
            sD[(wv * 16 + q * 4 + r) * 65 + t * 16 + ln] = acc[r];
    }
    __syncthreads();
    for (int i = tid; i < 64 * 32; i += 256) {
        int row = i >> 5, c2 = i & 31;
        int nd = base + row;
        if (nd < NN) {
            float di = dinv[nd];
            float lo = sD[row * 65 + c2 * 2] * di;
            float hi = sD[row * 65 + c2 * 2 + 1] * di;
            H[nd * 32 + c2] = bpack(lo, hi);
        }
    }
}

// ---------------------------------------------------------------- aggregate + bias + relu + optional LN
// One wave per node; 16-lane group g handles edge 4r+g.  One coalesced
// csrSrc load covers edges 0..63; per-round indices via __shfl.  The 8
// static rounds (deg<=32) issue ALL gathers into q[8] before consumption
// -> 8 loads in flight per wave.  deg>32 uses a WAVE-UNIFORM trip-count
// loop: R2 is uniform so every __shfl executes with all 64 lanes active
// (round-8 lesson: ds_bpermute from an exec-masked-off source lane
// returns garbage; per-lane trip counts around __shfl are UB).
__global__ __launch_bounds__(256, 4) void agg_k(
        const int* __restrict__ cursor, const int* __restrict__ degI,
        const int* __restrict__ csrSrc, const float* __restrict__ dinv,
        const uint2* __restrict__ H2, const float4* __restrict__ bias4,
        const float4* __restrict__ g4, const float4* __restrict__ beta4,
        float4* __restrict__ OUT4, int doLN) {
    int tid = threadIdx.x;
    int w = tid >> 6, lane = tid & 63;
    int g = lane >> 4;
    unsigned f = (unsigned)(lane & 15);
    unsigned node = (unsigned)(blockIdx.x * 4 + w);
    int start = cursor[node];
    int deg = degI[node];
    // one coalesced index load for the whole wave (edges 0..min(deg,64))
    int myIdx = 0;
    if (lane < deg) myIdx = csrSrc[(unsigned)(start + lane)];
    float ax = 0.f, ay = 0.f, az = 0.f, aw = 0.f;
    float bx = 0.f, by = 0.f, bz = 0.f, bw = 0.f;
    // ---- static 8 rounds: issue all gathers first (edges 0..31).
    // __shfl is unconditional (full exec); only the load is guarded.
    uint2 q[8];
#pragma unroll
    for (int r = 0; r < 8; ++r) {
        int e = r * 4 + g;
        unsigned s = (unsigned)__shfl(myIdx, e);
        q[r] = make_uint2(0u, 0u);
        if (e < deg) q[r] = H2[s * 16u + f];
    }
#pragma unroll
    for (int r = 0; r < 8; r += 2) {
        ax += blo(q[r].x);     ay += bhi(q[r].x);
        az += blo(q[r].y);     aw += bhi(q[r].y);
        bx += blo(q[r + 1].x); by += bhi(q[r + 1].x);
        bz += blo(q[r + 1].y); bw += bhi(q[r + 1].y);
    }
    // ---- rare deg in (32,64]: wave-uniform rounds 8..R2-1 (deg uniform
    // per wave => uniform trip count => __shfl sees full exec mask)
    if (deg > 32) {
        int R2 = (deg + 3) >> 2;
        if (R2 > 16) R2 = 16;
        for (int r = 8; r < R2; ++r) {
            int e = r * 4 + g;
            unsigned s = (unsigned)__shfl(myIdx, e);
            uint2 qq = make_uint2(0u, 0u);
            if (e < deg) qq = H2[s * 16u + f];
            ax += blo(qq.x); ay += bhi(qq.x); az += blo(qq.y); aw += bhi(qq.y);
        }
        // ---- deg > 64 global tail (no shuffle; divergence is safe here)
        for (int ee = 64 + g; ee < deg; ee += 4) {
            uint2 qq = H2[(unsigned)csrSrc[(unsigned)(start + ee)] * 16u + f];
            ax += blo(qq.x); ay += bhi(qq.x); az += blo(qq.y); aw += bhi(qq.y);
        }
    }
    ax += bx; ay += by; az += bz; aw += bw;
    ax += __shfl_xor(ax, 16); ay += __shfl_xor(ay, 16);
    az += __shfl_xor(az, 16); aw += __shfl_xor(aw, 16);
    ax += __shfl_xor(ax, 32); ay += __shfl_xor(ay, 32);
    az += __shfl_xor(az, 32); aw += __shfl_xor(aw, 32);
    float di = dinv[node];
    uint2 qs = H2[node * 16u + f];
    float4 bb = bias4[f];
    float vx = fmaxf((ax + blo(qs.x)) * di + bb.x, 0.f);
    float vy = fmaxf((ay + bhi(qs.x)) * di + bb.y, 0.f);
    float vz = fmaxf((az + blo(qs.y)) * di + bb.z, 0.f);
    float vw = fmaxf((aw + bhi(qs.y)) * di + bb.w, 0.f);
    if (doLN) {
        float s = vx + vy + vz + vw;
        s += __shfl_xor(s, 1); s += __shfl_xor(s, 2);
        s += __shfl_xor(s, 4); s += __shfl_xor(s, 8);
        float mu = s * (1.f / 64.f);
        vx -= mu; vy -= mu; vz -= mu; vw -= mu;
        float vs = vx * vx + vy * vy + vz * vz + vw * vw;
        vs += __shfl_xor(vs, 1); vs += __shfl_xor(vs, 2);
        vs += __shfl_xor(vs, 4); vs += __shfl_xor(vs, 8);
        float inv = rsqrtf(vs * (1.f / 64.f) + LN_EPS);
        float4 gg = g4[f];
        float4 tt = beta4[f];
        vx = vx * inv * gg.x + tt.x;
        vy = vy * inv * gg.y + tt.y;
        vz = vz * inv * gg.z + tt.z;
        vw = vw * inv * gg.w + tt.w;
    }
    if (g == 0) OUT4[node * 16u + f] = make_float4(vx, vy, vz, vw);
}

// ---------------------------------------------------------------- fuse the two head linears
__global__ void fuse_k(const float* __restrict__ W0, const float* __restrict__ b0,
                       const float* __restrict__ W1, const float* __restrict__ b1,
                       float* __restrict__ Wf, float* __restrict__ bf) {
    int tid = threadIdx.x;
    for (int i = tid; i < 64 * 48; i += 256) {
        int k = i / 48, n = i % 48;
        float acc = 0.f;
        if (n < DOUT) {
            for (int j = 0; j < 64; ++j) acc = fmaf(W0[k * 64 + j], W1[j * DOUT + n], acc);
        }
        Wf[i] = acc;
    }
    for (int n = tid; n < 48; n += 256) {
        float acc = 0.f;
        if (n < DOUT) {
            acc = b1[n];
            for (int j = 0; j < 64; ++j) acc = fmaf(b0[j], W1[j * DOUT + n], acc);
        }
        bf[n] = acc;
    }
}

// ---------------------------------------------------------------- MLP head via MFMA: OUT = Hin @ Wf + bf
__global__ __launch_bounds__(256, 2) void mlp_mfma(const float* __restrict__ Hin,
                                                   const float* __restrict__ Wf,
                                                   const float* __restrict__ bf,
                                                   float* __restrict__ OUT) {
    __shared__ unsigned short sW16[64 * 50];
    int tid = threadIdx.x;
    for (int i = tid; i < 64 * 48; i += 256) {
        int k = i / 48, n = i % 48;
        sW16[k * 50 + n] = (unsigned short)(bpack(Wf[i], 0.f) & 0xffffu);
    }
    __syncthreads();
    int wv = tid >> 6, lane = tid & 63;
    int q = lane >> 4, ln = lane & 15;
    short8 bfrag[2][3];
#pragma unroll
    for (int c = 0; c < 2; ++c) {
#pragma unroll
        for (int t = 0; t < 3; ++t) {
            int kb = (c * 32 + q * 8) * 50 + t * 16 + ln;
            unsigned u0 = (unsigned)sW16[kb]       | ((unsigned)sW16[kb + 50]  << 16);
            unsigned u1 = (unsigned)sW16[kb + 100] | ((unsigned)sW16[kb + 150] << 16);
            unsigned u2 = (unsigned)sW16[kb + 200] | ((unsigned)sW16[kb + 250] << 16);
            unsigned u3 = (unsigned)sW16[kb + 300] | ((unsigned)sW16[kb + 350] << 16);
            uint4 u = make_uint4(u0, u1, u2, u3);
            bfrag[c][t] = __builtin_bit_cast(short8, u);
        }
    }
    int base = blockIdx.x * 64;
    int node = base + wv * 16 + ln;
    bool ok = node < NN;
    short8 afrag[2];
#pragma unroll
    for (int c = 0; c < 2; ++c) {
        float4 f0 = make_float4(0.f, 0.f, 0.f, 0.f);
        float4 f1 = make_float4(0.f, 0.f, 0.f, 0.f);
        if (ok) {
            const float4* xp = (const float4*)(Hin + (long)node * 64 + c * 32 + q * 8);
            f0 = xp[0];
            f1 = xp[1];
        }
        uint4 u;
        u.x = bpack(f0.x, f0.y);
        u.y = bpack(f0.z, f0.w);
        u.z = bpack(f1.x, f1.y);
        u.w = bpack(f1.z, f1.w);
        afrag[c] = __builtin_bit_cast(short8, u);
    }
#pragma unroll
    for (int t = 0; t < 3; ++t) {
        f32x4 acc = {0.f, 0.f, 0.f, 0.f};
        acc = __builtin_amdgcn_mfma_f32_16x16x32_bf16(afrag[0], bfrag[0][t], acc, 0, 0, 0);
        acc = __builtin_amdgcn_mfma_f32_16x16x32_bf16(afrag[1], bfrag[1][t], acc, 0, 0, 0);
        int col = t * 16 + ln;
        if (col < DOUT) {
            float bv = bf[col];
#pragma unroll
            for (int r = 0; r < 4; ++r) {
                int nd = base + wv * 16 + q * 4 + r;
                if (nd < NN) OUT[(long)nd * DOUT + col] = acc[r] + bv;
            }
        }
    }
}

// ----------------------------------------------------------------
extern "C" void kernel_launch(void* const* d_in, const int* in_sizes, int n_in,
                              void* d_out, int out_size, void* d_ws, size_t ws_size,
                              hipStream_t stream) {
    const float* x    = (const float*)d_in[0];
    const int*   ei   = (const int*)d_in[1];
    const int*   srcI = ei;
    const int*   dstI = ei + EE;
    const float* W0   = (const float*)d_in[2];
    const float* b0   = (const float*)d_in[3];
    const float* W1   = (const float*)d_in[4];
    const float* b1   = (const float*)d_in[5];
    const float* W2   = (const float*)d_in[6];
    const float* b2   = (const float*)d_in[7];
    const float* ln0g = (const float*)d_in[8];
    const float* ln0b = (const float*)d_in[9];
    const float* ln1g = (const float*)d_in[10];
    const float* ln1b = (const float*)d_in[11];
    const float* mpW0 = (const float*)d_in[12];
    const float* mpb0 = (const float*)d_in[13];
    const float* mpW1 = (const float*)d_in[14];
    const float* mpb1 = (const float*)d_in[15];
    float* out = (float*)d_out;

    char* ws = (char*)d_ws;
    float*    dinv      = (float*)   (ws + 0);                      // 400 KB
    int*      degI      = (int*)     (ws + 512l * 1024);            // 400 KB
    int*      cursor    = (int*)     (ws + 1024l * 1024);           // 400 KB
    int*      bucketCur = (int*)     (ws + 1600l * 1024);
    float*    Wf        = (float*)   (ws + 1792l * 1024);
    float*    bfv       = (float*)   (ws + 1984l * 1024);
    unsigned* bE        = (unsigned*)(ws + 2048l * 1024);           // 391*8192*4 = 12.8 MB
    int*      csrSrc    = (int*)     (ws + 15l * 1024 * 1024);      // 6.4 MB
    unsigned* bufA      = (unsigned*)(ws + 22l * 1024 * 1024);      // bf16 H' 12.8 MB
    float*    bufB      = (float*)   (ws + 35l * 1024 * 1024);      // f32 hidden 25.6 MB

    const int aggBlocks  = NN / 4;             // 25000 exact
    const int gemmBlocks = (NN + 63) / 64;     // 1563

    binit_k<<<2, 256, 0, stream>>>(bucketCur);
    bucket_k<<<TBLK, 512, 0, stream>>>(srcI, dstI, bucketCur, bE);
    reorder2_k<<<NBUCK, 512, 0, stream>>>(bucketCur, bE, csrSrc, degI, cursor, dinv);
    fuse_k<<<1, 256, 0, stream>>>(mpW0, mpb0, mpW1, mpb1, Wf, bfv);

    // layer 0
    gemm_mfma<128><<<gemmBlocks, 256, 0, stream>>>(x, W0, dinv, bufA);
    agg_k<<<aggBlocks, 256, 0, stream>>>(cursor, degI, csrSrc, dinv, (const uint2*)bufA,
                                         (const float4*)b0, (const float4*)ln0g,
                                         (const float4*)ln0b, (float4*)bufB, 1);
    // layer 1
    gemm_mfma<64><<<gemmBlocks, 256, 0, stream>>>(bufB, W1, dinv, bufA);
    agg_k<<<aggBlocks, 256, 0, stream>>>(cursor, degI, csrSrc, dinv, (const uint2*)bufA,
                                         (const float4*)b1, (const float4*)ln1g,
                                         (const float4*)ln1b, (float4*)bufB, 1);
    // layer 2 (no LN) then fused MLP head via MFMA
    gemm_mfma<64><<<gemmBlocks, 256, 0, stream>>>(bufB, W2, dinv, bufA);
    agg_k<<<aggBlocks, 256, 0, stream>>>(cursor, degI, csrSrc, dinv, (const uint2*)bufA,
                                         (const float4*)b2, (const float4*)ln0g,
                                         (const float4*)ln0b, (float4*)bufB, 0);
    mlp_mfma<<<gemmBlocks, 256, 0, stream>>>(bufB, Wf, bfv, out);
}

// Round 10
// 354.465 us; speedup vs baseline: 6.4824x; 1.0087x over previous
//
#include <hip/hip_runtime.h>
#include <hip/hip_bf16.h>

#define NN 100000
#define EE 1600000
#define DOUT 40
#define LN_EPS 1e-5f
#define NBUCK 391  // buckets of 256 dst nodes
#define TILE 2048
#define TBLK 782   // ceil(EE/TILE)
#define BCAP 8192  // per-bucket capacity (expected 4092 +- 64)

typedef __attribute__((ext_vector_type(8))) short short8;   // 8 bf16 = 4 VGPRs
typedef __attribute__((ext_vector_type(4))) float f32x4;    // MFMA acc

// ---------------------------------------------------------------- bf16 helpers (RNE pack)
__device__ __forceinline__ float blo(unsigned u) { return __uint_as_float(u << 16); }
__device__ __forceinline__ float bhi(unsigned u) { return __uint_as_float(u & 0xffff0000u); }
__device__ __forceinline__ unsigned bpack(float lo, float hi) {
    unsigned a = __float_as_uint(lo);
    unsigned b = __float_as_uint(hi);
    a = (a + 0x7fffu + ((a >> 16) & 1u)) >> 16;
    b = (b + 0x7fffu + ((b >> 16) & 1u)) & 0xffff0000u;
    return (a & 0xffffu) | b;
}

// ---------------------------------------------------------------- bucket build
__global__ void binit_k(int* __restrict__ bucketCur) {
    int b = blockIdx.x * 256 + threadIdx.x;
    if (b < NBUCK) bucketCur[b] = b * BCAP;
}

// 782 blocks x 512 threads x 4 edges. Pass 1: per-wave LDS histogram.
// One global atomic per nonzero bucket per block. Pass 2: scatter into
// fixed-capacity bucket regions, per-wave sub-chunks (contiguous writes).
__global__ __launch_bounds__(512, 8) void bucket_k(const int* __restrict__ src,
                                                   const int* __restrict__ dst,
                                                   int* __restrict__ bucketCur,
                                                   unsigned* __restrict__ bE) {
    __shared__ int cnt[8][NBUCK];
    __shared__ int basew[8][NBUCK];
    int tid = threadIdx.x;
    int wv = tid >> 6;
    for (int i = tid; i < 8 * NBUCK; i += 512) ((int*)cnt)[i] = 0;
    __syncthreads();
    long e0 = (long)blockIdx.x * TILE;
    int d[4];
#pragma unroll
    for (int i = 0; i < 4; ++i) {
        long e = e0 + tid + i * 512;
        d[i] = (e < EE) ? dst[e] : -1;
    }
#pragma unroll
    for (int i = 0; i < 4; ++i) {
        if (d[i] >= 0) atomicAdd(&cnt[wv][d[i] >> 8], 1);
    }
    __syncthreads();
    for (int b = tid; b < NBUCK; b += 512) {
        int c[8];
        int tot = 0;
#pragma unroll
        for (int w = 0; w < 8; ++w) { c[w] = cnt[w][b]; tot += c[w]; }
        int base = tot ? atomicAdd(&bucketCur[b], tot) : 0;
        int run = base;
#pragma unroll
        for (int w = 0; w < 8; ++w) { basew[w][b] = run; run += c[w]; cnt[w][b] = 0; }
    }
    __syncthreads();
#pragma unroll
    for (int i = 0; i < 4; ++i) {
        if (d[i] >= 0) {
            long e = e0 + tid + i * 512;
            int b = d[i] >> 8;
            int pos = basew[wv][b] + atomicAdd(&cnt[wv][b], 1);
            bE[pos] = (unsigned)src[e] | ((unsigned)(d[i] & 255) << 24);
        }
    }
}

// ---------------------------------------------------------------- bucket -> exact CSR + degI + cursor + dinv
__global__ __launch_bounds__(512, 4) void reorder2_k(const int* __restrict__ bucketCur,
                                                     const unsigned* __restrict__ bE,
                                                     int* __restrict__ csrSrc,
                                                     int* __restrict__ degI,
                                                     int* __restrict__ cursor,
                                                     float* __restrict__ dinv) {
    __shared__ int sScan[512];
    __shared__ int sHist[256];
    __shared__ int sPre[256];
    __shared__ int sStart[256];
    int tid = threadIdx.x;
    int b = blockIdx.x;
    // --- exclusive prefix of bucket totals (391 values, 512-wide scan)
    int c = (tid < NBUCK) ? (bucketCur[tid] - tid * BCAP) : 0;
    sScan[tid] = c;
    __syncthreads();
    for (int off = 1; off < 512; off <<= 1) {
        int t = (tid >= off) ? sScan[tid - off] : 0;
        __syncthreads();
        sScan[tid] += t;
        __syncthreads();
    }
    int bbase = (b == 0) ? 0 : sScan[b - 1];   // LDS broadcast
    // --- per-node histogram of this bucket
    if (tid < 256) sHist[tid] = 0;
    __syncthreads();
    int start = b * BCAP;
    int end = bucketCur[b];
    for (int e = start + tid; e < end; e += 512) {
        unsigned v = bE[e];
        atomicAdd(&sHist[v >> 24], 1);
    }
    __syncthreads();
    // --- inclusive scan over 256 node counts
    if (tid < 256) sPre[tid] = sHist[tid];
    __syncthreads();
    for (int off = 1; off < 256; off <<= 1) {
        int t = (tid >= off && tid < 256) ? sPre[tid - off] : 0;
        __syncthreads();
        if (tid < 256) sPre[tid] += t;
        __syncthreads();
    }
    if (tid < 256) {
        int h = sHist[tid];
        int excl = sPre[tid] - h;
        int st = bbase + excl;
        sStart[tid] = st;
        int nd = (b << 8) + tid;
        if (nd < NN) {
            degI[nd] = h;
            cursor[nd] = st;
            dinv[nd] = rsqrtf((float)h + 1.0f);
        }
    }
    __syncthreads();
    // --- scatter into exact CSR
    for (int e = start + tid; e < end; e += 512) {
        unsigned v = bE[e];
        int pos = atomicAdd(&sStart[v >> 24], 1);
        csrSrc[pos] = (int)(v & 0xFFFFFFu);
    }
}

// ---------------------------------------------------------------- MFMA GEMM (f32 input): H' = bf16((X@W)*dinv)
// Layer 0 only (x is f32 [NN,128]).
template <int K>
__global__ __launch_bounds__(256, 2) void gemm_mfma(const float* __restrict__ X,
                                                    const float* __restrict__ W,
                                                    const float* __restrict__ dinv,
                                                    unsigned* __restrict__ H) {
    constexpr int C = K / 32;
    __shared__ unsigned short sW16[K * 66];
    __shared__ float sD[64 * 65];
    int tid = threadIdx.x;
    for (int i = tid; i < K * 64; i += 256) {
        int k = i >> 6, n = i & 63;
        sW16[k * 66 + n] = (unsigned short)(bpack(W[i], 0.f) & 0xffffu);
    }
    __syncthreads();
    int wv = tid >> 6, lane = tid & 63;
    int q = lane >> 4, ln = lane & 15;
    short8 bfrag[C][4];
#pragma unroll
    for (int c = 0; c < C; ++c) {
#pragma unroll
        for (int t = 0; t < 4; ++t) {
            int kb = (c * 32 + q * 8) * 66 + t * 16 + ln;
            unsigned u0 = (unsigned)sW16[kb]       | ((unsigned)sW16[kb + 66]  << 16);
            unsigned u1 = (unsigned)sW16[kb + 132] | ((unsigned)sW16[kb + 198] << 16);
            unsigned u2 = (unsigned)sW16[kb + 264] | ((unsigned)sW16[kb + 330] << 16);
            unsigned u3 = (unsigned)sW16[kb + 396] | ((unsigned)sW16[kb + 462] << 16);
            uint4 u = make_uint4(u0, u1, u2, u3);
            bfrag[c][t] = __builtin_bit_cast(short8, u);
        }
    }
    int base = blockIdx.x * 64;
    int node = base + wv * 16 + ln;
    bool ok = node < NN;
    short8 afrag[C];
#pragma unroll
    for (int c = 0; c < C; ++c) {
        float4 f0 = make_float4(0.f, 0.f, 0.f, 0.f);
        float4 f1 = make_float4(0.f, 0.f, 0.f, 0.f);
        if (ok) {
            const float4* xp = (const float4*)(X + (long)node * K + c * 32 + q * 8);
            f0 = xp[0];
            f1 = xp[1];
        }
        uint4 u;
        u.x = bpack(f0.x, f0.y);
        u.y = bpack(f0.z, f0.w);
        u.z = bpack(f1.x, f1.y);
        u.w = bpack(f1.z, f1.w);
        afrag[c] = __builtin_bit_cast(short8, u);
    }
#pragma unroll
    for (int t = 0; t < 4; ++t) {
        f32x4 acc = {0.f, 0.f, 0.f, 0.f};
#pragma unroll
        for (int c = 0; c < C; ++c)
            acc = __builtin_amdgcn_mfma_f32_16x16x32_bf16(afrag[c], bfrag[c][t], acc, 0, 0, 0);
#pragma unroll
        for (int r = 0; r < 4; ++r)
            sD[(wv * 16 + q * 4 + r) * 65 + t * 16 + ln] = acc[r];
    }
    __syncthreads();
    for (int i = tid; i < 64 * 32; i += 256) {
        int row = i >> 5, c2 = i & 31;
        int nd = base + row;
        if (nd < NN) {
            float di = dinv[nd];
            float lo = sD[row * 65 + c2 * 2] * di;
            float hi = sD[row * 65 + c2 * 2 + 1] * di;
            H[nd * 32 + c2] = bpack(lo, hi);
        }
    }
}

// ---------------------------------------------------------------- MFMA GEMM (bf16 input): H' = bf16((Hin@W)*dinv)
// Layers 1,2.  Hin rows are 32 words of packed bf16 pairs (word c2 = feats
// 2c2, 2c2+1) -> A fragments are raw uint4 loads, zero unpack VALU.
__global__ __launch_bounds__(256, 2) void gemm_b(const uint4* __restrict__ Hin4,
                                                 const float* __restrict__ W,
                                                 const float* __restrict__ dinv,
                                                 unsigned* __restrict__ H) {
    __shared__ unsigned short sW16[64 * 66];
    __shared__ float sD[64 * 65];
    int tid = threadIdx.x;
    for (int i = tid; i < 64 * 64; i += 256) {
        int k = i >> 6, n = i & 63;
        sW16[k * 66 + n] = (unsigned short)(bpack(W[i], 0.f) & 0xffffu);
    }
    __syncthreads();
    int wv = tid >> 6, lane = tid & 63;
    int q = lane >> 4, ln = lane & 15;
    short8 bfrag[2][4];
#pragma unroll
    for (int c = 0; c < 2; ++c) {
#pragma unroll
        for (int t = 0; t < 4; ++t) {
            int kb = (c * 32 + q * 8) * 66 + t * 16 + ln;
            unsigned u0 = (unsigned)sW16[kb]       | ((unsigned)sW16[kb + 66]  << 16);
            unsigned u1 = (unsigned)sW16[kb + 132] | ((unsigned)sW16[kb + 198] << 16);
            unsigned u2 = (unsigned)sW16[kb + 264] | ((unsigned)sW16[kb + 330] << 16);
            unsigned u3 = (unsigned)sW16[kb + 396] | ((unsigned)sW16[kb + 462] << 16);
            uint4 u = make_uint4(u0, u1, u2, u3);
            bfrag[c][t] = __builtin_bit_cast(short8, u);
        }
    }
    int base = blockIdx.x * 64;
    int node = base + wv * 16 + ln;
    bool ok = node < NN;
    short8 afrag[2];
    {
        uint4 u0 = make_uint4(0u, 0u, 0u, 0u), u1 = u0;
        if (ok) {
            u0 = Hin4[(unsigned)node * 8u + (unsigned)q];        // feats q*8 .. q*8+7
            u1 = Hin4[(unsigned)node * 8u + 4u + (unsigned)q];   // feats 32+q*8 ..
        }
        afrag[0] = __builtin_bit_cast(short8, u0);
        afrag[1] = __builtin_bit_cast(short8, u1);
    }
#pragma unroll
    for (int t = 0; t < 4; ++t) {
        f32x4 acc = {0.f, 0.f, 0.f, 0.f};
        acc = __builtin_amdgcn_mfma_f32_16x16x32_bf16(afrag[0], bfrag[0][t], acc, 0, 0, 0);
        acc = __builtin_amdgcn_mfma_f32_16x16x32_bf16(afrag[1], bfrag[1][t], acc, 0, 0, 0);
#pragma unroll
        for (int r = 0; r < 4; ++r)
            sD[(wv * 16 + q * 4 + r) * 65 + t * 16 + ln] = acc[r];
    }
    __syncthreads();
    for (int i = tid; i < 64 * 32; i += 256) {
        int row = i >> 5, c2 = i & 31;
        int nd = base + row;
        if (nd < NN) {
            float di = dinv[nd];
            float lo = sD[row * 65 + c2 * 2] * di;
            float hi = sD[row * 65 + c2 * 2 + 1] * di;
            H[nd * 32 + c2] = bpack(lo, hi);
        }
    }
}

// ---------------------------------------------------------------- aggregate + bias + relu + optional LN -> packed bf16
// One wave per node; 16-lane group g handles edge 4r+g.  One coalesced
// csrSrc load covers edges 0..63; per-round indices via __shfl.  The 8
// static rounds (deg<=32) issue ALL gathers into q[8] before consumption
// -> 8 loads in flight per wave.  deg>32 uses a WAVE-UNIFORM trip-count
// loop (round-8 lesson: __shfl under per-lane trip counts is UB).
// Output written as packed bf16 (same word layout as H) - halves write
// traffic and lets gemm_b/mlp consume raw uint4 A-fragments.
__global__ __launch_bounds__(256, 4) void agg_k(
        const int* __restrict__ cursor, const int* __restrict__ degI,
        const int* __restrict__ csrSrc, const float* __restrict__ dinv,
        const uint2* __restrict__ H2, const float4* __restrict__ bias4,
        const float4* __restrict__ g4, const float4* __restrict__ beta4,
        uint2* __restrict__ OUT2, int doLN) {
    int tid = threadIdx.x;
    int w = tid >> 6, lane = tid & 63;
    int g = lane >> 4;
    unsigned f = (unsigned)(lane & 15);
    unsigned node = (unsigned)(blockIdx.x * 4 + w);
    int start = cursor[node];
    int deg = degI[node];
    // one coalesced index load for the whole wave (edges 0..min(deg,64))
    int myIdx = 0;
    if (lane < deg) myIdx = csrSrc[(unsigned)(start + lane)];
    float ax = 0.f, ay = 0.f, az = 0.f, aw = 0.f;
    float bx = 0.f, by = 0.f, bz = 0.f, bw = 0.f;
    // ---- static 8 rounds: issue all gathers first (edges 0..31).
    // __shfl is unconditional (full exec); only the load is guarded.
    uint2 q[8];
#pragma unroll
    for (int r = 0; r < 8; ++r) {
        int e = r * 4 + g;
        unsigned s = (unsigned)__shfl(myIdx, e);
        q[r] = make_uint2(0u, 0u);
        if (e < deg) q[r] = H2[s * 16u + f];
    }
#pragma unroll
    for (int r = 0; r < 8; r += 2) {
        ax += blo(q[r].x);     ay += bhi(q[r].x);
        az += blo(q[r].y);     aw += bhi(q[r].y);
        bx += blo(q[r + 1].x); by += bhi(q[r + 1].x);
        bz += blo(q[r + 1].y); bw += bhi(q[r + 1].y);
    }
    // ---- rare deg in (32,64]: wave-uniform rounds 8..R2-1 (deg uniform
    // per wave => uniform trip count => __shfl sees full exec mask)
    if (deg > 32) {
        int R2 = (deg + 3) >> 2;
        if (R2 > 16) R2 = 16;
        for (int r = 8; r < R2; ++r) {
            int e = r * 4 + g;
            unsigned s = (unsigned)__shfl(myIdx, e);
            uint2 qq = make_uint2(0u, 0u);
            if (e < deg) qq = H2[s * 16u + f];
            ax += blo(qq.x); ay += bhi(qq.x); az += blo(qq.y); aw += bhi(qq.y);
        }
        // ---- deg > 64 global tail (no shuffle; divergence is safe here)
        for (int ee = 64 + g; ee < deg; ee += 4) {
            uint2 qq = H2[(unsigned)csrSrc[(unsigned)(start + ee)] * 16u + f];
            ax += blo(qq.x); ay += bhi(qq.x); az += blo(qq.y); aw += bhi(qq.y);
        }
    }
    ax += bx; ay += by; az += bz; aw += bw;
    ax += __shfl_xor(ax, 16); ay += __shfl_xor(ay, 16);
    az += __shfl_xor(az, 16); aw += __shfl_xor(aw, 16);
    ax += __shfl_xor(ax, 32); ay += __shfl_xor(ay, 32);
    az += __shfl_xor(az, 32); aw += __shfl_xor(aw, 32);
    float di = dinv[node];
    uint2 qs = H2[node * 16u + f];
    float4 bb = bias4[f];
    float vx = fmaxf((ax + blo(qs.x)) * di + bb.x, 0.f);
    float vy = fmaxf((ay + bhi(qs.x)) * di + bb.y, 0.f);
    float vz = fmaxf((az + blo(qs.y)) * di + bb.z, 0.f);
    float vw = fmaxf((aw + bhi(qs.y)) * di + bb.w, 0.f);
    if (doLN) {
        float s = vx + vy + vz + vw;
        s += __shfl_xor(s, 1); s += __shfl_xor(s, 2);
        s += __shfl_xor(s, 4); s += __shfl_xor(s, 8);
        float mu = s * (1.f / 64.f);
        vx -= mu; vy -= mu; vz -= mu; vw -= mu;
        float vs = vx * vx + vy * vy + vz * vz + vw * vw;
        vs += __shfl_xor(vs, 1); vs += __shfl_xor(vs, 2);
        vs += __shfl_xor(vs, 4); vs += __shfl_xor(vs, 8);
        float inv = rsqrtf(vs * (1.f / 64.f) + LN_EPS);
        float4 gg = g4[f];
        float4 tt = beta4[f];
        vx = vx * inv * gg.x + tt.x;
        vy = vy * inv * gg.y + tt.y;
        vz = vz * inv * gg.z + tt.z;
        vw = vw * inv * gg.w + tt.w;
    }
    if (g == 0) OUT2[node * 16u + f] = make_uint2(bpack(vx, vy), bpack(vz, vw));
}

// ---------------------------------------------------------------- fuse the two head linears
__global__ void fuse_k(const float* __restrict__ W0, const float* __restrict__ b0,
                       const float* __restrict__ W1, const float* __restrict__ b1,
                       float* __restrict__ Wf, float* __restrict__ bf) {
    int tid = threadIdx.x;
    for (int i = tid; i < 64 * 48; i += 256) {
        int k = i / 48, n = i % 48;
        float acc = 0.f;
        if (n < DOUT) {
            for (int j = 0; j < 64; ++j) acc = fmaf(W0[k * 64 + j], W1[j * DOUT + n], acc);
        }
        Wf[i] = acc;
    }
    for (int n = tid; n < 48; n += 256) {
        float acc = 0.f;
        if (n < DOUT) {
            acc = b1[n];
            for (int j = 0; j < 64; ++j) acc = fmaf(b0[j], W1[j * DOUT + n], acc);
        }
        bf[n] = acc;
    }
}

// ---------------------------------------------------------------- MLP head via MFMA: OUT = Hin @ Wf + bf (bf16 input)
__global__ __launch_bounds__(256, 2) void mlp_mfma(const uint4* __restrict__ Hin4,
                                                   const float* __restrict__ Wf,
                                                   const float* __restrict__ bf,
                                                   float* __restrict__ OUT) {
    __shared__ unsigned short sW16[64 * 50];
    int tid = threadIdx.x;
    for (int i = tid; i < 64 * 48; i += 256) {
        int k = i / 48, n = i % 48;
        sW16[k * 50 + n] = (unsigned short)(bpack(Wf[i], 0.f) & 0xffffu);
    }
    __syncthreads();
    int wv = tid >> 6, lane = tid & 63;
    int q = lane >> 4, ln = lane & 15;
    short8 bfrag[2][3];
#pragma unroll
    for (int c = 0; c < 2; ++c) {
#pragma unroll
        for (int t = 0; t < 3; ++t) {
            int kb = (c * 32 + q * 8) * 50 + t * 16 + ln;
            unsigned u0 = (unsigned)sW16[kb]       | ((unsigned)sW16[kb + 50]  << 16);
            unsigned u1 = (unsigned)sW16[kb + 100] | ((unsigned)sW16[kb + 150] << 16);
            unsigned u2 = (unsigned)sW16[kb + 200] | ((unsigned)sW16[kb + 250] << 16);
            unsigned u3 = (unsigned)sW16[kb + 300] | ((unsigned)sW16[kb + 350] << 16);
            uint4 u = make_uint4(u0, u1, u2, u3);
            bfrag[c][t] = __builtin_bit_cast(short8, u);
        }
    }
    int base = blockIdx.x * 64;
    int node = base + wv * 16 + ln;
    bool ok = node < NN;
    short8 afrag[2];
    {
        uint4 u0 = make_uint4(0u, 0u, 0u, 0u), u1 = u0;
        if (ok) {
            u0 = Hin4[(unsigned)node * 8u + (unsigned)q];
            u1 = Hin4[(unsigned)node * 8u + 4u + (unsigned)q];
        }
        afrag[0] = __builtin_bit_cast(short8, u0);
        afrag[1] = __builtin_bit_cast(short8, u1);
    }
#pragma unroll
    for (int t = 0; t < 3; ++t) {
        f32x4 acc = {0.f, 0.f, 0.f, 0.f};
        acc = __builtin_amdgcn_mfma_f32_16x16x32_bf16(afrag[0], bfrag[0][t], acc, 0, 0, 0);
        acc = __builtin_amdgcn_mfma_f32_16x16x32_bf16(afrag[1], bfrag[1][t], acc, 0, 0, 0);
        int col = t * 16 + ln;
        if (col < DOUT) {
            float bv = bf[col];
#pragma unroll
            for (int r = 0; r < 4; ++r) {
                int nd = base + wv * 16 + q * 4 + r;
                if (nd < NN) OUT[(long)nd * DOUT + col] = acc[r] + bv;
            }
        }
    }
}

// ----------------------------------------------------------------
extern "C" void kernel_launch(void* const* d_in, const int* in_sizes, int n_in,
                              void* d_out, int out_size, void* d_ws, size_t ws_size,
                              hipStream_t stream) {
    const float* x    = (const float*)d_in[0];
    const int*   ei   = (const int*)d_in[1];
    const int*   srcI = ei;
    const int*   dstI = ei + EE;
    const float* W0   = (const float*)d_in[2];
    const float* b0   = (const float*)d_in[3];
    const float* W1   = (const float*)d_in[4];
    const float* b1   = (const float*)d_in[5];
    const float* W2   = (const float*)d_in[6];
    const float* b2   = (const float*)d_in[7];
    const float* ln0g = (const float*)d_in[8];
    const float* ln0b = (const float*)d_in[9];
    const float* ln1g = (const float*)d_in[10];
    const float* ln1b = (const float*)d_in[11];
    const float* mpW0 = (const float*)d_in[12];
    const float* mpb0 = (const float*)d_in[13];
    const float* mpW1 = (const float*)d_in[14];
    const float* mpb1 = (const float*)d_in[15];
    float* out = (float*)d_out;

    char* ws = (char*)d_ws;
    float*    dinv      = (float*)   (ws + 0);                      // 400 KB
    int*      degI      = (int*)     (ws + 512l * 1024);            // 400 KB
    int*      cursor    = (int*)     (ws + 1024l * 1024);           // 400 KB
    int*      bucketCur = (int*)     (ws + 1600l * 1024);
    float*    Wf        = (float*)   (ws + 1792l * 1024);
    float*    bfv       = (float*)   (ws + 1984l * 1024);
    unsigned* bE        = (unsigned*)(ws + 2048l * 1024);           // 391*8192*4 = 12.8 MB
    int*      csrSrc    = (int*)     (ws + 15l * 1024 * 1024);      // 6.4 MB
    unsigned* bufA      = (unsigned*)(ws + 22l * 1024 * 1024);      // bf16 H' 12.8 MB
    unsigned* bufB      = (unsigned*)(ws + 36l * 1024 * 1024);      // bf16 hidden 12.8 MB

    const int aggBlocks  = NN / 4;             // 25000 exact
    const int gemmBlocks = (NN + 63) / 64;     // 1563

    binit_k<<<2, 256, 0, stream>>>(bucketCur);
    bucket_k<<<TBLK, 512, 0, stream>>>(srcI, dstI, bucketCur, bE);
    reorder2_k<<<NBUCK, 512, 0, stream>>>(bucketCur, bE, csrSrc, degI, cursor, dinv);
    fuse_k<<<1, 256, 0, stream>>>(mpW0, mpb0, mpW1, mpb1, Wf, bfv);

    // layer 0 (f32 input)
    gemm_mfma<128><<<gemmBlocks, 256, 0, stream>>>(x, W0, dinv, bufA);
    agg_k<<<aggBlocks, 256, 0, stream>>>(cursor, degI, csrSrc, dinv, (const uint2*)bufA,
                                         (const float4*)b0, (const float4*)ln0g,
                                         (const float4*)ln0b, (uint2*)bufB, 1);
    // layer 1 (bf16 hidden)
    gemm_b<<<gemmBlocks, 256, 0, stream>>>((const uint4*)bufB, W1, dinv, bufA);
    agg_k<<<aggBlocks, 256, 0, stream>>>(cursor, degI, csrSrc, dinv, (const uint2*)bufA,
                                         (const float4*)b1, (const float4*)ln1g,
                                         (const float4*)ln1b, (uint2*)bufB, 1);
    // layer 2 (no LN) then fused MLP head via MFMA
    gemm_b<<<gemmBlocks, 256, 0, stream>>>((const uint4*)bufB, W2, dinv, bufA);
    agg_k<<<aggBlocks, 256, 0, stream>>>(cursor, degI, csrSrc, dinv, (const uint2*)bufA,
                                         (const float4*)b2, (const float4*)ln0g,
                                         (const float4*)ln0b, (uint2*)bufB, 0);
    mlp_mfma<<<gemmBlocks, 256, 0, stream>>>((const uint4*)bufB, Wf, bfv, out);
}

// Round 11
// 342.243 us; speedup vs baseline: 6.7139x; 1.0357x over previous
//
#include <hip/hip_runtime.h>
#include <hip/hip_bf16.h>

#define NN 100000
#define EE 1600000
#define DOUT 40
#define LN_EPS 1e-5f
#define NBUCK 391  // buckets of 256 dst nodes
#define TILE 2048
#define TBLK 782   // ceil(EE/TILE)
#define BCAP 8192  // per-bucket capacity (expected 4092 +- 64)

typedef __attribute__((ext_vector_type(8))) short short8;   // 8 bf16 = 4 VGPRs
typedef __attribute__((ext_vector_type(4))) float f32x4;    // MFMA acc

// ---------------------------------------------------------------- bf16 helpers (RNE pack)
__device__ __forceinline__ float blo(unsigned u) { return __uint_as_float(u << 16); }
__device__ __forceinline__ float bhi(unsigned u) { return __uint_as_float(u & 0xffff0000u); }
__device__ __forceinline__ unsigned bpack(float lo, float hi) {
    unsigned a = __float_as_uint(lo);
    unsigned b = __float_as_uint(hi);
    a = (a + 0x7fffu + ((a >> 16) & 1u)) >> 16;
    b = (b + 0x7fffu + ((b >> 16) & 1u)) & 0xffff0000u;
    return (a & 0xffffu) | b;
}

// ---------------------------------------------------------------- bucket build
__global__ void binit_k(int* __restrict__ bucketCur) {
    int b = blockIdx.x * 256 + threadIdx.x;
    if (b < NBUCK) bucketCur[b] = b * BCAP;
}

// 782 blocks x 512 threads x 4 edges. Pass 1: per-wave LDS histogram.
// One global atomic per nonzero bucket per block. Pass 2: scatter into
// fixed-capacity bucket regions, per-wave sub-chunks (contiguous writes).
__global__ __launch_bounds__(512, 8) void bucket_k(const int* __restrict__ src,
                                                   const int* __restrict__ dst,
                                                   int* __restrict__ bucketCur,
                                                   unsigned* __restrict__ bE) {
    __shared__ int cnt[8][NBUCK];
    __shared__ int basew[8][NBUCK];
    int tid = threadIdx.x;
    int wv = tid >> 6;
    for (int i = tid; i < 8 * NBUCK; i += 512) ((int*)cnt)[i] = 0;
    __syncthreads();
    long e0 = (long)blockIdx.x * TILE;
    int d[4];
#pragma unroll
    for (int i = 0; i < 4; ++i) {
        long e = e0 + tid + i * 512;
        d[i] = (e < EE) ? dst[e] : -1;
    }
#pragma unroll
    for (int i = 0; i < 4; ++i) {
        if (d[i] >= 0) atomicAdd(&cnt[wv][d[i] >> 8], 1);
    }
    __syncthreads();
    for (int b = tid; b < NBUCK; b += 512) {
        int c[8];
        int tot = 0;
#pragma unroll
        for (int w = 0; w < 8; ++w) { c[w] = cnt[w][b]; tot += c[w]; }
        int base = tot ? atomicAdd(&bucketCur[b], tot) : 0;
        int run = base;
#pragma unroll
        for (int w = 0; w < 8; ++w) { basew[w][b] = run; run += c[w]; cnt[w][b] = 0; }
    }
    __syncthreads();
#pragma unroll
    for (int i = 0; i < 4; ++i) {
        if (d[i] >= 0) {
            long e = e0 + tid + i * 512;
            int b = d[i] >> 8;
            int pos = basew[wv][b] + atomicAdd(&cnt[wv][b], 1);
            bE[pos] = (unsigned)src[e] | ((unsigned)(d[i] & 255) << 24);
        }
    }
}

// ---------------------------------------------------------------- bucket -> exact CSR + degI + cursor + dinv
__global__ __launch_bounds__(512, 4) void reorder2_k(const int* __restrict__ bucketCur,
                                                     const unsigned* __restrict__ bE,
                                                     int* __restrict__ csrSrc,
                                                     int* __restrict__ degI,
                                                     int* __restrict__ cursor,
                                                     float* __restrict__ dinv) {
    __shared__ int sScan[512];
    __shared__ int sHist[256];
    __shared__ int sPre[256];
    __shared__ int sStart[256];
    int tid = threadIdx.x;
    int b = blockIdx.x;
    // --- exclusive prefix of bucket totals (391 values, 512-wide scan)
    int c = (tid < NBUCK) ? (bucketCur[tid] - tid * BCAP) : 0;
    sScan[tid] = c;
    __syncthreads();
    for (int off = 1; off < 512; off <<= 1) {
        int t = (tid >= off) ? sScan[tid - off] : 0;
        __syncthreads();
        sScan[tid] += t;
        __syncthreads();
    }
    int bbase = (b == 0) ? 0 : sScan[b - 1];   // LDS broadcast
    // --- per-node histogram of this bucket
    if (tid < 256) sHist[tid] = 0;
    __syncthreads();
    int start = b * BCAP;
    int end = bucketCur[b];
    for (int e = start + tid; e < end; e += 512) {
        unsigned v = bE[e];
        atomicAdd(&sHist[v >> 24], 1);
    }
    __syncthreads();
    // --- inclusive scan over 256 node counts
    if (tid < 256) sPre[tid] = sHist[tid];
    __syncthreads();
    for (int off = 1; off < 256; off <<= 1) {
        int t = (tid >= off && tid < 256) ? sPre[tid - off] : 0;
        __syncthreads();
        if (tid < 256) sPre[tid] += t;
        __syncthreads();
    }
    if (tid < 256) {
        int h = sHist[tid];
        int excl = sPre[tid] - h;
        int st = bbase + excl;
        sStart[tid] = st;
        int nd = (b << 8) + tid;
        if (nd < NN) {
            degI[nd] = h;
            cursor[nd] = st;
            dinv[nd] = rsqrtf((float)h + 1.0f);
        }
    }
    __syncthreads();
    // --- scatter into exact CSR
    for (int e = start + tid; e < end; e += 512) {
        unsigned v = bE[e];
        int pos = atomicAdd(&sStart[v >> 24], 1);
        csrSrc[pos] = (int)(v & 0xFFFFFFu);
    }
}

// ---------------------------------------------------------------- prep: fuse head linears + pre-pack ALL weights
// Packs each K x 64(48) f32 weight into MFMA B-fragment uint4 order:
// out[(c*NT+t)*64+lane], word w = bpack(W[row0+2w][col], W[row0+2w+1][col]),
// row0 = c*32+(lane>>4)*8, col = t*16+(lane&15).  GEMMs then load fragments
// as coalesced L2-hot uint4s (deletes per-block LDS staging + ushort build).
__global__ void prep_k(const float* __restrict__ W0, const float* __restrict__ W1,
                       const float* __restrict__ W2,
                       const float* __restrict__ mpW0, const float* __restrict__ mpb0,
                       const float* __restrict__ mpW1, const float* __restrict__ mpb1,
                       uint4* __restrict__ W0pk, uint4* __restrict__ W1pk,
                       uint4* __restrict__ W2pk, uint4* __restrict__ Wfpk,
                       float* __restrict__ bf) {
    __shared__ float sWf[64 * 48];
    int tid = threadIdx.x;
    // fuse the two head linears into sWf (64 x 48, cols >= DOUT zero)
    for (int i = tid; i < 64 * 48; i += 256) {
        int k = i / 48, n = i % 48;
        float acc = 0.f;
        if (n < DOUT) {
            for (int j = 0; j < 64; ++j) acc = fmaf(mpW0[k * 64 + j], mpW1[j * DOUT + n], acc);
        }
        sWf[i] = acc;
    }
    for (int n = tid; n < 48; n += 256) {
        float acc = 0.f;
        if (n < DOUT) {
            acc = mpb1[n];
            for (int j = 0; j < 64; ++j) acc = fmaf(mpb0[j], mpW1[j * DOUT + n], acc);
        }
        bf[n] = acc;
    }
    // W0: K=128, NT=4 -> 1024 uint4
    for (int i = tid; i < 1024; i += 256) {
        int lane = i & 63, ct = i >> 6;
        int q = lane >> 4, ln = lane & 15;
        int c = ct >> 2, t = ct & 3;
        int row0 = c * 32 + q * 8, col = t * 16 + ln;
        uint4 u;
        u.x = bpack(W0[(row0 + 0) * 64 + col], W0[(row0 + 1) * 64 + col]);
        u.y = bpack(W0[(row0 + 2) * 64 + col], W0[(row0 + 3) * 64 + col]);
        u.z = bpack(W0[(row0 + 4) * 64 + col], W0[(row0 + 5) * 64 + col]);
        u.w = bpack(W0[(row0 + 6) * 64 + col], W0[(row0 + 7) * 64 + col]);
        W0pk[i] = u;
    }
    // W1, W2: K=64, NT=4 -> 512 uint4 each
    for (int i = tid; i < 512; i += 256) {
        int lane = i & 63, ct = i >> 6;
        int q = lane >> 4, ln = lane & 15;
        int c = ct >> 2, t = ct & 3;
        int row0 = c * 32 + q * 8, col = t * 16 + ln;
        uint4 u;
        u.x = bpack(W1[(row0 + 0) * 64 + col], W1[(row0 + 1) * 64 + col]);
        u.y = bpack(W1[(row0 + 2) * 64 + col], W1[(row0 + 3) * 64 + col]);
        u.z = bpack(W1[(row0 + 4) * 64 + col], W1[(row0 + 5) * 64 + col]);
        u.w = bpack(W1[(row0 + 6) * 64 + col], W1[(row0 + 7) * 64 + col]);
        W1pk[i] = u;
        uint4 v;
        v.x = bpack(W2[(row0 + 0) * 64 + col], W2[(row0 + 1) * 64 + col]);
        v.y = bpack(W2[(row0 + 2) * 64 + col], W2[(row0 + 3) * 64 + col]);
        v.z = bpack(W2[(row0 + 4) * 64 + col], W2[(row0 + 5) * 64 + col]);
        v.w = bpack(W2[(row0 + 6) * 64 + col], W2[(row0 + 7) * 64 + col]);
        W2pk[i] = v;
    }
    __syncthreads();
    // Wf: K=64, NT=3 (48 cols) -> 384 uint4, from LDS
    for (int i = tid; i < 384; i += 256) {
        int lane = i & 63, ct = i >> 6;   // ct in 0..5
        int q = lane >> 4, ln = lane & 15;
        int c = ct / 3, t = ct % 3;
        int row0 = c * 32 + q * 8, col = t * 16 + ln;
        uint4 u;
        u.x = bpack(sWf[(row0 + 0) * 48 + col], sWf[(row0 + 1) * 48 + col]);
        u.y = bpack(sWf[(row0 + 2) * 48 + col], sWf[(row0 + 3) * 48 + col]);
        u.z = bpack(sWf[(row0 + 4) * 48 + col], sWf[(row0 + 5) * 48 + col]);
        u.w = bpack(sWf[(row0 + 6) * 48 + col], sWf[(row0 + 7) * 48 + col]);
        Wfpk[i] = u;
    }
}

// ---------------------------------------------------------------- MFMA GEMM layer 0 (f32 input): H' = bf16((X@W0)*dinv)
__global__ __launch_bounds__(256, 2) void gemm0(const float* __restrict__ X,
                                                const uint4* __restrict__ Wpk,
                                                const float* __restrict__ dinv,
                                                unsigned* __restrict__ H) {
    __shared__ float sD[64 * 65];
    int tid = threadIdx.x;
    int wv = tid >> 6, lane = tid & 63;
    int q = lane >> 4, ln = lane & 15;
    short8 bfrag[4][4];
#pragma unroll
    for (int c = 0; c < 4; ++c)
#pragma unroll
        for (int t = 0; t < 4; ++t)
            bfrag[c][t] = __builtin_bit_cast(short8, Wpk[(c * 4 + t) * 64 + lane]);
    int base = blockIdx.x * 64;
    int node = base + wv * 16 + ln;
    bool ok = node < NN;
    short8 afrag[4];
#pragma unroll
    for (int c = 0; c < 4; ++c) {
        float4 f0 = make_float4(0.f, 0.f, 0.f, 0.f);
        float4 f1 = make_float4(0.f, 0.f, 0.f, 0.f);
        if (ok) {
            const float4* xp = (const float4*)(X + (long)node * 128 + c * 32 + q * 8);
            f0 = xp[0];
            f1 = xp[1];
        }
        uint4 u;
        u.x = bpack(f0.x, f0.y);
        u.y = bpack(f0.z, f0.w);
        u.z = bpack(f1.x, f1.y);
        u.w = bpack(f1.z, f1.w);
        afrag[c] = __builtin_bit_cast(short8, u);
    }
#pragma unroll
    for (int t = 0; t < 4; ++t) {
        f32x4 acc = {0.f, 0.f, 0.f, 0.f};
#pragma unroll
        for (int c = 0; c < 4; ++c)
            acc = __builtin_amdgcn_mfma_f32_16x16x32_bf16(afrag[c], bfrag[c][t], acc, 0, 0, 0);
#pragma unroll
        for (int r = 0; r < 4; ++r)
            sD[(wv * 16 + q * 4 + r) * 65 + t * 16 + ln] = acc[r];
    }
    __syncthreads();
    for (int i = tid; i < 64 * 32; i += 256) {
        int row = i >> 5, c2 = i & 31;
        int nd = base + row;
        if (nd < NN) {
            float di = dinv[nd];
            float lo = sD[row * 65 + c2 * 2] * di;
            float hi = sD[row * 65 + c2 * 2 + 1] * di;
            H[nd * 32 + c2] = bpack(lo, hi);
        }
    }
}

// ---------------------------------------------------------------- MFMA GEMM (bf16 input): H' = bf16((Hin@W)*dinv)
__global__ __launch_bounds__(256, 2) void gemm_b(const uint4* __restrict__ Hin4,
                                                 const uint4* __restrict__ Wpk,
                                                 const float* __restrict__ dinv,
                                                 unsigned* __restrict__ H) {
    __shared__ float sD[64 * 65];
    int tid = threadIdx.x;
    int wv = tid >> 6, lane = tid & 63;
    int q = lane >> 4, ln = lane & 15;
    short8 bfrag[2][4];
#pragma unroll
    for (int c = 0; c < 2; ++c)
#pragma unroll
        for (int t = 0; t < 4; ++t)
            bfrag[c][t] = __builtin_bit_cast(short8, Wpk[(c * 4 + t) * 64 + lane]);
    int base = blockIdx.x * 64;
    int node = base + wv * 16 + ln;
    bool ok = node < NN;
    short8 afrag[2];
    {
        uint4 u0 = make_uint4(0u, 0u, 0u, 0u), u1 = u0;
        if (ok) {
            u0 = Hin4[(unsigned)node * 8u + (unsigned)q];        // feats q*8 .. q*8+7
            u1 = Hin4[(unsigned)node * 8u + 4u + (unsigned)q];   // feats 32+q*8 ..
        }
        afrag[0] = __builtin_bit_cast(short8, u0);
        afrag[1] = __builtin_bit_cast(short8, u1);
    }
#pragma unroll
    for (int t = 0; t < 4; ++t) {
        f32x4 acc = {0.f, 0.f, 0.f, 0.f};
        acc = __builtin_amdgcn_mfma_f32_16x16x32_bf16(afrag[0], bfrag[0][t], acc, 0, 0, 0);
        acc = __builtin_amdgcn_mfma_f32_16x16x32_bf16(afrag[1], bfrag[1][t], acc, 0, 0, 0);
#pragma unroll
        for (int r = 0; r < 4; ++r)
            sD[(wv * 16 + q * 4 + r) * 65 + t * 16 + ln] = acc[r];
    }
    __syncthreads();
    for (int i = tid; i < 64 * 32; i += 256) {
        int row = i >> 5, c2 = i & 31;
        int nd = base + row;
        if (nd < NN) {
            float di = dinv[nd];
            float lo = sD[row * 65 + c2 * 2] * di;
            float hi = sD[row * 65 + c2 * 2 + 1] * di;
            H[nd * 32 + c2] = bpack(lo, hi);
        }
    }
}

// ---------------------------------------------------------------- aggregate + bias + relu + optional LN -> packed bf16
// One wave per node; 16-lane group g handles edge 4r+g.  One coalesced
// csrSrc load covers edges 0..63; per-round indices via __shfl.  Deg is
// wave-uniform -> wave-uniform path split: deg<=16 runs 4 rounds (54% of
// Poisson(16) nodes; rounds 4-7 would add zeros), deg<=32 runs 8, rare
// deg>32 continues with uniform-trip loops.  All gathers of a path are
// issued before consumption (8 loads in flight).  __shfl only ever
// executes under full exec (round-8 lesson).
__global__ __launch_bounds__(256, 4) void agg_k(
        const int* __restrict__ cursor, const int* __restrict__ degI,
        const int* __restrict__ csrSrc, const float* __restrict__ dinv,
        const uint2* __restrict__ H2, const float4* __restrict__ bias4,
        const float4* __restrict__ g4, const float4* __restrict__ beta4,
        uint2* __restrict__ OUT2, int doLN) {
    int tid = threadIdx.x;
    int w = tid >> 6, lane = tid & 63;
    int g = lane >> 4;
    unsigned f = (unsigned)(lane & 15);
    unsigned node = (unsigned)(blockIdx.x * 4 + w);
    int start = cursor[node];
    int deg = degI[node];
    // one coalesced index load for the whole wave (edges 0..min(deg,64))
    int myIdx = 0;
    if (lane < deg) myIdx = csrSrc[(unsigned)(start + lane)];
    float ax = 0.f, ay = 0.f, az = 0.f, aw = 0.f;
    float bx = 0.f, by = 0.f, bz = 0.f, bw = 0.f;
    // ---- rounds 0..3 (edges 0..15): always issued, all in flight
    uint2 qa[4];
#pragma unroll
    for (int r = 0; r < 4; ++r) {
        int e = r * 4 + g;
        unsigned s = (unsigned)__shfl(myIdx, e);
        qa[r] = make_uint2(0u, 0u);
        if (e < deg) qa[r] = H2[s * 16u + f];
    }
    if (deg <= 16) {
#pragma unroll
        for (int r = 0; r < 4; r += 2) {
            ax += blo(qa[r].x);     ay += bhi(qa[r].x);
            az += blo(qa[r].y);     aw += bhi(qa[r].y);
            bx += blo(qa[r + 1].x); by += bhi(qa[r + 1].x);
            bz += blo(qa[r + 1].y); bw += bhi(qa[r + 1].y);
        }
    } else {
        // ---- rounds 4..7 (edges 16..31)
        uint2 qb[4];
#pragma unroll
        for (int r = 0; r < 4; ++r) {
            int e = 16 + r * 4 + g;
            unsigned s = (unsigned)__shfl(myIdx, e);
            qb[r] = make_uint2(0u, 0u);
            if (e < deg) qb[r] = H2[s * 16u + f];
        }
#pragma unroll
        for (int r = 0; r < 4; r += 2) {
            ax += blo(qa[r].x);     ay += bhi(qa[r].x);
            az += blo(qa[r].y);     aw += bhi(qa[r].y);
            bx += blo(qa[r + 1].x); by += bhi(qa[r + 1].x);
            bz += blo(qa[r + 1].y); bw += bhi(qa[r + 1].y);
        }
#pragma unroll
        for (int r = 0; r < 4; r += 2) {
            ax += blo(qb[r].x);     ay += bhi(qb[r].x);
            az += blo(qb[r].y);     aw += bhi(qb[r].y);
            bx += blo(qb[r + 1].x); by += bhi(qb[r + 1].x);
            bz += blo(qb[r + 1].y); bw += bhi(qb[r + 1].y);
        }
        // ---- rare deg in (32,64]: wave-uniform rounds (full exec for __shfl)
        if (deg > 32) {
            int R2 = (deg + 3) >> 2;
            if (R2 > 16) R2 = 16;
            for (int r = 8; r < R2; ++r) {
                int e = r * 4 + g;
                unsigned s = (unsigned)__shfl(myIdx, e);
                uint2 qq = make_uint2(0u, 0u);
                if (e < deg) qq = H2[s * 16u + f];
                ax += blo(qq.x); ay += bhi(qq.x); az += blo(qq.y); aw += bhi(qq.y);
            }
            // ---- deg > 64 global tail (no shuffle; divergence safe)
            for (int ee = 64 + g; ee < deg; ee += 4) {
                uint2 qq = H2[(unsigned)csrSrc[(unsigned)(start + ee)] * 16u + f];
                ax += blo(qq.x); ay += bhi(qq.x); az += blo(qq.y); aw += bhi(qq.y);
            }
        }
    }
    ax += bx; ay += by; az += bz; aw += bw;
    ax += __shfl_xor(ax, 16); ay += __shfl_xor(ay, 16);
    az += __shfl_xor(az, 16); aw += __shfl_xor(aw, 16);
    ax += __shfl_xor(ax, 32); ay += __shfl_xor(ay, 32);
    az += __shfl_xor(az, 32); aw += __shfl_xor(aw, 32);
    float di = dinv[node];
    uint2 qs = H2[node * 16u + f];
    float4 bb = bias4[f];
    float vx = fmaxf((ax + blo(qs.x)) * di + bb.x, 0.f);
    float vy = fmaxf((ay + bhi(qs.x)) * di + bb.y, 0.f);
    float vz = fmaxf((az + blo(qs.y)) * di + bb.z, 0.f);
    float vw = fmaxf((aw + bhi(qs.y)) * di + bb.w, 0.f);
    if (doLN) {
        float s = vx + vy + vz + vw;
        s += __shfl_xor(s, 1); s += __shfl_xor(s, 2);
        s += __shfl_xor(s, 4); s += __shfl_xor(s, 8);
        float mu = s * (1.f / 64.f);
        vx -= mu; vy -= mu; vz -= mu; vw -= mu;
        float vs = vx * vx + vy * vy + vz * vz + vw * vw;
        vs += __shfl_xor(vs, 1); vs += __shfl_xor(vs, 2);
        vs += __shfl_xor(vs, 4); vs += __shfl_xor(vs, 8);
        float inv = rsqrtf(vs * (1.f / 64.f) + LN_EPS);
        float4 gg = g4[f];
        float4 tt = beta4[f];
        vx = vx * inv * gg.x + tt.x;
        vy = vy * inv * gg.y + tt.y;
        vz = vz * inv * gg.z + tt.z;
        vw = vw * inv * gg.w + tt.w;
    }
    if (g == 0) OUT2[node * 16u + f] = make_uint2(bpack(vx, vy), bpack(vz, vw));
}

// ---------------------------------------------------------------- MLP head via MFMA: OUT = Hin @ Wf + bf (bf16 input)
__global__ __launch_bounds__(256, 2) void mlp_mfma(const uint4* __restrict__ Hin4,
                                                   const uint4* __restrict__ Wfpk,
                                                   const float* __restrict__ bf,
                                                   float* __restrict__ OUT) {
    int tid = threadIdx.x;
    int wv = tid >> 6, lane = tid & 63;
    int q = lane >> 4, ln = lane & 15;
    short8 bfrag[2][3];
#pragma unroll
    for (int c = 0; c < 2; ++c)
#pragma unroll
        for (int t = 0; t < 3; ++t)
            bfrag[c][t] = __builtin_bit_cast(short8, Wfpk[(c * 3 + t) * 64 + lane]);
    int base = blockIdx.x * 64;
    int node = base + wv * 16 + ln;
    bool ok = node < NN;
    short8 afrag[2];
    {
        uint4 u0 = make_uint4(0u, 0u, 0u, 0u), u1 = u0;
        if (ok) {
            u0 = Hin4[(unsigned)node * 8u + (unsigned)q];
            u1 = Hin4[(unsigned)node * 8u + 4u + (unsigned)q];
        }
        afrag[0] = __builtin_bit_cast(short8, u0);
        afrag[1] = __builtin_bit_cast(short8, u1);
    }
#pragma unroll
    for (int t = 0; t < 3; ++t) {
        f32x4 acc = {0.f, 0.f, 0.f, 0.f};
        acc = __builtin_amdgcn_mfma_f32_16x16x32_bf16(afrag[0], bfrag[0][t], acc, 0, 0, 0);
        acc = __builtin_amdgcn_mfma_f32_16x16x32_bf16(afrag[1], bfrag[1][t], acc, 0, 0, 0);
        int col = t * 16 + ln;
        if (col < DOUT) {
            float bv = bf[col];
#pragma unroll
            for (int r = 0; r < 4; ++r) {
                int nd = base + wv * 16 + q * 4 + r;
                if (nd < NN) OUT[(long)nd * DOUT + col] = acc[r] + bv;
            }
        }
    }
}

// ----------------------------------------------------------------
extern "C" void kernel_launch(void* const* d_in, const int* in_sizes, int n_in,
                              void* d_out, int out_size, void* d_ws, size_t ws_size,
                              hipStream_t stream) {
    const float* x    = (const float*)d_in[0];
    const int*   ei   = (const int*)d_in[1];
    const int*   srcI = ei;
    const int*   dstI = ei + EE;
    const float* W0   = (const float*)d_in[2];
    const float* b0   = (const float*)d_in[3];
    const float* W1   = (const float*)d_in[4];
    const float* b1   = (const float*)d_in[5];
    const float* W2   = (const float*)d_in[6];
    const float* b2   = (const float*)d_in[7];
    const float* ln0g = (const float*)d_in[8];
    const float* ln0b = (const float*)d_in[9];
    const float* ln1g = (const float*)d_in[10];
    const float* ln1b = (const float*)d_in[11];
    const float* mpW0 = (const float*)d_in[12];
    const float* mpb0 = (const float*)d_in[13];
    const float* mpW1 = (const float*)d_in[14];
    const float* mpb1 = (const float*)d_in[15];
    float* out = (float*)d_out;

    char* ws = (char*)d_ws;
    float*    dinv      = (float*)   (ws + 0);                      // 400 KB
    int*      degI      = (int*)     (ws + 512l * 1024);            // 400 KB
    int*      cursor    = (int*)     (ws + 1024l * 1024);           // 400 KB
    int*      bucketCur = (int*)     (ws + 1600l * 1024);
    uint4*    W0pk      = (uint4*)   (ws + 1792l * 1024);           // 16 KB
    uint4*    W1pk      = (uint4*)   (ws + 1824l * 1024);           // 8 KB
    uint4*    W2pk      = (uint4*)   (ws + 1856l * 1024);           // 8 KB
    uint4*    Wfpk      = (uint4*)   (ws + 1888l * 1024);           // 6 KB
    float*    bfv       = (float*)   (ws + 1920l * 1024);           // 192 B
    unsigned* bE        = (unsigned*)(ws + 2048l * 1024);           // 391*8192*4 = 12.8 MB
    int*      csrSrc    = (int*)     (ws + 15l * 1024 * 1024);      // 6.4 MB
    unsigned* bufA      = (unsigned*)(ws + 22l * 1024 * 1024);      // bf16 H' 12.8 MB
    unsigned* bufB      = (unsigned*)(ws + 36l * 1024 * 1024);      // bf16 hidden 12.8 MB

    const int aggBlocks  = NN / 4;             // 25000 exact
    const int gemmBlocks = (NN + 63) / 64;     // 1563

    binit_k<<<2, 256, 0, stream>>>(bucketCur);
    bucket_k<<<TBLK, 512, 0, stream>>>(srcI, dstI, bucketCur, bE);
    reorder2_k<<<NBUCK, 512, 0, stream>>>(bucketCur, bE, csrSrc, degI, cursor, dinv);
    prep_k<<<1, 256, 0, stream>>>(W0, W1, W2, mpW0, mpb0, mpW1, mpb1,
                                  W0pk, W1pk, W2pk, Wfpk, bfv);

    // layer 0 (f32 input)
    gemm0<<<gemmBlocks, 256, 0, stream>>>(x, W0pk, dinv, bufA);
    agg_k<<<aggBlocks, 256, 0, stream>>>(cursor, degI, csrSrc, dinv, (const uint2*)bufA,
                                         (const float4*)b0, (const float4*)ln0g,
                                         (const float4*)ln0b, (uint2*)bufB, 1);
    // layer 1 (bf16 hidden)
    gemm_b<<<gemmBlocks, 256, 0, stream>>>((const uint4*)bufB, W1pk, dinv, bufA);
    agg_k<<<aggBlocks, 256, 0, stream>>>(cursor, degI, csrSrc, dinv, (const uint2*)bufA,
                                         (const float4*)b1, (const float4*)ln1g,
                                         (const float4*)ln1b, (uint2*)bufB, 1);
    // layer 2 (no LN) then fused MLP head via MFMA
    gemm_b<<<gemmBlocks, 256, 0, stream>>>((const uint4*)bufB, W2pk, dinv, bufA);
    agg_k<<<aggBlocks, 256, 0, stream>>>(cursor, degI, csrSrc, dinv, (const uint2*)bufA,
                                         (const float4*)b2, (const float4*)ln0g,
                                         (const float4*)ln0b, (uint2*)bufB, 0);
    mlp_mfma<<<gemmBlocks, 256, 0, stream>>>((const uint4*)bufB, Wfpk, bfv, out);
}

// Round 12
// 328.303 us; speedup vs baseline: 6.9990x; 1.0425x over previous
//
#include <hip/hip_runtime.h>
#include <hip/hip_bf16.h>

#define NN 100000
#define EE 1600000
#define DOUT 40
#define LN_EPS 1e-5f
#define NBUCK 391  // buckets of 256 dst nodes
#define TILE 4096
#define TBLK 391   // ceil(EE/TILE)
#define BCAP 8192  // per-bucket capacity (expected 4092 +- 64)

typedef __attribute__((ext_vector_type(8))) short short8;   // 8 bf16 = 4 VGPRs
typedef __attribute__((ext_vector_type(4))) float f32x4;    // MFMA acc

// ---------------------------------------------------------------- bf16 helpers (RNE pack)
__device__ __forceinline__ float blo(unsigned u) { return __uint_as_float(u << 16); }
__device__ __forceinline__ float bhi(unsigned u) { return __uint_as_float(u & 0xffff0000u); }
__device__ __forceinline__ unsigned bpack(float lo, float hi) {
    unsigned a = __float_as_uint(lo);
    unsigned b = __float_as_uint(hi);
    a = (a + 0x7fffu + ((a >> 16) & 1u)) >> 16;
    b = (b + 0x7fffu + ((b >> 16) & 1u)) & 0xffff0000u;
    return (a & 0xffffu) | b;
}

// ---------------------------------------------------------------- bucket build
// 391 blocks x 512 threads x 8 edges (TILE=4096).  bucketCur holds RELATIVE
// counts (memset-0; absolute position = b*BCAP + rel) - binit kernel deleted.
// Pass 1: per-wave LDS histogram; one global atomic per nonzero bucket per
// block.  Pass 2: scatter into fixed-capacity bucket regions, per-wave
// sub-chunks (contiguous ~42B runs per bucket per block).
__global__ __launch_bounds__(512, 8) void bucket_k(const int* __restrict__ src,
                                                   const int* __restrict__ dst,
                                                   int* __restrict__ bucketCur,
                                                   unsigned* __restrict__ bE) {
    __shared__ int cnt[8][NBUCK];
    __shared__ int basew[8][NBUCK];
    int tid = threadIdx.x;
    int wv = tid >> 6;
    for (int i = tid; i < 8 * NBUCK; i += 512) ((int*)cnt)[i] = 0;
    __syncthreads();
    long e0 = (long)blockIdx.x * TILE;
    int d[8];
#pragma unroll
    for (int i = 0; i < 8; ++i) {
        long e = e0 + tid + i * 512;
        d[i] = (e < EE) ? dst[e] : -1;
    }
#pragma unroll
    for (int i = 0; i < 8; ++i) {
        if (d[i] >= 0) atomicAdd(&cnt[wv][d[i] >> 8], 1);
    }
    __syncthreads();
    for (int b = tid; b < NBUCK; b += 512) {
        int c[8];
        int tot = 0;
#pragma unroll
        for (int w = 0; w < 8; ++w) { c[w] = cnt[w][b]; tot += c[w]; }
        int base = tot ? atomicAdd(&bucketCur[b], tot) : 0;
        int run = b * BCAP + base;
#pragma unroll
        for (int w = 0; w < 8; ++w) { basew[w][b] = run; run += c[w]; cnt[w][b] = 0; }
    }
    __syncthreads();
#pragma unroll
    for (int i = 0; i < 8; ++i) {
        if (d[i] >= 0) {
            long e = e0 + tid + i * 512;
            int b = d[i] >> 8;
            int pos = basew[wv][b] + atomicAdd(&cnt[wv][b], 1);
            bE[pos] = (unsigned)src[e] | ((unsigned)(d[i] & 255) << 24);
        }
    }
}

// ---------------------------------------------------------------- bucket -> exact CSR + degI + cursor + dinv
__global__ __launch_bounds__(512, 4) void reorder2_k(const int* __restrict__ bucketCur,
                                                     const unsigned* __restrict__ bE,
                                                     int* __restrict__ csrSrc,
                                                     int* __restrict__ degI,
                                                     int* __restrict__ cursor,
                                                     float* __restrict__ dinv) {
    __shared__ int sScan[512];
    __shared__ int sHist[256];
    __shared__ int sPre[256];
    __shared__ int sStart[256];
    int tid = threadIdx.x;
    int b = blockIdx.x;
    // --- exclusive prefix of bucket totals (391 relative counts, 512-wide scan)
    int c = (tid < NBUCK) ? bucketCur[tid] : 0;
    sScan[tid] = c;
    __syncthreads();
    for (int off = 1; off < 512; off <<= 1) {
        int t = (tid >= off) ? sScan[tid - off] : 0;
        __syncthreads();
        sScan[tid] += t;
        __syncthreads();
    }
    int bbase = (b == 0) ? 0 : sScan[b - 1];   // LDS broadcast
    // --- per-node histogram of this bucket
    if (tid < 256) sHist[tid] = 0;
    __syncthreads();
    int start = b * BCAP;
    int end = start + bucketCur[b];
    for (int e = start + tid; e < end; e += 512) {
        unsigned v = bE[e];
        atomicAdd(&sHist[v >> 24], 1);
    }
    __syncthreads();
    // --- inclusive scan over 256 node counts
    if (tid < 256) sPre[tid] = sHist[tid];
    __syncthreads();
    for (int off = 1; off < 256; off <<= 1) {
        int t = (tid >= off && tid < 256) ? sPre[tid - off] : 0;
        __syncthreads();
        if (tid < 256) sPre[tid] += t;
        __syncthreads();
    }
    if (tid < 256) {
        int h = sHist[tid];
        int excl = sPre[tid] - h;
        int st = bbase + excl;
        sStart[tid] = st;
        int nd = (b << 8) + tid;
        if (nd < NN) {
            degI[nd] = h;
            cursor[nd] = st;
            dinv[nd] = rsqrtf((float)h + 1.0f);
        }
    }
    __syncthreads();
    // --- scatter into exact CSR
    for (int e = start + tid; e < end; e += 512) {
        unsigned v = bE[e];
        int pos = atomicAdd(&sStart[v >> 24], 1);
        csrSrc[pos] = (int)(v & 0xFFFFFFu);
    }
}

// ---------------------------------------------------------------- prep: fuse head linears + pre-pack ALL weights
// Packs each K x 64(48) f32 weight into MFMA B-fragment uint4 order:
// out[(c*NT+t)*64+lane], word w = bpack(W[row0+2w][col], W[row0+2w+1][col]),
// row0 = c*32+(lane>>4)*8, col = t*16+(lane&15).  GEMMs then load fragments
// as coalesced L2-hot uint4s (deletes per-block LDS staging + ushort build).
__global__ void prep_k(const float* __restrict__ W0, const float* __restrict__ W1,
                       const float* __restrict__ W2,
                       const float* __restrict__ mpW0, const float* __restrict__ mpb0,
                       const float* __restrict__ mpW1, const float* __restrict__ mpb1,
                       uint4* __restrict__ W0pk, uint4* __restrict__ W1pk,
                       uint4* __restrict__ W2pk, uint4* __restrict__ Wfpk,
                       float* __restrict__ bf) {
    __shared__ float sWf[64 * 48];
    int tid = threadIdx.x;
    // fuse the two head linears into sWf (64 x 48, cols >= DOUT zero)
    for (int i = tid; i < 64 * 48; i += 256) {
        int k = i / 48, n = i % 48;
        float acc = 0.f;
        if (n < DOUT) {
            for (int j = 0; j < 64; ++j) acc = fmaf(mpW0[k * 64 + j], mpW1[j * DOUT + n], acc);
        }
        sWf[i] = acc;
    }
    for (int n = tid; n < 48; n += 256) {
        float acc = 0.f;
        if (n < DOUT) {
            acc = mpb1[n];
            for (int j = 0; j < 64; ++j) acc = fmaf(mpb0[j], mpW1[j * DOUT + n], acc);
        }
        bf[n] = acc;
    }
    // W0: K=128, NT=4 -> 1024 uint4
    for (int i = tid; i < 1024; i += 256) {
        int lane = i & 63, ct = i >> 6;
        int q = lane >> 4, ln = lane & 15;
        int c = ct >> 2, t = ct & 3;
        int row0 = c * 32 + q * 8, col = t * 16 + ln;
        uint4 u;
        u.x = bpack(W0[(row0 + 0) * 64 + col], W0[(row0 + 1) * 64 + col]);
        u.y = bpack(W0[(row0 + 2) * 64 + col], W0[(row0 + 3) * 64 + col]);
        u.z = bpack(W0[(row0 + 4) * 64 + col], W0[(row0 + 5) * 64 + col]);
        u.w = bpack(W0[(row0 + 6) * 64 + col], W0[(row0 + 7) * 64 + col]);
        W0pk[i] = u;
    }
    // W1, W2: K=64, NT=4 -> 512 uint4 each
    for (int i = tid; i < 512; i += 256) {
        int lane = i & 63, ct = i >> 6;
        int q = lane >> 4, ln = lane & 15;
        int c = ct >> 2, t = ct & 3;
        int row0 = c * 32 + q * 8, col = t * 16 + ln;
        uint4 u;
        u.x = bpack(W1[(row0 + 0) * 64 + col], W1[(row0 + 1) * 64 + col]);
        u.y = bpack(W1[(row0 + 2) * 64 + col], W1[(row0 + 3) * 64 + col]);
        u.z = bpack(W1[(row0 + 4) * 64 + col], W1[(row0 + 5) * 64 + col]);
        u.w = bpack(W1[(row0 + 6) * 64 + col], W1[(row0 + 7) * 64 + col]);
        W1pk[i] = u;
        uint4 v;
        v.x = bpack(W2[(row0 + 0) * 64 + col], W2[(row0 + 1) * 64 + col]);
        v.y = bpack(W2[(row0 + 2) * 64 + col], W2[(row0 + 3) * 64 + col]);
        v.z = bpack(W2[(row0 + 4) * 64 + col], W2[(row0 + 5) * 64 + col]);
        v.w = bpack(W2[(row0 + 6) * 64 + col], W2[(row0 + 7) * 64 + col]);
        W2pk[i] = v;
    }
    __syncthreads();
    // Wf: K=64, NT=3 (48 cols) -> 384 uint4, from LDS
    for (int i = tid; i < 384; i += 256) {
        int lane = i & 63, ct = i >> 6;   // ct in 0..5
        int q = lane >> 4, ln = lane & 15;
        int c = ct / 3, t = ct % 3;
        int row0 = c * 32 + q * 8, col = t * 16 + ln;
        uint4 u;
        u.x = bpack(sWf[(row0 + 0) * 48 + col], sWf[(row0 + 1) * 48 + col]);
        u.y = bpack(sWf[(row0 + 2) * 48 + col], sWf[(row0 + 3) * 48 + col]);
        u.z = bpack(sWf[(row0 + 4) * 48 + col], sWf[(row0 + 5) * 48 + col]);
        u.w = bpack(sWf[(row0 + 6) * 48 + col], sWf[(row0 + 7) * 48 + col]);
        Wfpk[i] = u;
    }
}

// ---------------------------------------------------------------- MFMA GEMM layer 0 (f32 input): H' = bf16((X@W0)*dinv)
__global__ __launch_bounds__(256, 2) void gemm0(const float* __restrict__ X,
                                                const uint4* __restrict__ Wpk,
                                                const float* __restrict__ dinv,
                                                unsigned* __restrict__ H) {
    __shared__ float sD[64 * 65];
    int tid = threadIdx.x;
    int wv = tid >> 6, lane = tid & 63;
    int q = lane >> 4, ln = lane & 15;
    short8 bfrag[4][4];
#pragma unroll
    for (int c = 0; c < 4; ++c)
#pragma unroll
        for (int t = 0; t < 4; ++t)
            bfrag[c][t] = __builtin_bit_cast(short8, Wpk[(c * 4 + t) * 64 + lane]);
    int base = blockIdx.x * 64;
    int node = base + wv * 16 + ln;
    bool ok = node < NN;
    short8 afrag[4];
#pragma unroll
    for (int c = 0; c < 4; ++c) {
        float4 f0 = make_float4(0.f, 0.f, 0.f, 0.f);
        float4 f1 = make_float4(0.f, 0.f, 0.f, 0.f);
        if (ok) {
            const float4* xp = (const float4*)(X + (long)node * 128 + c * 32 + q * 8);
            f0 = xp[0];
            f1 = xp[1];
        }
        uint4 u;
        u.x = bpack(f0.x, f0.y);
        u.y = bpack(f0.z, f0.w);
        u.z = bpack(f1.x, f1.y);
        u.w = bpack(f1.z, f1.w);
        afrag[c] = __builtin_bit_cast(short8, u);
    }
#pragma unroll
    for (int t = 0; t < 4; ++t) {
        f32x4 acc = {0.f, 0.f, 0.f, 0.f};
#pragma unroll
        for (int c = 0; c < 4; ++c)
            acc = __builtin_amdgcn_mfma_f32_16x16x32_bf16(afrag[c], bfrag[c][t], acc, 0, 0, 0);
#pragma unroll
        for (int r = 0; r < 4; ++r)
            sD[(wv * 16 + q * 4 + r) * 65 + t * 16 + ln] = acc[r];
    }
    __syncthreads();
    for (int i = tid; i < 64 * 32; i += 256) {
        int row = i >> 5, c2 = i & 31;
        int nd = base + row;
        if (nd < NN) {
            float di = dinv[nd];
            float lo = sD[row * 65 + c2 * 2] * di;
            float hi = sD[row * 65 + c2 * 2 + 1] * di;
            H[nd * 32 + c2] = bpack(lo, hi);
        }
    }
}

// ---------------------------------------------------------------- MFMA GEMM (bf16 input): H' = bf16((Hin@W)*dinv)
__global__ __launch_bounds__(256, 2) void gemm_b(const uint4* __restrict__ Hin4,
                                                 const uint4* __restrict__ Wpk,
                                                 const float* __restrict__ dinv,
                                                 unsigned* __restrict__ H) {
    __shared__ float sD[64 * 65];
    int tid = threadIdx.x;
    int wv = tid >> 6, lane = tid & 63;
    int q = lane >> 4, ln = lane & 15;
    short8 bfrag[2][4];
#pragma unroll
    for (int c = 0; c < 2; ++c)
#pragma unroll
        for (int t = 0; t < 4; ++t)
            bfrag[c][t] = __builtin_bit_cast(short8, Wpk[(c * 4 + t) * 64 + lane]);
    int base = blockIdx.x * 64;
    int node = base + wv * 16 + ln;
    bool ok = node < NN;
    short8 afrag[2];
    {
        uint4 u0 = make_uint4(0u, 0u, 0u, 0u), u1 = u0;
        if (ok) {
            u0 = Hin4[(unsigned)node * 8u + (unsigned)q];        // feats q*8 .. q*8+7
            u1 = Hin4[(unsigned)node * 8u + 4u + (unsigned)q];   // feats 32+q*8 ..
        }
        afrag[0] = __builtin_bit_cast(short8, u0);
        afrag[1] = __builtin_bit_cast(short8, u1);
    }
#pragma unroll
    for (int t = 0; t < 4; ++t) {
        f32x4 acc = {0.f, 0.f, 0.f, 0.f};
        acc = __builtin_amdgcn_mfma_f32_16x16x32_bf16(afrag[0], bfrag[0][t], acc, 0, 0, 0);
        acc = __builtin_amdgcn_mfma_f32_16x16x32_bf16(afrag[1], bfrag[1][t], acc, 0, 0, 0);
#pragma unroll
        for (int r = 0; r < 4; ++r)
            sD[(wv * 16 + q * 4 + r) * 65 + t * 16 + ln] = acc[r];
    }
    __syncthreads();
    for (int i = tid; i < 64 * 32; i += 256) {
        int row = i >> 5, c2 = i & 31;
        int nd = base + row;
        if (nd < NN) {
            float di = dinv[nd];
            float lo = sD[row * 65 + c2 * 2] * di;
            float hi = sD[row * 65 + c2 * 2 + 1] * di;
            H[nd * 32 + c2] = bpack(lo, hi);
        }
    }
}

// ---------------------------------------------------------------- aggregate + bias + relu + optional LN -> packed bf16
// One wave per node; 16-lane group g handles edge 4r+g.  One coalesced
// csrSrc load covers edges 0..63; per-round indices via __shfl.  Deg is
// wave-uniform -> wave-uniform path split (deg<=16: 4 rounds, <=32: 8).
// Self-row / dinv / bias loads are issued BEFORE the edge loop so their
// latency hides under the gathers (they were a dependent tail).  __shfl
// only ever executes under full exec (round-8 lesson).
__global__ __launch_bounds__(256, 4) void agg_k(
        const int* __restrict__ cursor, const int* __restrict__ degI,
        const int* __restrict__ csrSrc, const float* __restrict__ dinv,
        const uint2* __restrict__ H2, const float4* __restrict__ bias4,
        const float4* __restrict__ g4, const float4* __restrict__ beta4,
        uint2* __restrict__ OUT2, int doLN) {
    int tid = threadIdx.x;
    int w = tid >> 6, lane = tid & 63;
    int g = lane >> 4;
    unsigned f = (unsigned)(lane & 15);
    unsigned node = (unsigned)(blockIdx.x * 4 + w);
    int start = cursor[node];
    int deg = degI[node];
    // issue the independent loads up front: edge indices, self row, dinv, bias
    int myIdx = 0;
    if (lane < deg) myIdx = csrSrc[(unsigned)(start + lane)];
    uint2 qs = H2[node * 16u + f];
    float di = dinv[node];
    float4 bb = bias4[f];
    float ax = 0.f, ay = 0.f, az = 0.f, aw = 0.f;
    float bx = 0.f, by = 0.f, bz = 0.f, bw = 0.f;
    // ---- rounds 0..3 (edges 0..15): always issued, all in flight
    uint2 qa[4];
#pragma unroll
    for (int r = 0; r < 4; ++r) {
        int e = r * 4 + g;
        unsigned s = (unsigned)__shfl(myIdx, e);
        qa[r] = make_uint2(0u, 0u);
        if (e < deg) qa[r] = H2[s * 16u + f];
    }
    if (deg <= 16) {
#pragma unroll
        for (int r = 0; r < 4; r += 2) {
            ax += blo(qa[r].x);     ay += bhi(qa[r].x);
            az += blo(qa[r].y);     aw += bhi(qa[r].y);
            bx += blo(qa[r + 1].x); by += bhi(qa[r + 1].x);
            bz += blo(qa[r + 1].y); bw += bhi(qa[r + 1].y);
        }
    } else {
        // ---- rounds 4..7 (edges 16..31)
        uint2 qb[4];
#pragma unroll
        for (int r = 0; r < 4; ++r) {
            int e = 16 + r * 4 + g;
            unsigned s = (unsigned)__shfl(myIdx, e);
            qb[r] = make_uint2(0u, 0u);
            if (e < deg) qb[r] = H2[s * 16u + f];
        }
#pragma unroll
        for (int r = 0; r < 4; r += 2) {
            ax += blo(qa[r].x);     ay += bhi(qa[r].x);
            az += blo(qa[r].y);     aw += bhi(qa[r].y);
            bx += blo(qa[r + 1].x); by += bhi(qa[r + 1].x);
            bz += blo(qa[r + 1].y); bw += bhi(qa[r + 1].y);
        }
#pragma unroll
        for (int r = 0; r < 4; r += 2) {
            ax += blo(qb[r].x);     ay += bhi(qb[r].x);
            az += blo(qb[r].y);     aw += bhi(qb[r].y);
            bx += blo(qb[r + 1].x); by += bhi(qb[r + 1].x);
            bz += blo(qb[r + 1].y); bw += bhi(qb[r + 1].y);
        }
        // ---- rare deg in (32,64]: wave-uniform rounds (full exec for __shfl)
        if (deg > 32) {
            int R2 = (deg + 3) >> 2;
            if (R2 > 16) R2 = 16;
            for (int r = 8; r < R2; ++r) {
                int e = r * 4 + g;
                unsigned s = (unsigned)__shfl(myIdx, e);
                uint2 qq = make_uint2(0u, 0u);
                if (e < deg) qq = H2[s * 16u + f];
                ax += blo(qq.x); ay += bhi(qq.x); az += blo(qq.y); aw += bhi(qq.y);
            }
            // ---- deg > 64 global tail (no shuffle; divergence safe)
            for (int ee = 64 + g; ee < deg; ee += 4) {
                uint2 qq = H2[(unsigned)csrSrc[(unsigned)(start + ee)] * 16u + f];
                ax += blo(qq.x); ay += bhi(qq.x); az += blo(qq.y); aw += bhi(qq.y);
            }
        }
    }
    ax += bx; ay += by; az += bz; aw += bw;
    ax += __shfl_xor(ax, 16); ay += __shfl_xor(ay, 16);
    az += __shfl_xor(az, 16); aw += __shfl_xor(aw, 16);
    ax += __shfl_xor(ax, 32); ay += __shfl_xor(ay, 32);
    az += __shfl_xor(az, 32); aw += __shfl_xor(aw, 32);
    float vx = fmaxf((ax + blo(qs.x)) * di + bb.x, 0.f);
    float vy = fmaxf((ay + bhi(qs.x)) * di + bb.y, 0.f);
    float vz = fmaxf((az + blo(qs.y)) * di + bb.z, 0.f);
    float vw = fmaxf((aw + bhi(qs.y)) * di + bb.w, 0.f);
    if (doLN) {
        float s = vx + vy + vz + vw;
        s += __shfl_xor(s, 1); s += __shfl_xor(s, 2);
        s += __shfl_xor(s, 4); s += __shfl_xor(s, 8);
        float mu = s * (1.f / 64.f);
        vx -= mu; vy -= mu; vz -= mu; vw -= mu;
        float vs = vx * vx + vy * vy + vz * vz + vw * vw;
        vs += __shfl_xor(vs, 1); vs += __shfl_xor(vs, 2);
        vs += __shfl_xor(vs, 4); vs += __shfl_xor(vs, 8);
        float inv = rsqrtf(vs * (1.f / 64.f) + LN_EPS);
        float4 gg = g4[f];
        float4 tt = beta4[f];
        vx = vx * inv * gg.x + tt.x;
        vy = vy * inv * gg.y + tt.y;
        vz = vz * inv * gg.z + tt.z;
        vw = vw * inv * gg.w + tt.w;
    }
    if (g == 0) OUT2[node * 16u + f] = make_uint2(bpack(vx, vy), bpack(vz, vw));
}

// ---------------------------------------------------------------- MLP head via MFMA: OUT = Hin @ Wf + bf (bf16 input)
__global__ __launch_bounds__(256, 2) void mlp_mfma(const uint4* __restrict__ Hin4,
                                                   const uint4* __restrict__ Wfpk,
                                                   const float* __restrict__ bf,
                                                   float* __restrict__ OUT) {
    int tid = threadIdx.x;
    int wv = tid >> 6, lane = tid & 63;
    int q = lane >> 4, ln = lane & 15;
    short8 bfrag[2][3];
#pragma unroll
    for (int c = 0; c < 2; ++c)
#pragma unroll
        for (int t = 0; t < 3; ++t)
            bfrag[c][t] = __builtin_bit_cast(short8, Wfpk[(c * 3 + t) * 64 + lane]);
    int base = blockIdx.x * 64;
    int node = base + wv * 16 + ln;
    bool ok = node < NN;
    short8 afrag[2];
    {
        uint4 u0 = make_uint4(0u, 0u, 0u, 0u), u1 = u0;
        if (ok) {
            u0 = Hin4[(unsigned)node * 8u + (unsigned)q];
            u1 = Hin4[(unsigned)node * 8u + 4u + (unsigned)q];
        }
        afrag[0] = __builtin_bit_cast(short8, u0);
        afrag[1] = __builtin_bit_cast(short8, u1);
    }
#pragma unroll
    for (int t = 0; t < 3; ++t) {
        f32x4 acc = {0.f, 0.f, 0.f, 0.f};
        acc = __builtin_amdgcn_mfma_f32_16x16x32_bf16(afrag[0], bfrag[0][t], acc, 0, 0, 0);
        acc = __builtin_amdgcn_mfma_f32_16x16x32_bf16(afrag[1], bfrag[1][t], acc, 0, 0, 0);
        int col = t * 16 + ln;
        if (col < DOUT) {
            float bv = bf[col];
#pragma unroll
            for (int r = 0; r < 4; ++r) {
                int nd = base + wv * 16 + q * 4 + r;
                if (nd < NN) OUT[(long)nd * DOUT + col] = acc[r] + bv;
            }
        }
    }
}

// ----------------------------------------------------------------
extern "C" void kernel_launch(void* const* d_in, const int* in_sizes, int n_in,
                              void* d_out, int out_size, void* d_ws, size_t ws_size,
                              hipStream_t stream) {
    const float* x    = (const float*)d_in[0];
    const int*   ei   = (const int*)d_in[1];
    const int*   srcI = ei;
    const int*   dstI = ei + EE;
    const float* W0   = (const float*)d_in[2];
    const float* b0   = (const float*)d_in[3];
    const float* W1   = (const float*)d_in[4];
    const float* b1   = (const float*)d_in[5];
    const float* W2   = (const float*)d_in[6];
    const float* b2   = (const float*)d_in[7];
    const float* ln0g = (const float*)d_in[8];
    const float* ln0b = (const float*)d_in[9];
    const float* ln1g = (const float*)d_in[10];
    const float* ln1b = (const float*)d_in[11];
    const float* mpW0 = (const float*)d_in[12];
    const float* mpb0 = (const float*)d_in[13];
    const float* mpW1 = (const float*)d_in[14];
    const float* mpb1 = (const float*)d_in[15];
    float* out = (float*)d_out;

    char* ws = (char*)d_ws;
    float*    dinv      = (float*)   (ws + 0);                      // 400 KB
    int*      degI      = (int*)     (ws + 512l * 1024);            // 400 KB
    int*      cursor    = (int*)     (ws + 1024l * 1024);           // 400 KB
    int*      bucketCur = (int*)     (ws + 1600l * 1024);
    uint4*    W0pk      = (uint4*)   (ws + 1792l * 1024);           // 16 KB
    uint4*    W1pk      = (uint4*)   (ws + 1824l * 1024);           // 8 KB
    uint4*    W2pk      = (uint4*)   (ws + 1856l * 1024);           // 8 KB
    uint4*    Wfpk      = (uint4*)   (ws + 1888l * 1024);           // 6 KB
    float*    bfv       = (float*)   (ws + 1920l * 1024);           // 192 B
    unsigned* bE        = (unsigned*)(ws + 2048l * 1024);           // 391*8192*4 = 12.8 MB
    int*      csrSrc    = (int*)     (ws + 15l * 1024 * 1024);      // 6.4 MB
    unsigned* bufA      = (unsigned*)(ws + 22l * 1024 * 1024);      // bf16 H' 12.8 MB
    unsigned* bufB      = (unsigned*)(ws + 36l * 1024 * 1024);      // bf16 hidden 12.8 MB

    const int aggBlocks  = NN / 4;             // 25000 exact
    const int gemmBlocks = (NN + 63) / 64;     // 1563

    hipMemsetAsync(bucketCur, 0, NBUCK * sizeof(int), stream);
    bucket_k<<<TBLK, 512, 0, stream>>>(srcI, dstI, bucketCur, bE);
    reorder2_k<<<NBUCK, 512, 0, stream>>>(bucketCur, bE, csrSrc, degI, cursor, dinv);
    prep_k<<<1, 256, 0, stream>>>(W0, W1, W2, mpW0, mpb0, mpW1, mpb1,
                                  W0pk, W1pk, W2pk, Wfpk, bfv);

    // layer 0 (f32 input)
    gemm0<<<gemmBlocks, 256, 0, stream>>>(x, W0pk, dinv, bufA);
    agg_k<<<aggBlocks, 256, 0, stream>>>(cursor, degI, csrSrc, dinv, (const uint2*)bufA,
                                         (const float4*)b0, (const float4*)ln0g,
                                         (const float4*)ln0b, (uint2*)bufB, 1);
    // layer 1 (bf16 hidden)
    gemm_b<<<gemmBlocks, 256, 0, stream>>>((const uint4*)bufB, W1pk, dinv, bufA);
    agg_k<<<aggBlocks, 256, 0, stream>>>(cursor, degI, csrSrc, dinv, (const uint2*)bufA,
                                         (const float4*)b1, (const float4*)ln1g,
                                         (const float4*)ln1b, (uint2*)bufB, 1);
    // layer 2 (no LN) then fused MLP head via MFMA
    gemm_b<<<gemmBlocks, 256, 0, stream>>>((const uint4*)bufB, W2pk, dinv, bufA);
    agg_k<<<aggBlocks, 256, 0, stream>>>(cursor, degI, csrSrc, dinv, (const uint2*)bufA,
                                         (const float4*)b2, (const float4*)ln0g,
                                         (const float4*)ln0b, (uint2*)bufB, 0);
    mlp_mfma<<<gemmBlocks, 256, 0, stream>>>((const uint4*)bufB, Wfpk, bfv, out);
}

// Round 13
// 312.300 us; speedup vs baseline: 7.3576x; 1.0512x over previous
//
#include <hip/hip_runtime.h>
#include <hip/hip_bf16.h>

#define NN 100000
#define EE 1600000
#define DOUT 40
#define LN_EPS 1e-5f
#define NBUCK 391  // buckets of 256 dst nodes
#define TILE 4096
#define TBLK 391   // ceil(EE/TILE)
#define BCAP 8192  // per-bucket capacity (expected 4092 +- 64)

typedef __attribute__((ext_vector_type(8))) short short8;   // 8 bf16 = 4 VGPRs
typedef __attribute__((ext_vector_type(4))) float f32x4;    // MFMA acc

// ---------------------------------------------------------------- bf16 helpers (RNE pack)
__device__ __forceinline__ float blo(unsigned u) { return __uint_as_float(u << 16); }
__device__ __forceinline__ float bhi(unsigned u) { return __uint_as_float(u & 0xffff0000u); }
__device__ __forceinline__ unsigned bpack(float lo, float hi) {
    unsigned a = __float_as_uint(lo);
    unsigned b = __float_as_uint(hi);
    a = (a + 0x7fffu + ((a >> 16) & 1u)) >> 16;
    b = (b + 0x7fffu + ((b >> 16) & 1u)) & 0xffff0000u;
    return (a & 0xffffu) | b;
}

// ---------------------------------------------------------------- bucket build (+ prep in last block)
// Blocks 0..TBLK-1: 512 threads x 8 edges (int4-vectorized reads; thread owns
// edges 4*(base4+tid)... remap is free - histogram/scatter are order-blind).
// bucketCur holds RELATIVE counts (memset-0; abs pos = b*BCAP + rel).
// Block TBLK: weight pre-pack + head-linear fusion (independent work,
// merged here to save one dispatch).
__global__ __launch_bounds__(512, 4) void bucket_k(
        const int* __restrict__ src, const int* __restrict__ dst,
        int* __restrict__ bucketCur, unsigned* __restrict__ bE,
        const float* __restrict__ W0, const float* __restrict__ W1,
        const float* __restrict__ W2,
        const float* __restrict__ mpW0, const float* __restrict__ mpb0,
        const float* __restrict__ mpW1, const float* __restrict__ mpb1,
        uint4* __restrict__ W0pk, uint4* __restrict__ W1pk,
        uint4* __restrict__ W2pk, uint4* __restrict__ Wfpk,
        float* __restrict__ bf) {
    __shared__ int cnt[8][NBUCK];
    __shared__ int basew[8][NBUCK];
    __shared__ float sWf[64 * 48];
    int tid = threadIdx.x;
    if (blockIdx.x == TBLK) {
        // ---------------- prep: fuse head linears + pre-pack all weights
        for (int i = tid; i < 64 * 48; i += 512) {
            int k = i / 48, n = i % 48;
            float acc = 0.f;
            if (n < DOUT) {
                for (int j = 0; j < 64; ++j) acc = fmaf(mpW0[k * 64 + j], mpW1[j * DOUT + n], acc);
            }
            sWf[i] = acc;
        }
        for (int n = tid; n < 48; n += 512) {
            float acc = 0.f;
            if (n < DOUT) {
                acc = mpb1[n];
                for (int j = 0; j < 64; ++j) acc = fmaf(mpb0[j], mpW1[j * DOUT + n], acc);
            }
            bf[n] = acc;
        }
        for (int i = tid; i < 1024; i += 512) {
            int lane = i & 63, ct = i >> 6;
            int q = lane >> 4, ln = lane & 15;
            int c = ct >> 2, t = ct & 3;
            int row0 = c * 32 + q * 8, col = t * 16 + ln;
            uint4 u;
            u.x = bpack(W0[(row0 + 0) * 64 + col], W0[(row0 + 1) * 64 + col]);
            u.y = bpack(W0[(row0 + 2) * 64 + col], W0[(row0 + 3) * 64 + col]);
            u.z = bpack(W0[(row0 + 4) * 64 + col], W0[(row0 + 5) * 64 + col]);
            u.w = bpack(W0[(row0 + 6) * 64 + col], W0[(row0 + 7) * 64 + col]);
            W0pk[i] = u;
        }
        for (int i = tid; i < 512; i += 512) {
            int lane = i & 63, ct = i >> 6;
            int q = lane >> 4, ln = lane & 15;
            int c = ct >> 2, t = ct & 3;
            int row0 = c * 32 + q * 8, col = t * 16 + ln;
            uint4 u;
            u.x = bpack(W1[(row0 + 0) * 64 + col], W1[(row0 + 1) * 64 + col]);
            u.y = bpack(W1[(row0 + 2) * 64 + col], W1[(row0 + 3) * 64 + col]);
            u.z = bpack(W1[(row0 + 4) * 64 + col], W1[(row0 + 5) * 64 + col]);
            u.w = bpack(W1[(row0 + 6) * 64 + col], W1[(row0 + 7) * 64 + col]);
            W1pk[i] = u;
            uint4 v;
            v.x = bpack(W2[(row0 + 0) * 64 + col], W2[(row0 + 1) * 64 + col]);
            v.y = bpack(W2[(row0 + 2) * 64 + col], W2[(row0 + 3) * 64 + col]);
            v.z = bpack(W2[(row0 + 4) * 64 + col], W2[(row0 + 5) * 64 + col]);
            v.w = bpack(W2[(row0 + 6) * 64 + col], W2[(row0 + 7) * 64 + col]);
            W2pk[i] = v;
        }
        __syncthreads();
        for (int i = tid; i < 384; i += 512) {
            int lane = i & 63, ct = i >> 6;   // ct in 0..5
            int q = lane >> 4, ln = lane & 15;
            int c = ct / 3, t = ct % 3;
            int row0 = c * 32 + q * 8, col = t * 16 + ln;
            uint4 u;
            u.x = bpack(sWf[(row0 + 0) * 48 + col], sWf[(row0 + 1) * 48 + col]);
            u.y = bpack(sWf[(row0 + 2) * 48 + col], sWf[(row0 + 3) * 48 + col]);
            u.z = bpack(sWf[(row0 + 4) * 48 + col], sWf[(row0 + 5) * 48 + col]);
            u.w = bpack(sWf[(row0 + 6) * 48 + col], sWf[(row0 + 7) * 48 + col]);
            Wfpk[i] = u;
        }
        return;
    }
    int wv = tid >> 6;
    for (int i = tid; i < 8 * NBUCK; i += 512) ((int*)cnt)[i] = 0;
    __syncthreads();
    // int4-vectorized edge loads: thread owns edges 4*(base4 + j*512 + tid) + k
    const int4* dst4 = (const int4*)dst;
    const int4* src4 = (const int4*)src;
    long base4 = (long)blockIdx.x * (TILE / 4);
    int d[8], s[8];
#pragma unroll
    for (int j = 0; j < 2; ++j) {
        long i4 = base4 + j * 512 + tid;
        int4 dv = make_int4(-1, -1, -1, -1);
        int4 sv = make_int4(0, 0, 0, 0);
        if (i4 < EE / 4) { dv = dst4[i4]; sv = src4[i4]; }
        d[j * 4 + 0] = dv.x; d[j * 4 + 1] = dv.y; d[j * 4 + 2] = dv.z; d[j * 4 + 3] = dv.w;
        s[j * 4 + 0] = sv.x; s[j * 4 + 1] = sv.y; s[j * 4 + 2] = sv.z; s[j * 4 + 3] = sv.w;
    }
#pragma unroll
    for (int i = 0; i < 8; ++i) {
        if (d[i] >= 0) atomicAdd(&cnt[wv][d[i] >> 8], 1);
    }
    __syncthreads();
    for (int b = tid; b < NBUCK; b += 512) {
        int c[8];
        int tot = 0;
#pragma unroll
        for (int w = 0; w < 8; ++w) { c[w] = cnt[w][b]; tot += c[w]; }
        int base = tot ? atomicAdd(&bucketCur[b], tot) : 0;
        int run = b * BCAP + base;
#pragma unroll
        for (int w = 0; w < 8; ++w) { basew[w][b] = run; run += c[w]; cnt[w][b] = 0; }
    }
    __syncthreads();
#pragma unroll
    for (int i = 0; i < 8; ++i) {
        if (d[i] >= 0) {
            int b = d[i] >> 8;
            int pos = basew[wv][b] + atomicAdd(&cnt[wv][b], 1);
            bE[pos] = (unsigned)s[i] | ((unsigned)(d[i] & 255) << 24);
        }
    }
}

// ---------------------------------------------------------------- bucket -> exact CSR + degI + cursor + dinv
__global__ __launch_bounds__(512, 4) void reorder2_k(const int* __restrict__ bucketCur,
                                                     const unsigned* __restrict__ bE,
                                                     int* __restrict__ csrSrc,
                                                     int* __restrict__ degI,
                                                     int* __restrict__ cursor,
                                                     float* __restrict__ dinv) {
    __shared__ int sScan[512];
    __shared__ int sHist[256];
    __shared__ int sPre[256];
    __shared__ int sStart[256];
    int tid = threadIdx.x;
    int b = blockIdx.x;
    // --- exclusive prefix of bucket totals (391 relative counts, 512-wide scan)
    int c = (tid < NBUCK) ? bucketCur[tid] : 0;
    sScan[tid] = c;
    __syncthreads();
    for (int off = 1; off < 512; off <<= 1) {
        int t = (tid >= off) ? sScan[tid - off] : 0;
        __syncthreads();
        sScan[tid] += t;
        __syncthreads();
    }
    int bbase = (b == 0) ? 0 : sScan[b - 1];   // LDS broadcast
    // --- per-node histogram of this bucket (uint4-vectorized, scalar tail)
    if (tid < 256) sHist[tid] = 0;
    __syncthreads();
    int start = b * BCAP;
    int ecnt = bucketCur[b];
    int nq = ecnt >> 2;
    const uint4* bE4 = (const uint4*)(bE + start);
    for (int i = tid; i < nq; i += 512) {
        uint4 v = bE4[i];
        atomicAdd(&sHist[v.x >> 24], 1);
        atomicAdd(&sHist[v.y >> 24], 1);
        atomicAdd(&sHist[v.z >> 24], 1);
        atomicAdd(&sHist[v.w >> 24], 1);
    }
    for (int e = (nq << 2) + tid; e < ecnt; e += 512) {
        atomicAdd(&sHist[bE[start + e] >> 24], 1);
    }
    __syncthreads();
    // --- inclusive scan over 256 node counts
    if (tid < 256) sPre[tid] = sHist[tid];
    __syncthreads();
    for (int off = 1; off < 256; off <<= 1) {
        int t = (tid >= off && tid < 256) ? sPre[tid - off] : 0;
        __syncthreads();
        if (tid < 256) sPre[tid] += t;
        __syncthreads();
    }
    if (tid < 256) {
        int h = sHist[tid];
        int excl = sPre[tid] - h;
        int st = bbase + excl;
        sStart[tid] = st;
        int nd = (b << 8) + tid;
        if (nd < NN) {
            degI[nd] = h;
            cursor[nd] = st;
            dinv[nd] = rsqrtf((float)h + 1.0f);
        }
    }
    __syncthreads();
    // --- scatter into exact CSR (uint4-vectorized, scalar tail)
    for (int i = tid; i < nq; i += 512) {
        uint4 v = bE4[i];
        int p0 = atomicAdd(&sStart[v.x >> 24], 1);
        csrSrc[p0] = (int)(v.x & 0xFFFFFFu);
        int p1 = atomicAdd(&sStart[v.y >> 24], 1);
        csrSrc[p1] = (int)(v.y & 0xFFFFFFu);
        int p2 = atomicAdd(&sStart[v.z >> 24], 1);
        csrSrc[p2] = (int)(v.z & 0xFFFFFFu);
        int p3 = atomicAdd(&sStart[v.w >> 24], 1);
        csrSrc[p3] = (int)(v.w & 0xFFFFFFu);
    }
    for (int e = (nq << 2) + tid; e < ecnt; e += 512) {
        unsigned v = bE[start + e];
        int pos = atomicAdd(&sStart[v >> 24], 1);
        csrSrc[pos] = (int)(v & 0xFFFFFFu);
    }
}

// ---------------------------------------------------------------- MFMA GEMM layer 0 (f32 input): H' = bf16((X@W0)*dinv)
// B-fragments loaded on demand (L2-hot) instead of preloaded: ~45 VGPR ->
// ~8 waves/SIMD so the 51 MB of HBM x-loads get full latency hiding.
__global__ __launch_bounds__(256, 4) void gemm0(const float* __restrict__ X,
                                                const uint4* __restrict__ Wpk,
                                                const float* __restrict__ dinv,
                                                unsigned* __restrict__ H) {
    __shared__ float sD[64 * 65];
    int tid = threadIdx.x;
    int wv = tid >> 6, lane = tid & 63;
    int q = lane >> 4, ln = lane & 15;
    int base = blockIdx.x * 64;
    int node = base + wv * 16 + ln;
    bool ok = node < NN;
    short8 afrag[4];
#pragma unroll
    for (int c = 0; c < 4; ++c) {
        float4 f0 = make_float4(0.f, 0.f, 0.f, 0.f);
        float4 f1 = make_float4(0.f, 0.f, 0.f, 0.f);
        if (ok) {
            const float4* xp = (const float4*)(X + (long)node * 128 + c * 32 + q * 8);
            f0 = xp[0];
            f1 = xp[1];
        }
        uint4 u;
        u.x = bpack(f0.x, f0.y);
        u.y = bpack(f0.z, f0.w);
        u.z = bpack(f1.x, f1.y);
        u.w = bpack(f1.z, f1.w);
        afrag[c] = __builtin_bit_cast(short8, u);
    }
#pragma unroll
    for (int t = 0; t < 4; ++t) {
        f32x4 acc = {0.f, 0.f, 0.f, 0.f};
#pragma unroll
        for (int c = 0; c < 4; ++c) {
            short8 bfrag = __builtin_bit_cast(short8, Wpk[(c * 4 + t) * 64 + lane]);
            acc = __builtin_amdgcn_mfma_f32_16x16x32_bf16(afrag[c], bfrag, acc, 0, 0, 0);
        }
#pragma unroll
        for (int r = 0; r < 4; ++r)
            sD[(wv * 16 + q * 4 + r) * 65 + t * 16 + ln] = acc[r];
    }
    __syncthreads();
    for (int i = tid; i < 64 * 32; i += 256) {
        int row = i >> 5, c2 = i & 31;
        int nd = base + row;
        if (nd < NN) {
            float di = dinv[nd];
            float lo = sD[row * 65 + c2 * 2] * di;
            float hi = sD[row * 65 + c2 * 2 + 1] * di;
            H[nd * 32 + c2] = bpack(lo, hi);
        }
    }
}

// ---------------------------------------------------------------- MFMA GEMM (bf16 input): H' = bf16((Hin@W)*dinv)
__global__ __launch_bounds__(256, 4) void gemm_b(const uint4* __restrict__ Hin4,
                                                 const uint4* __restrict__ Wpk,
                                                 const float* __restrict__ dinv,
                                                 unsigned* __restrict__ H) {
    __shared__ float sD[64 * 65];
    int tid = threadIdx.x;
    int wv = tid >> 6, lane = tid & 63;
    int q = lane >> 4, ln = lane & 15;
    int base = blockIdx.x * 64;
    int node = base + wv * 16 + ln;
    bool ok = node < NN;
    short8 afrag[2];
    {
        uint4 u0 = make_uint4(0u, 0u, 0u, 0u), u1 = u0;
        if (ok) {
            u0 = Hin4[(unsigned)node * 8u + (unsigned)q];        // feats q*8 .. q*8+7
            u1 = Hin4[(unsigned)node * 8u + 4u + (unsigned)q];   // feats 32+q*8 ..
        }
        afrag[0] = __builtin_bit_cast(short8, u0);
        afrag[1] = __builtin_bit_cast(short8, u1);
    }
#pragma unroll
    for (int t = 0; t < 4; ++t) {
        f32x4 acc = {0.f, 0.f, 0.f, 0.f};
#pragma unroll
        for (int c = 0; c < 2; ++c) {
            short8 bfrag = __builtin_bit_cast(short8, Wpk[(c * 4 + t) * 64 + lane]);
            acc = __builtin_amdgcn_mfma_f32_16x16x32_bf16(afrag[c], bfrag, acc, 0, 0, 0);
        }
#pragma unroll
        for (int r = 0; r < 4; ++r)
            sD[(wv * 16 + q * 4 + r) * 65 + t * 16 + ln] = acc[r];
    }
    __syncthreads();
    for (int i = tid; i < 64 * 32; i += 256) {
        int row = i >> 5, c2 = i & 31;
        int nd = base + row;
        if (nd < NN) {
            float di = dinv[nd];
            float lo = sD[row * 65 + c2 * 2] * di;
            float hi = sD[row * 65 + c2 * 2 + 1] * di;
            H[nd * 32 + c2] = bpack(lo, hi);
        }
    }
}

// ---------------------------------------------------------------- aggregate + bias + relu + optional LN -> packed bf16
// One wave per node; 16-lane group g handles edge 4r+g.  One coalesced
// csrSrc load covers edges 0..63; per-round indices via __shfl.  Deg is
// wave-uniform -> wave-uniform path split (deg<=16: 4 rounds, <=32: 8).
// Self-row / dinv / bias loads issued BEFORE the edge loop.  __shfl only
// ever executes under full exec (round-8 lesson).
__global__ __launch_bounds__(256, 4) void agg_k(
        const int* __restrict__ cursor, const int* __restrict__ degI,
        const int* __restrict__ csrSrc, const float* __restrict__ dinv,
        const uint2* __restrict__ H2, const float4* __restrict__ bias4,
        const float4* __restrict__ g4, const float4* __restrict__ beta4,
        uint2* __restrict__ OUT2, int doLN) {
    int tid = threadIdx.x;
    int w = tid >> 6, lane = tid & 63;
    int g = lane >> 4;
    unsigned f = (unsigned)(lane & 15);
    unsigned node = (unsigned)(blockIdx.x * 4 + w);
    int start = cursor[node];
    int deg = degI[node];
    // issue the independent loads up front: edge indices, self row, dinv, bias
    int myIdx = 0;
    if (lane < deg) myIdx = csrSrc[(unsigned)(start + lane)];
    uint2 qs = H2[node * 16u + f];
    float di = dinv[node];
    float4 bb = bias4[f];
    float ax = 0.f, ay = 0.f, az = 0.f, aw = 0.f;
    float bx = 0.f, by = 0.f, bz = 0.f, bw = 0.f;
    // ---- rounds 0..3 (edges 0..15): always issued, all in flight
    uint2 qa[4];
#pragma unroll
    for (int r = 0; r < 4; ++r) {
        int e = r * 4 + g;
        unsigned s = (unsigned)__shfl(myIdx, e);
        qa[r] = make_uint2(0u, 0u);
        if (e < deg) qa[r] = H2[s * 16u + f];
    }
    if (deg <= 16) {
#pragma unroll
        for (int r = 0; r < 4; r += 2) {
            ax += blo(qa[r].x);     ay += bhi(qa[r].x);
            az += blo(qa[r].y);     aw += bhi(qa[r].y);
            bx += blo(qa[r + 1].x); by += bhi(qa[r + 1].x);
            bz += blo(qa[r + 1].y); bw += bhi(qa[r + 1].y);
        }
    } else {
        // ---- rounds 4..7 (edges 16..31)
        uint2 qb[4];
#pragma unroll
        for (int r = 0; r < 4; ++r) {
            int e = 16 + r * 4 + g;
            unsigned s = (unsigned)__shfl(myIdx, e);
            qb[r] = make_uint2(0u, 0u);
            if (e < deg) qb[r] = H2[s * 16u + f];
        }
#pragma unroll
        for (int r = 0; r < 4; r += 2) {
            ax += blo(qa[r].x);     ay += bhi(qa[r].x);
            az += blo(qa[r].y);     aw += bhi(qa[r].y);
            bx += blo(qa[r + 1].x); by += bhi(qa[r + 1].x);
            bz += blo(qa[r + 1].y); bw += bhi(qa[r + 1].y);
        }
#pragma unroll
        for (int r = 0; r < 4; r += 2) {
            ax += blo(qb[r].x);     ay += bhi(qb[r].x);
            az += blo(qb[r].y);     aw += bhi(qb[r].y);
            bx += blo(qb[r + 1].x); by += bhi(qb[r + 1].x);
            bz += blo(qb[r + 1].y); bw += bhi(qb[r + 1].y);
        }
        // ---- rare deg in (32,64]: wave-uniform rounds (full exec for __shfl)
        if (deg > 32) {
            int R2 = (deg + 3) >> 2;
            if (R2 > 16) R2 = 16;
            for (int r = 8; r < R2; ++r) {
                int e = r * 4 + g;
                unsigned s = (unsigned)__shfl(myIdx, e);
                uint2 qq = make_uint2(0u, 0u);
                if (e < deg) qq = H2[s * 16u + f];
                ax += blo(qq.x); ay += bhi(qq.x); az += blo(qq.y); aw += bhi(qq.y);
            }
            // ---- deg > 64 global tail (no shuffle; divergence safe)
            for (int ee = 64 + g; ee < deg; ee += 4) {
                uint2 qq = H2[(unsigned)csrSrc[(unsigned)(start + ee)] * 16u + f];
                ax += blo(qq.x); ay += bhi(qq.x); az += blo(qq.y); aw += bhi(qq.y);
            }
        }
    }
    ax += bx; ay += by; az += bz; aw += bw;
    ax += __shfl_xor(ax, 16); ay += __shfl_xor(ay, 16);
    az += __shfl_xor(az, 16); aw += __shfl_xor(aw, 16);
    ax += __shfl_xor(ax, 32); ay += __shfl_xor(ay, 32);
    az += __shfl_xor(az, 32); aw += __shfl_xor(aw, 32);
    float vx = fmaxf((ax + blo(qs.x)) * di + bb.x, 0.f);
    float vy = fmaxf((ay + bhi(qs.x)) * di + bb.y, 0.f);
    float vz = fmaxf((az + blo(qs.y)) * di + bb.z, 0.f);
    float vw = fmaxf((aw + bhi(qs.y)) * di + bb.w, 0.f);
    if (doLN) {
        float s = vx + vy + vz + vw;
        s += __shfl_xor(s, 1); s += __shfl_xor(s, 2);
        s += __shfl_xor(s, 4); s += __shfl_xor(s, 8);
        float mu = s * (1.f / 64.f);
        vx -= mu; vy -= mu; vz -= mu; vw -= mu;
        float vs = vx * vx + vy * vy + vz * vz + vw * vw;
        vs += __shfl_xor(vs, 1); vs += __shfl_xor(vs, 2);
        vs += __shfl_xor(vs, 4); vs += __shfl_xor(vs, 8);
        float inv = rsqrtf(vs * (1.f / 64.f) + LN_EPS);
        float4 gg = g4[f];
        float4 tt = beta4[f];
        vx = vx * inv * gg.x + tt.x;
        vy = vy * inv * gg.y + tt.y;
        vz = vz * inv * gg.z + tt.z;
        vw = vw * inv * gg.w + tt.w;
    }
    if (g == 0) OUT2[node * 16u + f] = make_uint2(bpack(vx, vy), bpack(vz, vw));
}

// ---------------------------------------------------------------- MLP head via MFMA: OUT = Hin @ Wf + bf (bf16 input)
__global__ __launch_bounds__(256, 4) void mlp_mfma(const uint4* __restrict__ Hin4,
                                                   const uint4* __restrict__ Wfpk,
                                                   const float* __restrict__ bf,
                                                   float* __restrict__ OUT) {
    int tid = threadIdx.x;
    int wv = tid >> 6, lane = tid & 63;
    int q = lane >> 4, ln = lane & 15;
    int base = blockIdx.x * 64;
    int node = base + wv * 16 + ln;
    bool ok = node < NN;
    short8 afrag[2];
    {
        uint4 u0 = make_uint4(0u, 0u, 0u, 0u), u1 = u0;
        if (ok) {
            u0 = Hin4[(unsigned)node * 8u + (unsigned)q];
            u1 = Hin4[(unsigned)node * 8u + 4u + (unsigned)q];
        }
        afrag[0] = __builtin_bit_cast(short8, u0);
        afrag[1] = __builtin_bit_cast(short8, u1);
    }
#pragma unroll
    for (int t = 0; t < 3; ++t) {
        f32x4 acc = {0.f, 0.f, 0.f, 0.f};
#pragma unroll
        for (int c = 0; c < 2; ++c) {
            short8 bfrag = __builtin_bit_cast(short8, Wfpk[(c * 3 + t) * 64 + lane]);
            acc = __builtin_amdgcn_mfma_f32_16x16x32_bf16(afrag[c], bfrag, acc, 0, 0, 0);
        }
        int col = t * 16 + ln;
        if (col < DOUT) {
            float bv = bf[col];
#pragma unroll
            for (int r = 0; r < 4; ++r) {
                int nd = base + wv * 16 + q * 4 + r;
                if (nd < NN) OUT[(long)nd * DOUT + col] = acc[r] + bv;
            }
        }
    }
}

// ----------------------------------------------------------------
extern "C" void kernel_launch(void* const* d_in, const int* in_sizes, int n_in,
                              void* d_out, int out_size, void* d_ws, size_t ws_size,
                              hipStream_t stream) {
    const float* x    = (const float*)d_in[0];
    const int*   ei   = (const int*)d_in[1];
    const int*   srcI = ei;
    const int*   dstI = ei + EE;
    const float* W0   = (const float*)d_in[2];
    const float* b0   = (const float*)d_in[3];
    const float* W1   = (const float*)d_in[4];
    const float* b1   = (const float*)d_in[5];
    const float* W2   = (const float*)d_in[6];
    const float* b2   = (const float*)d_in[7];
    const float* ln0g = (const float*)d_in[8];
    const float* ln0b = (const float*)d_in[9];
    const float* ln1g = (const float*)d_in[10];
    const float* ln1b = (const float*)d_in[11];
    const float* mpW0 = (const float*)d_in[12];
    const float* mpb0 = (const float*)d_in[13];
    const float* mpW1 = (const float*)d_in[14];
    const float* mpb1 = (const float*)d_in[15];
    float* out = (float*)d_out;

    char* ws = (char*)d_ws;
    float*    dinv      = (float*)   (ws + 0);                      // 400 KB
    int*      degI      = (int*)     (ws + 512l * 1024);            // 400 KB
    int*      cursor    = (int*)     (ws + 1024l * 1024);           // 400 KB
    int*      bucketCur = (int*)     (ws + 1600l * 1024);
    uint4*    W0pk      = (uint4*)   (ws + 1792l * 1024);           // 16 KB
    uint4*    W1pk      = (uint4*)   (ws + 1824l * 1024);           // 8 KB
    uint4*    W2pk      = (uint4*)   (ws + 1856l * 1024);           // 8 KB
    uint4*    Wfpk      = (uint4*)   (ws + 1888l * 1024);           // 6 KB
    float*    bfv       = (float*)   (ws + 1920l * 1024);           // 192 B
    unsigned* bE        = (unsigned*)(ws + 2048l * 1024);           // 391*8192*4 = 12.8 MB
    int*      csrSrc    = (int*)     (ws + 15l * 1024 * 1024);      // 6.4 MB
    unsigned* bufA      = (unsigned*)(ws + 22l * 1024 * 1024);      // bf16 H' 12.8 MB
    unsigned* bufB      = (unsigned*)(ws + 36l * 1024 * 1024);      // bf16 hidden 12.8 MB

    const int aggBlocks  = NN / 4;             // 25000 exact
    const int gemmBlocks = (NN + 63) / 64;     // 1563

    hipMemsetAsync(bucketCur, 0, NBUCK * sizeof(int), stream);
    bucket_k<<<TBLK + 1, 512, 0, stream>>>(srcI, dstI, bucketCur, bE,
                                           W0, W1, W2, mpW0, mpb0, mpW1, mpb1,
                                           W0pk, W1pk, W2pk, Wfpk, bfv);
    reorder2_k<<<NBUCK, 512, 0, stream>>>(bucketCur, bE, csrSrc, degI, cursor, dinv);

    // layer 0 (f32 input)
    gemm0<<<gemmBlocks, 256, 0, stream>>>(x, W0pk, dinv, bufA);
    agg_k<<<aggBlocks, 256, 0, stream>>>(cursor, degI, csrSrc, dinv, (const uint2*)bufA,
                                         (const float4*)b0, (const float4*)ln0g,
                                         (const float4*)ln0b, (uint2*)bufB, 1);
    // layer 1 (bf16 hidden)
    gemm_b<<<gemmBlocks, 256, 0, stream>>>((const uint4*)bufB, W1pk, dinv, bufA);
    agg_k<<<aggBlocks, 256, 0, stream>>>(cursor, degI, csrSrc, dinv, (const uint2*)bufA,
                                         (const float4*)b1, (const float4*)ln1g,
                                         (const float4*)ln1b, (uint2*)bufB, 1);
    // layer 2 (no LN) then fused MLP head via MFMA
    gemm_b<<<gemmBlocks, 256, 0, stream>>>((const uint4*)bufB, W2pk, dinv, bufA);
    agg_k<<<aggBlocks, 256, 0, stream>>>(cursor, degI, csrSrc, dinv, (const uint2*)bufA,
                                         (const float4*)b2, (const float4*)ln0g,
                                         (const float4*)ln0b, (uint2*)bufB, 0);
    mlp_mfma<<<gemmBlocks, 256, 0, stream>>>((const uint4*)bufB, Wfpk, bfv, out);
}

// Round 14
// 311.073 us; speedup vs baseline: 7.3866x; 1.0039x over previous
//
#include <hip/hip_runtime.h>
#include <hip/hip_bf16.h>

#define NN 100000
#define EE 1600000
#define DOUT 40
#define LN_EPS 1e-5f
#define NBUCK 391  // buckets of 256 dst nodes
#define TILE 4096
#define TBLK 391   // ceil(EE/TILE)
#define BCAP 8192  // per-bucket capacity (expected 4092 +- 64)

typedef __attribute__((ext_vector_type(8))) short short8;   // 8 bf16 = 4 VGPRs
typedef __attribute__((ext_vector_type(4))) float f32x4;    // MFMA acc

// ---------------------------------------------------------------- bf16 helpers (RNE pack)
__device__ __forceinline__ float blo(unsigned u) { return __uint_as_float(u << 16); }
__device__ __forceinline__ float bhi(unsigned u) { return __uint_as_float(u & 0xffff0000u); }
__device__ __forceinline__ unsigned bpack(float lo, float hi) {
    unsigned a = __float_as_uint(lo);
    unsigned b = __float_as_uint(hi);
    a = (a + 0x7fffu + ((a >> 16) & 1u)) >> 16;
    b = (b + 0x7fffu + ((b >> 16) & 1u)) & 0xffff0000u;
    return (a & 0xffffu) | b;
}

// ---------------------------------------------------------------- bucket build (+ prep in last block)
// Blocks 0..TBLK-1: 1024 threads x 4 edges (one int4 pair per thread).
// 16 waves/block, 2 blocks/CU -> 32 waves/CU (round-13: 392x8-wave blocks
// = 1.5 blocks/CU = 10.7% occupancy was the bottleneck).  Two waves share
// one of 8 LDS histograms (hv = tid>>7).  bucketCur holds RELATIVE counts
// (memset-0; abs pos = b*BCAP + rel).  Block TBLK: weight pre-pack (sWf
// unioned onto basew - prep block never touches cnt/basew).
__global__ __launch_bounds__(1024, 4) void bucket_k(
        const int* __restrict__ src, const int* __restrict__ dst,
        int* __restrict__ bucketCur, unsigned* __restrict__ bE,
        const float* __restrict__ W0, const float* __restrict__ W1,
        const float* __restrict__ W2,
        const float* __restrict__ mpW0, const float* __restrict__ mpb0,
        const float* __restrict__ mpW1, const float* __restrict__ mpb1,
        uint4* __restrict__ W0pk, uint4* __restrict__ W1pk,
        uint4* __restrict__ W2pk, uint4* __restrict__ Wfpk,
        float* __restrict__ bf) {
    __shared__ int cnt[8][NBUCK];
    __shared__ int basew[8][NBUCK];
    int tid = threadIdx.x;
    if (blockIdx.x == TBLK) {
        // ---------------- prep: fuse head linears + pre-pack all weights
        float* sWf = (float*)&basew[0][0];   // 12512 B >= 64*48*4 = 12288 B
        for (int i = tid; i < 64 * 48; i += 1024) {
            int k = i / 48, n = i % 48;
            float acc = 0.f;
            if (n < DOUT) {
                for (int j = 0; j < 64; ++j) acc = fmaf(mpW0[k * 64 + j], mpW1[j * DOUT + n], acc);
            }
            sWf[i] = acc;
        }
        for (int n = tid; n < 48; n += 1024) {
            float acc = 0.f;
            if (n < DOUT) {
                acc = mpb1[n];
                for (int j = 0; j < 64; ++j) acc = fmaf(mpb0[j], mpW1[j * DOUT + n], acc);
            }
            bf[n] = acc;
        }
        for (int i = tid; i < 1024; i += 1024) {
            int lane = i & 63, ct = i >> 6;
            int q = lane >> 4, ln = lane & 15;
            int c = ct >> 2, t = ct & 3;
            int row0 = c * 32 + q * 8, col = t * 16 + ln;
            uint4 u;
            u.x = bpack(W0[(row0 + 0) * 64 + col], W0[(row0 + 1) * 64 + col]);
            u.y = bpack(W0[(row0 + 2) * 64 + col], W0[(row0 + 3) * 64 + col]);
            u.z = bpack(W0[(row0 + 4) * 64 + col], W0[(row0 + 5) * 64 + col]);
            u.w = bpack(W0[(row0 + 6) * 64 + col], W0[(row0 + 7) * 64 + col]);
            W0pk[i] = u;
        }
        for (int i = tid; i < 512; i += 1024) {
            int lane = i & 63, ct = i >> 6;
            int q = lane >> 4, ln = lane & 15;
            int c = ct >> 2, t = ct & 3;
            int row0 = c * 32 + q * 8, col = t * 16 + ln;
            uint4 u;
            u.x = bpack(W1[(row0 + 0) * 64 + col], W1[(row0 + 1) * 64 + col]);
            u.y = bpack(W1[(row0 + 2) * 64 + col], W1[(row0 + 3) * 64 + col]);
            u.z = bpack(W1[(row0 + 4) * 64 + col], W1[(row0 + 5) * 64 + col]);
            u.w = bpack(W1[(row0 + 6) * 64 + col], W1[(row0 + 7) * 64 + col]);
            W1pk[i] = u;
            uint4 v;
            v.x = bpack(W2[(row0 + 0) * 64 + col], W2[(row0 + 1) * 64 + col]);
            v.y = bpack(W2[(row0 + 2) * 64 + col], W2[(row0 + 3) * 64 + col]);
            v.z = bpack(W2[(row0 + 4) * 64 + col], W2[(row0 + 5) * 64 + col]);
            v.w = bpack(W2[(row0 + 6) * 64 + col], W2[(row0 + 7) * 64 + col]);
            W2pk[i] = v;
        }
        __syncthreads();
        for (int i = tid; i < 384; i += 1024) {
            int lane = i & 63, ct = i >> 6;   // ct in 0..5
            int q = lane >> 4, ln = lane & 15;
            int c = ct / 3, t = ct % 3;
            int row0 = c * 32 + q * 8, col = t * 16 + ln;
            uint4 u;
            u.x = bpack(sWf[(row0 + 0) * 48 + col], sWf[(row0 + 1) * 48 + col]);
            u.y = bpack(sWf[(row0 + 2) * 48 + col], sWf[(row0 + 3) * 48 + col]);
            u.z = bpack(sWf[(row0 + 4) * 48 + col], sWf[(row0 + 5) * 48 + col]);
            u.w = bpack(sWf[(row0 + 6) * 48 + col], sWf[(row0 + 7) * 48 + col]);
            Wfpk[i] = u;
        }
        return;
    }
    int hv = tid >> 7;   // 0..7, two waves share one histogram row
    for (int i = tid; i < 8 * NBUCK; i += 1024) ((int*)cnt)[i] = 0;
    __syncthreads();
    // one int4 pair per thread: edges 4*(blockIdx*1024 + tid) .. +3
    const int4* dst4 = (const int4*)dst;
    const int4* src4 = (const int4*)src;
    long i4 = (long)blockIdx.x * 1024 + tid;   // TILE/4 = 1024
    int4 dv = make_int4(-1, -1, -1, -1);
    int4 sv = make_int4(0, 0, 0, 0);
    if (i4 < EE / 4) { dv = dst4[i4]; sv = src4[i4]; }
    int d[4] = {dv.x, dv.y, dv.z, dv.w};
    int s[4] = {sv.x, sv.y, sv.z, sv.w};
#pragma unroll
    for (int i = 0; i < 4; ++i) {
        if (d[i] >= 0) atomicAdd(&cnt[hv][d[i] >> 8], 1);
    }
    __syncthreads();
    for (int b = tid; b < NBUCK; b += 1024) {
        int c[8];
        int tot = 0;
#pragma unroll
        for (int w = 0; w < 8; ++w) { c[w] = cnt[w][b]; tot += c[w]; }
        int base = tot ? atomicAdd(&bucketCur[b], tot) : 0;
        int run = b * BCAP + base;
#pragma unroll
        for (int w = 0; w < 8; ++w) { basew[w][b] = run; run += c[w]; cnt[w][b] = 0; }
    }
    __syncthreads();
#pragma unroll
    for (int i = 0; i < 4; ++i) {
        if (d[i] >= 0) {
            int b = d[i] >> 8;
            int pos = basew[hv][b] + atomicAdd(&cnt[hv][b], 1);
            bE[pos] = (unsigned)s[i] | ((unsigned)(d[i] & 255) << 24);
        }
    }
}

// ---------------------------------------------------------------- bucket -> exact CSR + degI + cursor + dinv
// 1024 threads (16 waves/block; round-13's 8-wave version was grid-limited).
__global__ __launch_bounds__(1024, 4) void reorder2_k(const int* __restrict__ bucketCur,
                                                      const unsigned* __restrict__ bE,
                                                      int* __restrict__ csrSrc,
                                                      int* __restrict__ degI,
                                                      int* __restrict__ cursor,
                                                      float* __restrict__ dinv) {
    __shared__ int sScan[512];
    __shared__ int sHist[256];
    __shared__ int sPre[256];
    __shared__ int sStart[256];
    int tid = threadIdx.x;
    int b = blockIdx.x;
    // --- exclusive prefix of bucket totals (391 relative counts, 512-wide scan)
    if (tid < 512) sScan[tid] = (tid < NBUCK) ? bucketCur[tid] : 0;
    __syncthreads();
    for (int off = 1; off < 512; off <<= 1) {
        int t = (tid >= off && tid < 512) ? sScan[tid - off] : 0;
        __syncthreads();
        if (tid < 512) sScan[tid] += t;
        __syncthreads();
    }
    int bbase = (b == 0) ? 0 : sScan[b - 1];   // LDS broadcast
    // --- per-node histogram of this bucket (uint4-vectorized, scalar tail)
    if (tid < 256) sHist[tid] = 0;
    __syncthreads();
    int start = b * BCAP;
    int ecnt = bucketCur[b];
    int nq = ecnt >> 2;
    const uint4* bE4 = (const uint4*)(bE + start);
    for (int i = tid; i < nq; i += 1024) {
        uint4 v = bE4[i];
        atomicAdd(&sHist[v.x >> 24], 1);
        atomicAdd(&sHist[v.y >> 24], 1);
        atomicAdd(&sHist[v.z >> 24], 1);
        atomicAdd(&sHist[v.w >> 24], 1);
    }
    for (int e = (nq << 2) + tid; e < ecnt; e += 1024) {
        atomicAdd(&sHist[bE[start + e] >> 24], 1);
    }
    __syncthreads();
    // --- inclusive scan over 256 node counts
    if (tid < 256) sPre[tid] = sHist[tid];
    __syncthreads();
    for (int off = 1; off < 256; off <<= 1) {
        int t = (tid >= off && tid < 256) ? sPre[tid - off] : 0;
        __syncthreads();
        if (tid < 256) sPre[tid] += t;
        __syncthreads();
    }
    if (tid < 256) {
        int h = sHist[tid];
        int excl = sPre[tid] - h;
        int st = bbase + excl;
        sStart[tid] = st;
        int nd = (b << 8) + tid;
        if (nd < NN) {
            degI[nd] = h;
            cursor[nd] = st;
            dinv[nd] = rsqrtf((float)h + 1.0f);
        }
    }
    __syncthreads();
    // --- scatter into exact CSR (uint4-vectorized, scalar tail)
    for (int i = tid; i < nq; i += 1024) {
        uint4 v = bE4[i];
        int p0 = atomicAdd(&sStart[v.x >> 24], 1);
        csrSrc[p0] = (int)(v.x & 0xFFFFFFu);
        int p1 = atomicAdd(&sStart[v.y >> 24], 1);
        csrSrc[p1] = (int)(v.y & 0xFFFFFFu);
        int p2 = atomicAdd(&sStart[v.z >> 24], 1);
        csrSrc[p2] = (int)(v.z & 0xFFFFFFu);
        int p3 = atomicAdd(&sStart[v.w >> 24], 1);
        csrSrc[p3] = (int)(v.w & 0xFFFFFFu);
    }
    for (int e = (nq << 2) + tid; e < ecnt; e += 1024) {
        unsigned v = bE[start + e];
        int pos = atomicAdd(&sStart[v >> 24], 1);
        csrSrc[pos] = (int)(v & 0xFFFFFFu);
    }
}

// ---------------------------------------------------------------- MFMA GEMM layer 0 (f32 input): H' = bf16((X@W0)*dinv)
// B-fragments loaded on demand (L2-hot): low VGPR -> 8 waves/SIMD so the
// 51 MB of HBM x-loads get full latency hiding.
__global__ __launch_bounds__(256, 4) void gemm0(const float* __restrict__ X,
                                                const uint4* __restrict__ Wpk,
                                                const float* __restrict__ dinv,
                                                unsigned* __restrict__ H) {
    __shared__ float sD[64 * 65];
    int tid = threadIdx.x;
    int wv = tid >> 6, lane = tid & 63;
    int q = lane >> 4, ln = lane & 15;
    int base = blockIdx.x * 64;
    int node = base + wv * 16 + ln;
    bool ok = node < NN;
    short8 afrag[4];
#pragma unroll
    for (int c = 0; c < 4; ++c) {
        float4 f0 = make_float4(0.f, 0.f, 0.f, 0.f);
        float4 f1 = make_float4(0.f, 0.f, 0.f, 0.f);
        if (ok) {
            const float4* xp = (const float4*)(X + (long)node * 128 + c * 32 + q * 8);
            f0 = xp[0];
            f1 = xp[1];
        }
        uint4 u;
        u.x = bpack(f0.x, f0.y);
        u.y = bpack(f0.z, f0.w);
        u.z = bpack(f1.x, f1.y);
        u.w = bpack(f1.z, f1.w);
        afrag[c] = __builtin_bit_cast(short8, u);
    }
#pragma unroll
    for (int t = 0; t < 4; ++t) {
        f32x4 acc = {0.f, 0.f, 0.f, 0.f};
#pragma unroll
        for (int c = 0; c < 4; ++c) {
            short8 bfrag = __builtin_bit_cast(short8, Wpk[(c * 4 + t) * 64 + lane]);
            acc = __builtin_amdgcn_mfma_f32_16x16x32_bf16(afrag[c], bfrag, acc, 0, 0, 0);
        }
#pragma unroll
        for (int r = 0; r < 4; ++r)
            sD[(wv * 16 + q * 4 + r) * 65 + t * 16 + ln] = acc[r];
    }
    __syncthreads();
    for (int i = tid; i < 64 * 32; i += 256) {
        int row = i >> 5, c2 = i & 31;
        int nd = base + row;
        if (nd < NN) {
            float di = dinv[nd];
            float lo = sD[row * 65 + c2 * 2] * di;
            float hi = sD[row * 65 + c2 * 2 + 1] * di;
            H[nd * 32 + c2] = bpack(lo, hi);
        }
    }
}

// ---------------------------------------------------------------- MFMA GEMM (bf16 input): H' = bf16((Hin@W)*dinv)
__global__ __launch_bounds__(256, 4) void gemm_b(const uint4* __restrict__ Hin4,
                                                 const uint4* __restrict__ Wpk,
                                                 const float* __restrict__ dinv,
                                                 unsigned* __restrict__ H) {
    __shared__ float sD[64 * 65];
    int tid = threadIdx.x;
    int wv = tid >> 6, lane = tid & 63;
    int q = lane >> 4, ln = lane & 15;
    int base = blockIdx.x * 64;
    int node = base + wv * 16 + ln;
    bool ok = node < NN;
    short8 afrag[2];
    {
        uint4 u0 = make_uint4(0u, 0u, 0u, 0u), u1 = u0;
        if (ok) {
            u0 = Hin4[(unsigned)node * 8u + (unsigned)q];        // feats q*8 .. q*8+7
            u1 = Hin4[(unsigned)node * 8u + 4u + (unsigned)q];   // feats 32+q*8 ..
        }
        afrag[0] = __builtin_bit_cast(short8, u0);
        afrag[1] = __builtin_bit_cast(short8, u1);
    }
#pragma unroll
    for (int t = 0; t < 4; ++t) {
        f32x4 acc = {0.f, 0.f, 0.f, 0.f};
#pragma unroll
        for (int c = 0; c < 2; ++c) {
            short8 bfrag = __builtin_bit_cast(short8, Wpk[(c * 4 + t) * 64 + lane]);
            acc = __builtin_amdgcn_mfma_f32_16x16x32_bf16(afrag[c], bfrag, acc, 0, 0, 0);
        }
#pragma unroll
        for (int r = 0; r < 4; ++r)
            sD[(wv * 16 + q * 4 + r) * 65 + t * 16 + ln] = acc[r];
    }
    __syncthreads();
    for (int i = tid; i < 64 * 32; i += 256) {
        int row = i >> 5, c2 = i & 31;
        int nd = base + row;
        if (nd < NN) {
            float di = dinv[nd];
            float lo = sD[row * 65 + c2 * 2] * di;
            float hi = sD[row * 65 + c2 * 2 + 1] * di;
            H[nd * 32 + c2] = bpack(lo, hi);
        }
    }
}

// ---------------------------------------------------------------- aggregate + bias + relu + optional LN -> packed bf16
// One wave per node; 16-lane group g handles edge 4r+g.  One coalesced
// csrSrc load covers edges 0..63; per-round indices via __shfl.  Deg is
// wave-uniform -> wave-uniform path split (deg<=16: 4 rounds, <=32: 8).
// Self-row / dinv / bias loads issued BEFORE the edge loop.  __shfl only
// ever executes under full exec (round-8 lesson).
__global__ __launch_bounds__(256, 4) void agg_k(
        const int* __restrict__ cursor, const int* __restrict__ degI,
        const int* __restrict__ csrSrc, const float* __restrict__ dinv,
        const uint2* __restrict__ H2, const float4* __restrict__ bias4,
        const float4* __restrict__ g4, const float4* __restrict__ beta4,
        uint2* __restrict__ OUT2, int doLN) {
    int tid = threadIdx.x;
    int w = tid >> 6, lane = tid & 63;
    int g = lane >> 4;
    unsigned f = (unsigned)(lane & 15);
    unsigned node = (unsigned)(blockIdx.x * 4 + w);
    int start = cursor[node];
    int deg = degI[node];
    // issue the independent loads up front: edge indices, self row, dinv, bias
    int myIdx = 0;
    if (lane < deg) myIdx = csrSrc[(unsigned)(start + lane)];
    uint2 qs = H2[node * 16u + f];
    float di = dinv[node];
    float4 bb = bias4[f];
    float ax = 0.f, ay = 0.f, az = 0.f, aw = 0.f;
    float bx = 0.f, by = 0.f, bz = 0.f, bw = 0.f;
    // ---- rounds 0..3 (edges 0..15): always issued, all in flight
    uint2 qa[4];
#pragma unroll
    for (int r = 0; r < 4; ++r) {
        int e = r * 4 + g;
        unsigned s = (unsigned)__shfl(myIdx, e);
        qa[r] = make_uint2(0u, 0u);
        if (e < deg) qa[r] = H2[s * 16u + f];
    }
    if (deg <= 16) {
#pragma unroll
        for (int r = 0; r < 4; r += 2) {
            ax += blo(qa[r].x);     ay += bhi(qa[r].x);
            az += blo(qa[r].y);     aw += bhi(qa[r].y);
            bx += blo(qa[r + 1].x); by += bhi(qa[r + 1].x);
            bz += blo(qa[r + 1].y); bw += bhi(qa[r + 1].y);
        }
    } else {
        // ---- rounds 4..7 (edges 16..31)
        uint2 qb[4];
#pragma unroll
        for (int r = 0; r < 4; ++r) {
            int e = 16 + r * 4 + g;
            unsigned s = (unsigned)__shfl(myIdx, e);
            qb[r] = make_uint2(0u, 0u);
            if (e < deg) qb[r] = H2[s * 16u + f];
        }
#pragma unroll
        for (int r = 0; r < 4; r += 2) {
            ax += blo(qa[r].x);     ay += bhi(qa[r].x);
            az += blo(qa[r].y);     aw += bhi(qa[r].y);
            bx += blo(qa[r + 1].x); by += bhi(qa[r + 1].x);
            bz += blo(qa[r + 1].y); bw += bhi(qa[r + 1].y);
        }
#pragma unroll
        for (int r = 0; r < 4; r += 2) {
            ax += blo(qb[r].x);     ay += bhi(qb[r].x);
            az += blo(qb[r].y);     aw += bhi(qb[r].y);
            bx += blo(qb[r + 1].x); by += bhi(qb[r + 1].x);
            bz += blo(qb[r + 1].y); bw += bhi(qb[r + 1].y);
        }
        // ---- rare deg in (32,64]: wave-uniform rounds (full exec for __shfl)
        if (deg > 32) {
            int R2 = (deg + 3) >> 2;
            if (R2 > 16) R2 = 16;
            for (int r = 8; r < R2; ++r) {
                int e = r * 4 + g;
                unsigned s = (unsigned)__shfl(myIdx, e);
                uint2 qq = make_uint2(0u, 0u);
                if (e < deg) qq = H2[s * 16u + f];
                ax += blo(qq.x); ay += bhi(qq.x); az += blo(qq.y); aw += bhi(qq.y);
            }
            // ---- deg > 64 global tail (no shuffle; divergence safe)
            for (int ee = 64 + g; ee < deg; ee += 4) {
                uint2 qq = H2[(unsigned)csrSrc[(unsigned)(start + ee)] * 16u + f];
                ax += blo(qq.x); ay += bhi(qq.x); az += blo(qq.y); aw += bhi(qq.y);
            }
        }
    }
    ax += bx; ay += by; az += bz; aw += bw;
    ax += __shfl_xor(ax, 16); ay += __shfl_xor(ay, 16);
    az += __shfl_xor(az, 16); aw += __shfl_xor(aw, 16);
    ax += __shfl_xor(ax, 32); ay += __shfl_xor(ay, 32);
    az += __shfl_xor(az, 32); aw += __shfl_xor(aw, 32);
    float vx = fmaxf((ax + blo(qs.x)) * di + bb.x, 0.f);
    float vy = fmaxf((ay + bhi(qs.x)) * di + bb.y, 0.f);
    float vz = fmaxf((az + blo(qs.y)) * di + bb.z, 0.f);
    float vw = fmaxf((aw + bhi(qs.y)) * di + bb.w, 0.f);
    if (doLN) {
        float s = vx + vy + vz + vw;
        s += __shfl_xor(s, 1); s += __shfl_xor(s, 2);
        s += __shfl_xor(s, 4); s += __shfl_xor(s, 8);
        float mu = s * (1.f / 64.f);
        vx -= mu; vy -= mu; vz -= mu; vw -= mu;
        float vs = vx * vx + vy * vy + vz * vz + vw * vw;
        vs += __shfl_xor(vs, 1); vs += __shfl_xor(vs, 2);
        vs += __shfl_xor(vs, 4); vs += __shfl_xor(vs, 8);
        float inv = rsqrtf(vs * (1.f / 64.f) + LN_EPS);
        float4 gg = g4[f];
        float4 tt = beta4[f];
        vx = vx * inv * gg.x + tt.x;
        vy = vy * inv * gg.y + tt.y;
        vz = vz * inv * gg.z + tt.z;
        vw = vw * inv * gg.w + tt.w;
    }
    if (g == 0) OUT2[node * 16u + f] = make_uint2(bpack(vx, vy), bpack(vz, vw));
}

// ---------------------------------------------------------------- MLP head via MFMA: OUT = Hin @ Wf + bf (bf16 input)
__global__ __launch_bounds__(256, 4) void mlp_mfma(const uint4* __restrict__ Hin4,
                                                   const uint4* __restrict__ Wfpk,
                                                   const float* __restrict__ bf,
                                                   float* __restrict__ OUT) {
    int tid = threadIdx.x;
    int wv = tid >> 6, lane = tid & 63;
    int q = lane >> 4, ln = lane & 15;
    int base = blockIdx.x * 64;
    int node = base + wv * 16 + ln;
    bool ok = node < NN;
    short8 afrag[2];
    {
        uint4 u0 = make_uint4(0u, 0u, 0u, 0u), u1 = u0;
        if (ok) {
            u0 = Hin4[(unsigned)node * 8u + (unsigned)q];
            u1 = Hin4[(unsigned)node * 8u + 4u + (unsigned)q];
        }
        afrag[0] = __builtin_bit_cast(short8, u0);
        afrag[1] = __builtin_bit_cast(short8, u1);
    }
#pragma unroll
    for (int t = 0; t < 3; ++t) {
        f32x4 acc = {0.f, 0.f, 0.f, 0.f};
#pragma unroll
        for (int c = 0; c < 2; ++c) {
            short8 bfrag = __builtin_bit_cast(short8, Wfpk[(c * 3 + t) * 64 + lane]);
            acc = __builtin_amdgcn_mfma_f32_16x16x32_bf16(afrag[c], bfrag, acc, 0, 0, 0);
        }
        int col = t * 16 + ln;
        if (col < DOUT) {
            float bv = bf[col];
#pragma unroll
            for (int r = 0; r < 4; ++r) {
                int nd = base + wv * 16 + q * 4 + r;
                if (nd < NN) OUT[(long)nd * DOUT + col] = acc[r] + bv;
            }
        }
    }
}

// ----------------------------------------------------------------
extern "C" void kernel_launch(void* const* d_in, const int* in_sizes, int n_in,
                              void* d_out, int out_size, void* d_ws, size_t ws_size,
                              hipStream_t stream) {
    const float* x    = (const float*)d_in[0];
    const int*   ei   = (const int*)d_in[1];
    const int*   srcI = ei;
    const int*   dstI = ei + EE;
    const float* W0   = (const float*)d_in[2];
    const float* b0   = (const float*)d_in[3];
    const float* W1   = (const float*)d_in[4];
    const float* b1   = (const float*)d_in[5];
    const float* W2   = (const float*)d_in[6];
    const float* b2   = (const float*)d_in[7];
    const float* ln0g = (const float*)d_in[8];
    const float* ln0b = (const float*)d_in[9];
    const float* ln1g = (const float*)d_in[10];
    const float* ln1b = (const float*)d_in[11];
    const float* mpW0 = (const float*)d_in[12];
    const float* mpb0 = (const float*)d_in[13];
    const float* mpW1 = (const float*)d_in[14];
    const float* mpb1 = (const float*)d_in[15];
    float* out = (float*)d_out;

    char* ws = (char*)d_ws;
    float*    dinv      = (float*)   (ws + 0);                      // 400 KB
    int*      degI      = (int*)     (ws + 512l * 1024);            // 400 KB
    int*      cursor    = (int*)     (ws + 1024l * 1024);           // 400 KB
    int*      bucketCur = (int*)     (ws + 1600l * 1024);
    uint4*    W0pk      = (uint4*)   (ws + 1792l * 1024);           // 16 KB
    uint4*    W1pk      = (uint4*)   (ws + 1824l * 1024);           // 8 KB
    uint4*    W2pk      = (uint4*)   (ws + 1856l * 1024);           // 8 KB
    uint4*    Wfpk      = (uint4*)   (ws + 1888l * 1024);           // 6 KB
    float*    bfv       = (float*)   (ws + 1920l * 1024);           // 192 B
    unsigned* bE        = (unsigned*)(ws + 2048l * 1024);           // 391*8192*4 = 12.8 MB
    int*      csrSrc    = (int*)     (ws + 15l * 1024 * 1024);      // 6.4 MB
    unsigned* bufA      = (unsigned*)(ws + 22l * 1024 * 1024);      // bf16 H' 12.8 MB
    unsigned* bufB      = (unsigned*)(ws + 36l * 1024 * 1024);      // bf16 hidden 12.8 MB

    const int aggBlocks  = NN / 4;             // 25000 exact
    const int gemmBlocks = (NN + 63) / 64;     // 1563

    hipMemsetAsync(bucketCur, 0, NBUCK * sizeof(int), stream);
    bucket_k<<<TBLK + 1, 1024, 0, stream>>>(srcI, dstI, bucketCur, bE,
                                            W0, W1, W2, mpW0, mpb0, mpW1, mpb1,
                                            W0pk, W1pk, W2pk, Wfpk, bfv);
    reorder2_k<<<NBUCK, 1024, 0, stream>>>(bucketCur, bE, csrSrc, degI, cursor, dinv);

    // layer 0 (f32 input)
    gemm0<<<gemmBlocks, 256, 0, stream>>>(x, W0pk, dinv, bufA);
    agg_k<<<aggBlocks, 256, 0, stream>>>(cursor, degI, csrSrc, dinv, (const uint2*)bufA,
                                         (const float4*)b0, (const float4*)ln0g,
                                         (const float4*)ln0b, (uint2*)bufB, 1);
    // layer 1 (bf16 hidden)
    gemm_b<<<gemmBlocks, 256, 0, stream>>>((const uint4*)bufB, W1pk, dinv, bufA);
    agg_k<<<aggBlocks, 256, 0, stream>>>(cursor, degI, csrSrc, dinv, (const uint2*)bufA,
                                         (const float4*)b1, (const float4*)ln1g,
                                         (const float4*)ln1b, (uint2*)bufB, 1);
    // layer 2 (no LN) then fused MLP head via MFMA
    gemm_b<<<gemmBlocks, 256, 0, stream>>>((const uint4*)bufB, W2pk, dinv, bufA);
    agg_k<<<aggBlocks, 256, 0, stream>>>(cursor, degI, csrSrc, dinv, (const uint2*)bufA,
                                         (const float4*)b2, (const float4*)ln0g,
                                         (const float4*)ln0b, (uint2*)bufB, 0);
    mlp_mfma<<<gemmBlocks, 256, 0, stream>>>((const uint4*)bufB, Wfpk, bfv, out);
}

// Round 15
// 307.948 us; speedup vs baseline: 7.4616x; 1.0101x over previous
//
#include <hip/hip_runtime.h>
#include <hip/hip_bf16.h>

#define NN 100000
#define EE 1600000
#define DOUT 40
#define LN_EPS 1e-5f
#define NBUCK 391  // buckets of 256 dst nodes
#define TILE 4096
#define TBLK 391   // ceil(EE/TILE)
#define BCAP 8192  // per-bucket capacity (expected 4092 +- 64)

typedef __attribute__((ext_vector_type(8))) short short8;   // 8 bf16 = 4 VGPRs
typedef __attribute__((ext_vector_type(4))) float f32x4;    // MFMA acc

// ---------------------------------------------------------------- bf16 helpers (RNE pack)
__device__ __forceinline__ float blo(unsigned u) { return __uint_as_float(u << 16); }
__device__ __forceinline__ float bhi(unsigned u) { return __uint_as_float(u & 0xffff0000u); }
__device__ __forceinline__ unsigned bpack(float lo, float hi) {
    unsigned a = __float_as_uint(lo);
    unsigned b = __float_as_uint(hi);
    a = (a + 0x7fffu + ((a >> 16) & 1u)) >> 16;
    b = (b + 0x7fffu + ((b >> 16) & 1u)) & 0xffff0000u;
    return (a & 0xffffu) | b;
}

// ---------------------------------------------------------------- bucket build (+ prep in last block)
// Blocks 0..TBLK-1: 1024 threads x 4 edges (one int4 pair per thread).
// Two waves share one of 8 LDS histograms (hv = tid>>7).  bucketCur holds
// RELATIVE counts (memset-0; abs pos = b*BCAP + rel).  Block TBLK: weight
// pre-pack (sWf unioned onto basew - prep block never touches cnt/basew).
__global__ __launch_bounds__(1024, 4) void bucket_k(
        const int* __restrict__ src, const int* __restrict__ dst,
        int* __restrict__ bucketCur, unsigned* __restrict__ bE,
        const float* __restrict__ W0, const float* __restrict__ W1,
        const float* __restrict__ W2,
        const float* __restrict__ mpW0, const float* __restrict__ mpb0,
        const float* __restrict__ mpW1, const float* __restrict__ mpb1,
        uint4* __restrict__ W0pk, uint4* __restrict__ W1pk,
        uint4* __restrict__ W2pk, uint4* __restrict__ Wfpk,
        float* __restrict__ bf) {
    __shared__ int cnt[8][NBUCK];
    __shared__ int basew[8][NBUCK];
    int tid = threadIdx.x;
    if (blockIdx.x == TBLK) {
        // ---------------- prep: fuse head linears + pre-pack all weights
        float* sWf = (float*)&basew[0][0];   // 12512 B >= 64*48*4 = 12288 B
        for (int i = tid; i < 64 * 48; i += 1024) {
            int k = i / 48, n = i % 48;
            float acc = 0.f;
            if (n < DOUT) {
                for (int j = 0; j < 64; ++j) acc = fmaf(mpW0[k * 64 + j], mpW1[j * DOUT + n], acc);
            }
            sWf[i] = acc;
        }
        for (int n = tid; n < 48; n += 1024) {
            float acc = 0.f;
            if (n < DOUT) {
                acc = mpb1[n];
                for (int j = 0; j < 64; ++j) acc = fmaf(mpb0[j], mpW1[j * DOUT + n], acc);
            }
            bf[n] = acc;
        }
        for (int i = tid; i < 1024; i += 1024) {
            int lane = i & 63, ct = i >> 6;
            int q = lane >> 4, ln = lane & 15;
            int c = ct >> 2, t = ct & 3;
            int row0 = c * 32 + q * 8, col = t * 16 + ln;
            uint4 u;
            u.x = bpack(W0[(row0 + 0) * 64 + col], W0[(row0 + 1) * 64 + col]);
            u.y = bpack(W0[(row0 + 2) * 64 + col], W0[(row0 + 3) * 64 + col]);
            u.z = bpack(W0[(row0 + 4) * 64 + col], W0[(row0 + 5) * 64 + col]);
            u.w = bpack(W0[(row0 + 6) * 64 + col], W0[(row0 + 7) * 64 + col]);
            W0pk[i] = u;
        }
        for (int i = tid; i < 512; i += 1024) {
            int lane = i & 63, ct = i >> 6;
            int q = lane >> 4, ln = lane & 15;
            int c = ct >> 2, t = ct & 3;
            int row0 = c * 32 + q * 8, col = t * 16 + ln;
            uint4 u;
            u.x = bpack(W1[(row0 + 0) * 64 + col], W1[(row0 + 1) * 64 + col]);
            u.y = bpack(W1[(row0 + 2) * 64 + col], W1[(row0 + 3) * 64 + col]);
            u.z = bpack(W1[(row0 + 4) * 64 + col], W1[(row0 + 5) * 64 + col]);
            u.w = bpack(W1[(row0 + 6) * 64 + col], W1[(row0 + 7) * 64 + col]);
            W1pk[i] = u;
            uint4 v;
            v.x = bpack(W2[(row0 + 0) * 64 + col], W2[(row0 + 1) * 64 + col]);
            v.y = bpack(W2[(row0 + 2) * 64 + col], W2[(row0 + 3) * 64 + col]);
            v.z = bpack(W2[(row0 + 4) * 64 + col], W2[(row0 + 5) * 64 + col]);
            v.w = bpack(W2[(row0 + 6) * 64 + col], W2[(row0 + 7) * 64 + col]);
            W2pk[i] = v;
        }
        __syncthreads();
        for (int i = tid; i < 384; i += 1024) {
            int lane = i & 63, ct = i >> 6;   // ct in 0..5
            int q = lane >> 4, ln = lane & 15;
            int c = ct / 3, t = ct % 3;
            int row0 = c * 32 + q * 8, col = t * 16 + ln;
            uint4 u;
            u.x = bpack(sWf[(row0 + 0) * 48 + col], sWf[(row0 + 1) * 48 + col]);
            u.y = bpack(sWf[(row0 + 2) * 48 + col], sWf[(row0 + 3) * 48 + col]);
            u.z = bpack(sWf[(row0 + 4) * 48 + col], sWf[(row0 + 5) * 48 + col]);
            u.w = bpack(sWf[(row0 + 6) * 48 + col], sWf[(row0 + 7) * 48 + col]);
            Wfpk[i] = u;
        }
        return;
    }
    int hv = tid >> 7;   // 0..7, two waves share one histogram row
    for (int i = tid; i < 8 * NBUCK; i += 1024) ((int*)cnt)[i] = 0;
    __syncthreads();
    const int4* dst4 = (const int4*)dst;
    const int4* src4 = (const int4*)src;
    long i4 = (long)blockIdx.x * 1024 + tid;   // TILE/4 = 1024
    int4 dv = make_int4(-1, -1, -1, -1);
    int4 sv = make_int4(0, 0, 0, 0);
    if (i4 < EE / 4) { dv = dst4[i4]; sv = src4[i4]; }
    int d[4] = {dv.x, dv.y, dv.z, dv.w};
    int s[4] = {sv.x, sv.y, sv.z, sv.w};
#pragma unroll
    for (int i = 0; i < 4; ++i) {
        if (d[i] >= 0) atomicAdd(&cnt[hv][d[i] >> 8], 1);
    }
    __syncthreads();
    for (int b = tid; b < NBUCK; b += 1024) {
        int c[8];
        int tot = 0;
#pragma unroll
        for (int w = 0; w < 8; ++w) { c[w] = cnt[w][b]; tot += c[w]; }
        int base = tot ? atomicAdd(&bucketCur[b], tot) : 0;
        int run = b * BCAP + base;
#pragma unroll
        for (int w = 0; w < 8; ++w) { basew[w][b] = run; run += c[w]; cnt[w][b] = 0; }
    }
    __syncthreads();
#pragma unroll
    for (int i = 0; i < 4; ++i) {
        if (d[i] >= 0) {
            int b = d[i] >> 8;
            int pos = basew[hv][b] + atomicAdd(&cnt[hv][b], 1);
            bE[pos] = (unsigned)s[i] | ((unsigned)(d[i] & 255) << 24);
        }
    }
}

// ---------------------------------------------------------------- bucket -> exact CSR + degI + cursor + dinv
__global__ __launch_bounds__(1024, 4) void reorder2_k(const int* __restrict__ bucketCur,
                                                      const unsigned* __restrict__ bE,
                                                      int* __restrict__ csrSrc,
                                                      int* __restrict__ degI,
                                                      int* __restrict__ cursor,
                                                      float* __restrict__ dinv) {
    __shared__ int sScan[512];
    __shared__ int sHist[256];
    __shared__ int sPre[256];
    __shared__ int sStart[256];
    int tid = threadIdx.x;
    int b = blockIdx.x;
    if (tid < 512) sScan[tid] = (tid < NBUCK) ? bucketCur[tid] : 0;
    __syncthreads();
    for (int off = 1; off < 512; off <<= 1) {
        int t = (tid >= off && tid < 512) ? sScan[tid - off] : 0;
        __syncthreads();
        if (tid < 512) sScan[tid] += t;
        __syncthreads();
    }
    int bbase = (b == 0) ? 0 : sScan[b - 1];   // LDS broadcast
    if (tid < 256) sHist[tid] = 0;
    __syncthreads();
    int start = b * BCAP;
    int ecnt = bucketCur[b];
    int nq = ecnt >> 2;
    const uint4* bE4 = (const uint4*)(bE + start);
    for (int i = tid; i < nq; i += 1024) {
        uint4 v = bE4[i];
        atomicAdd(&sHist[v.x >> 24], 1);
        atomicAdd(&sHist[v.y >> 24], 1);
        atomicAdd(&sHist[v.z >> 24], 1);
        atomicAdd(&sHist[v.w >> 24], 1);
    }
    for (int e = (nq << 2) + tid; e < ecnt; e += 1024) {
        atomicAdd(&sHist[bE[start + e] >> 24], 1);
    }
    __syncthreads();
    if (tid < 256) sPre[tid] = sHist[tid];
    __syncthreads();
    for (int off = 1; off < 256; off <<= 1) {
        int t = (tid >= off && tid < 256) ? sPre[tid - off] : 0;
        __syncthreads();
        if (tid < 256) sPre[tid] += t;
        __syncthreads();
    }
    if (tid < 256) {
        int h = sHist[tid];
        int excl = sPre[tid] - h;
        int st = bbase + excl;
        sStart[tid] = st;
        int nd = (b << 8) + tid;
        if (nd < NN) {
            degI[nd] = h;
            cursor[nd] = st;
            dinv[nd] = rsqrtf((float)h + 1.0f);
        }
    }
    __syncthreads();
    for (int i = tid; i < nq; i += 1024) {
        uint4 v = bE4[i];
        int p0 = atomicAdd(&sStart[v.x >> 24], 1);
        csrSrc[p0] = (int)(v.x & 0xFFFFFFu);
        int p1 = atomicAdd(&sStart[v.y >> 24], 1);
        csrSrc[p1] = (int)(v.y & 0xFFFFFFu);
        int p2 = atomicAdd(&sStart[v.z >> 24], 1);
        csrSrc[p2] = (int)(v.z & 0xFFFFFFu);
        int p3 = atomicAdd(&sStart[v.w >> 24], 1);
        csrSrc[p3] = (int)(v.w & 0xFFFFFFu);
    }
    for (int e = (nq << 2) + tid; e < ecnt; e += 1024) {
        unsigned v = bE[start + e];
        int pos = atomicAdd(&sStart[v >> 24], 1);
        csrSrc[pos] = (int)(v & 0xFFFFFFu);
    }
}

// ---------------------------------------------------------------- MFMA GEMM layer 0 (f32 input): H' = bf16((X@W0)*dinv)
__global__ __launch_bounds__(256, 4) void gemm0(const float* __restrict__ X,
                                                const uint4* __restrict__ Wpk,
                                                const float* __restrict__ dinv,
                                                unsigned* __restrict__ H) {
    __shared__ float sD[64 * 65];
    int tid = threadIdx.x;
    int wv = tid >> 6, lane = tid & 63;
    int q = lane >> 4, ln = lane & 15;
    int base = blockIdx.x * 64;
    int node = base + wv * 16 + ln;
    bool ok = node < NN;
    short8 afrag[4];
#pragma unroll
    for (int c = 0; c < 4; ++c) {
        float4 f0 = make_float4(0.f, 0.f, 0.f, 0.f);
        float4 f1 = make_float4(0.f, 0.f, 0.f, 0.f);
        if (ok) {
            const float4* xp = (const float4*)(X + (long)node * 128 + c * 32 + q * 8);
            f0 = xp[0];
            f1 = xp[1];
        }
        uint4 u;
        u.x = bpack(f0.x, f0.y);
        u.y = bpack(f0.z, f0.w);
        u.z = bpack(f1.x, f1.y);
        u.w = bpack(f1.z, f1.w);
        afrag[c] = __builtin_bit_cast(short8, u);
    }
#pragma unroll
    for (int t = 0; t < 4; ++t) {
        f32x4 acc = {0.f, 0.f, 0.f, 0.f};
#pragma unroll
        for (int c = 0; c < 4; ++c) {
            short8 bfrag = __builtin_bit_cast(short8, Wpk[(c * 4 + t) * 64 + lane]);
            acc = __builtin_amdgcn_mfma_f32_16x16x32_bf16(afrag[c], bfrag, acc, 0, 0, 0);
        }
#pragma unroll
        for (int r = 0; r < 4; ++r)
            sD[(wv * 16 + q * 4 + r) * 65 + t * 16 + ln] = acc[r];
    }
    __syncthreads();
    for (int i = tid; i < 64 * 32; i += 256) {
        int row = i >> 5, c2 = i & 31;
        int nd = base + row;
        if (nd < NN) {
            float di = dinv[nd];
            float lo = sD[row * 65 + c2 * 2] * di;
            float hi = sD[row * 65 + c2 * 2 + 1] * di;
            H[nd * 32 + c2] = bpack(lo, hi);
        }
    }
}

// ---------------------------------------------------------------- fused aggregate + relu (+LN) + NEXT-LAYER GEMM
// 1024 threads = 16 waves = 16 nodes/block (100000 = 6250*16 exact).
// Gather: one wave per node (round-9/10 structure, __shfl under full exec).
// Epilogue: the post-LN 64-vector is staged in LDS in the exact packed-H
// bit-layout, then waves 0..NT-1 run the same 16x16x32 MFMAs gemm_b ran
// (bit-identical operands) and write the next layer's H' (FINAL=0) or the
// head output with Wf+bf (FINAL=1).  Deletes gemm_b/mlp kernels + the
// entire inter-layer buffer round-trip.
template <int DOLN, int FINAL>
__global__ __launch_bounds__(1024, 8) void aggf_k(
        const int* __restrict__ cursor, const int* __restrict__ degI,
        const int* __restrict__ csrSrc, const float* __restrict__ dinv,
        const uint2* __restrict__ H2, const float4* __restrict__ bias4,
        const float4* __restrict__ g4, const float4* __restrict__ beta4,
        const uint4* __restrict__ Wpk, const float* __restrict__ bfv,
        unsigned* __restrict__ Hout, float* __restrict__ outF) {
    __shared__ __align__(16) unsigned sH[16][36];  // 36-word pitch: 2-way-free banks on uint4 reads
    __shared__ float sD[16 * 65];
    int tid = threadIdx.x;
    int wv = tid >> 6, lane = tid & 63;
    int g = lane >> 4;
    unsigned f = (unsigned)(lane & 15);
    unsigned node = (unsigned)(blockIdx.x * 16 + wv);   // always < NN (exact grid)
    int start = cursor[node];
    int deg = degI[node];
    int myIdx = 0;
    if (lane < deg) myIdx = csrSrc[(unsigned)(start + lane)];
    uint2 qs = H2[node * 16u + f];
    float di = dinv[node];
    float4 bb = bias4[f];
    float ax = 0.f, ay = 0.f, az = 0.f, aw = 0.f;
    float bx = 0.f, by = 0.f, bz = 0.f, bw = 0.f;
    uint2 qa[4];
#pragma unroll
    for (int r = 0; r < 4; ++r) {
        int e = r * 4 + g;
        unsigned s = (unsigned)__shfl(myIdx, e);
        qa[r] = make_uint2(0u, 0u);
        if (e < deg) qa[r] = H2[s * 16u + f];
    }
    if (deg <= 16) {
#pragma unroll
        for (int r = 0; r < 4; r += 2) {
            ax += blo(qa[r].x);     ay += bhi(qa[r].x);
            az += blo(qa[r].y);     aw += bhi(qa[r].y);
            bx += blo(qa[r + 1].x); by += bhi(qa[r + 1].x);
            bz += blo(qa[r + 1].y); bw += bhi(qa[r + 1].y);
        }
    } else {
        uint2 qb[4];
#pragma unroll
        for (int r = 0; r < 4; ++r) {
            int e = 16 + r * 4 + g;
            unsigned s = (unsigned)__shfl(myIdx, e);
            qb[r] = make_uint2(0u, 0u);
            if (e < deg) qb[r] = H2[s * 16u + f];
        }
#pragma unroll
        for (int r = 0; r < 4; r += 2) {
            ax += blo(qa[r].x);     ay += bhi(qa[r].x);
            az += blo(qa[r].y);     aw += bhi(qa[r].y);
            bx += blo(qa[r + 1].x); by += bhi(qa[r + 1].x);
            bz += blo(qa[r + 1].y); bw += bhi(qa[r + 1].y);
        }
#pragma unroll
        for (int r = 0; r < 4; r += 2) {
            ax += blo(qb[r].x);     ay += bhi(qb[r].x);
            az += blo(qb[r].y);     aw += bhi(qb[r].y);
            bx += blo(qb[r + 1].x); by += bhi(qb[r + 1].x);
            bz += blo(qb[r + 1].y); bw += bhi(qb[r + 1].y);
        }
        if (deg > 32) {
            int R2 = (deg + 3) >> 2;
            if (R2 > 16) R2 = 16;
            for (int r = 8; r < R2; ++r) {
                int e = r * 4 + g;
                unsigned s = (unsigned)__shfl(myIdx, e);
                uint2 qq = make_uint2(0u, 0u);
                if (e < deg) qq = H2[s * 16u + f];
                ax += blo(qq.x); ay += bhi(qq.x); az += blo(qq.y); aw += bhi(qq.y);
            }
            for (int ee = 64 + g; ee < deg; ee += 4) {
                uint2 qq = H2[(unsigned)csrSrc[(unsigned)(start + ee)] * 16u + f];
                ax += blo(qq.x); ay += bhi(qq.x); az += blo(qq.y); aw += bhi(qq.y);
            }
        }
    }
    ax += bx; ay += by; az += bz; aw += bw;
    ax += __shfl_xor(ax, 16); ay += __shfl_xor(ay, 16);
    az += __shfl_xor(az, 16); aw += __shfl_xor(aw, 16);
    ax += __shfl_xor(ax, 32); ay += __shfl_xor(ay, 32);
    az += __shfl_xor(az, 32); aw += __shfl_xor(aw, 32);
    float vx = fmaxf((ax + blo(qs.x)) * di + bb.x, 0.f);
    float vy = fmaxf((ay + bhi(qs.x)) * di + bb.y, 0.f);
    float vz = fmaxf((az + blo(qs.y)) * di + bb.z, 0.f);
    float vw = fmaxf((aw + bhi(qs.y)) * di + bb.w, 0.f);
    if (DOLN) {
        float s = vx + vy + vz + vw;
        s += __shfl_xor(s, 1); s += __shfl_xor(s, 2);
        s += __shfl_xor(s, 4); s += __shfl_xor(s, 8);
        float mu = s * (1.f / 64.f);
        vx -= mu; vy -= mu; vz -= mu; vw -= mu;
        float vs = vx * vx + vy * vy + vz * vz + vw * vw;
        vs += __shfl_xor(vs, 1); vs += __shfl_xor(vs, 2);
        vs += __shfl_xor(vs, 4); vs += __shfl_xor(vs, 8);
        float inv = rsqrtf(vs * (1.f / 64.f) + LN_EPS);
        float4 gg = g4[f];
        float4 tt = beta4[f];
        vx = vx * inv * gg.x + tt.x;
        vy = vy * inv * gg.y + tt.y;
        vz = vz * inv * gg.z + tt.z;
        vw = vw * inv * gg.w + tt.w;
    }
    // stage this node's row in LDS, exact packed-H bit layout (words 2f, 2f+1)
    if (g == 0) {
        sH[wv][2 * f] = bpack(vx, vy);
        sH[wv][2 * f + 1] = bpack(vz, vw);
    }
    __syncthreads();
    // ---- fused GEMM: 16 nodes x 64  @  W (64 x 64/48), waves 0..NT-1, t = wv
    constexpr int NT = FINAL ? 3 : 4;
    if (wv < NT) {
        int q = lane >> 4, ln = lane & 15;
        short8 a0 = __builtin_bit_cast(short8, ((const uint4*)sH[ln])[q]);       // k = q*8..q*8+7
        short8 a1 = __builtin_bit_cast(short8, ((const uint4*)sH[ln])[4 + q]);   // k = 32+q*8..
        f32x4 acc = {0.f, 0.f, 0.f, 0.f};
        acc = __builtin_amdgcn_mfma_f32_16x16x32_bf16(
            a0, __builtin_bit_cast(short8, Wpk[(0 * NT + wv) * 64 + lane]), acc, 0, 0, 0);
        acc = __builtin_amdgcn_mfma_f32_16x16x32_bf16(
            a1, __builtin_bit_cast(short8, Wpk[(1 * NT + wv) * 64 + lane]), acc, 0, 0, 0);
#pragma unroll
        for (int r = 0; r < 4; ++r)
            sD[(q * 4 + r) * 65 + wv * 16 + ln] = acc[r];
    }
    __syncthreads();
    if (FINAL) {
        for (int i = tid; i < 16 * DOUT; i += 1024) {
            int row = i / DOUT, col = i % DOUT;
            unsigned nd = (unsigned)(blockIdx.x * 16 + row);
            outF[nd * (unsigned)DOUT + col] = sD[row * 65 + col] + bfv[col];
        }
    } else {
        for (int i = tid; i < 16 * 32; i += 1024) {
            int row = i >> 5, c2 = i & 31;
            unsigned nd = (unsigned)(blockIdx.x * 16 + row);
            float dn = dinv[nd];
            Hout[nd * 32u + c2] = bpack(sD[row * 65 + c2 * 2] * dn,
                                        sD[row * 65 + c2 * 2 + 1] * dn);
        }
    }
}

// ----------------------------------------------------------------
extern "C" void kernel_launch(void* const* d_in, const int* in_sizes, int n_in,
                              void* d_out, int out_size, void* d_ws, size_t ws_size,
                              hipStream_t stream) {
    const float* x    = (const float*)d_in[0];
    const int*   ei   = (const int*)d_in[1];
    const int*   srcI = ei;
    const int*   dstI = ei + EE;
    const float* W0   = (const float*)d_in[2];
    const float* b0   = (const float*)d_in[3];
    const float* W1   = (const float*)d_in[4];
    const float* b1   = (const float*)d_in[5];
    const float* W2   = (const float*)d_in[6];
    const float* b2   = (const float*)d_in[7];
    const float* ln0g = (const float*)d_in[8];
    const float* ln0b = (const float*)d_in[9];
    const float* ln1g = (const float*)d_in[10];
    const float* ln1b = (const float*)d_in[11];
    const float* mpW0 = (const float*)d_in[12];
    const float* mpb0 = (const float*)d_in[13];
    const float* mpW1 = (const float*)d_in[14];
    const float* mpb1 = (const float*)d_in[15];
    float* out = (float*)d_out;

    char* ws = (char*)d_ws;
    float*    dinv      = (float*)   (ws + 0);                      // 400 KB
    int*      degI      = (int*)     (ws + 512l * 1024);            // 400 KB
    int*      cursor    = (int*)     (ws + 1024l * 1024);           // 400 KB
    int*      bucketCur = (int*)     (ws + 1600l * 1024);
    uint4*    W0pk      = (uint4*)   (ws + 1792l * 1024);           // 16 KB
    uint4*    W1pk      = (uint4*)   (ws + 1824l * 1024);           // 8 KB
    uint4*    W2pk      = (uint4*)   (ws + 1856l * 1024);           // 8 KB
    uint4*    Wfpk      = (uint4*)   (ws + 1888l * 1024);           // 6 KB
    float*    bfv       = (float*)   (ws + 1920l * 1024);           // 192 B
    unsigned* bE        = (unsigned*)(ws + 2048l * 1024);           // 391*8192*4 = 12.8 MB
    int*      csrSrc    = (int*)     (ws + 15l * 1024 * 1024);      // 6.4 MB
    unsigned* bufA      = (unsigned*)(ws + 22l * 1024 * 1024);      // bf16 H' 12.8 MB
    unsigned* bufB      = (unsigned*)(ws + 36l * 1024 * 1024);      // bf16 H' ping-pong 12.8 MB

    const int aggBlocks  = NN / 16;            // 6250 exact
    const int gemmBlocks = (NN + 63) / 64;     // 1563

    hipMemsetAsync(bucketCur, 0, NBUCK * sizeof(int), stream);
    bucket_k<<<TBLK + 1, 1024, 0, stream>>>(srcI, dstI, bucketCur, bE,
                                            W0, W1, W2, mpW0, mpb0, mpW1, mpb1,
                                            W0pk, W1pk, W2pk, Wfpk, bfv);
    reorder2_k<<<NBUCK, 1024, 0, stream>>>(bucketCur, bE, csrSrc, degI, cursor, dinv);

    // layer 0 GEMM (f32 input)
    gemm0<<<gemmBlocks, 256, 0, stream>>>(x, W0pk, dinv, bufA);
    // conv0 finish (LN0) + fused GEMM W1
    aggf_k<1, 0><<<aggBlocks, 1024, 0, stream>>>(cursor, degI, csrSrc, dinv,
                                                 (const uint2*)bufA, (const float4*)b0,
                                                 (const float4*)ln0g, (const float4*)ln0b,
                                                 W1pk, bfv, bufB, out);
    // conv1 finish (LN1) + fused GEMM W2
    aggf_k<1, 0><<<aggBlocks, 1024, 0, stream>>>(cursor, degI, csrSrc, dinv,
                                                 (const uint2*)bufB, (const float4*)b1,
                                                 (const float4*)ln1g, (const float4*)ln1b,
                                                 W2pk, bfv, bufA, out);
    // conv2 finish (no LN) + fused head GEMM Wf + bf -> output
    aggf_k<0, 1><<<aggBlocks, 1024, 0, stream>>>(cursor, degI, csrSrc, dinv,
                                                 (const uint2*)bufA, (const float4*)b2,
                                                 (const float4*)ln0g, (const float4*)ln0b,
                                                 Wfpk, bfv, bufB, out);
}